// Round 2
// baseline (4881.022 us; speedup 1.0000x reference)
//
#include <hip/hip_runtime.h>
#include <hip/hip_cooperative_groups.h>

// SimpleStateSpaceModel restructure v3:
//   v2 profile: k_weights (<<<1,64>>>, serial fp64) = 413us (20%!) -> grid-parallel (~3us)
//   pass2: 127 seq k_matvec launches -> 1 cooperative kernel, M staged in LDS once,
//          grid.sync() between chain steps (fallback to k_matvec loop if coop launch fails)
// Next-round candidates: 8-phase 256^2 GEMM for the 5 big k_gemm2; concat K=10240 obs GEMM.

#define SD 2048      // state dim
#define OD 512       // obs dim
#define NT 8192      // steps
#define BLK 64       // steps per block
#define KB 128       // number of blocks = NT/BLK
#define NP 7         // binomial terms p=0..6 (pass1 / M)
#define NPH 6        // homogeneous obs terms p=0..5
#define NPN 5        // noise obs terms p=0..4
#define PROC_STD 0.31622776601683794f
#define OBS_STD  0.7071067811865476f

namespace cg = cooperative_groups;

typedef __attribute__((ext_vector_type(8))) short v8s;
typedef __attribute__((ext_vector_type(4))) float v4f;

__device__ __forceinline__ unsigned short f2bf(float f) {
    union { float f; unsigned int u; } v; v.f = f;
    unsigned int r = v.u + 0x7fffu + ((v.u >> 16) & 1u);
    return (unsigned short)(r >> 16);
}

// ---------------- weights (device-computed, double precision, grid-parallel) -------------
__device__ double d_binom(int m, int p) {
    if (p < 0 || p > m) return 0.0;
    double c = 1.0;
    for (int q = 1; q <= p; ++q) c = c * (double)(m - p + q) / (double)q;
    return c;
}
__device__ double d_p99(int n) {
    double r = 1.0;
    for (int q = 0; q < n; ++q) r *= 0.99;
    return r;
}
// wW[p][j] = sigma*C(63-j,p)*0.99^(63-j-p)        (pass1 reduction weights)
// cW[p][i] = C(i,p)*0.99^(i-p)                    (homogeneous obs coeffs)
// T[p][j][i] = sigma*C(i-1-j,p)*0.99^(i-1-j-p)    (within-block noise prefix weights)
__global__ __launch_bounds__(256) void k_weights2(float* __restrict__ wW,
                                                  float* __restrict__ cW,
                                                  float* __restrict__ T) {
    int idx = blockIdx.x * 256 + threadIdx.x;     // 0 .. NP*64*64-1
    if (idx < NP * 64) {
        int p = idx >> 6, j = idx & 63;
        int m = 63 - j;
        wW[idx] = (p <= m) ? (float)((double)PROC_STD * d_binom(m, p) * d_p99(m - p)) : 0.f;
        cW[idx] = (p <= j) ? (float)(d_binom(j, p) * d_p99(j - p)) : 0.f;
    }
    if (idx < NP * 64 * 64) {
        int p = idx >> 12, j = (idx >> 6) & 63, i = idx & 63;
        int mm = i - 1 - j;
        T[idx] = (mm >= p) ? (float)((double)PROC_STD * d_binom(mm, p) * d_p99(mm - p)) : 0.f;
    }
}

// ---------------- prep kernels ----------------
__global__ __launch_bounds__(256) void k_prep_A(const float* __restrict__ A,
                                                unsigned short* __restrict__ Ebf,
                                                float* __restrict__ M, float c1) {
    int idx = blockIdx.x * 256 + threadIdx.x;
    int r = idx >> 11, c = idx & 2047;
    float e = A[idx] - (r == c ? 0.99f : 0.0f);
    Ebf[idx] = f2bf(e);
    M[idx] = c1 * e;
}

__global__ __launch_bounds__(256) void k_prep_C(const float* __restrict__ C,
                                                unsigned short* __restrict__ Cbf) {
    int idx = blockIdx.x * 256 + threadIdx.x;
    Cbf[idx] = f2bf(C[idx]);
}

__global__ __launch_bounds__(256) void k_prep_S0(const float* __restrict__ s0,
                                                 float* __restrict__ Sb) {
    int idx = blockIdx.x * 256 + threadIdx.x;
    Sb[idx] = s0[idx];
}

// S32[d][k] = Sb[k][d]
__global__ __launch_bounds__(256) void k_init_S(const float* __restrict__ Sb,
                                                float* __restrict__ S32,
                                                unsigned short* __restrict__ Sbf) {
    int idx = blockIdx.x * 256 + threadIdx.x;
    int d = idx >> 7, k = idx & 127;
    float v = Sb[k * SD + d];
    S32[idx] = v;
    Sbf[idx] = f2bf(v);
}

// ---------------- pass1 reduction: W_p[d][k] = sum_j wW[p][j]*pn[(k*64+j),d] -------------
// p=0..5 -> W; p=6 -> V32/Vbf (Horner init)
__global__ __launch_bounds__(256) void k_wsum(const float* __restrict__ pn,
                                              const float* __restrict__ wW,
                                              float* __restrict__ W,
                                              float* __restrict__ V32,
                                              unsigned short* __restrict__ Vbf) {
    __shared__ float ws[NP * 64];
    int tid = threadIdx.x;
    for (int t = tid; t < NP * 64; t += 256) ws[t] = wW[t];
    __syncthreads();
    int bx = blockIdx.x;                 // 1024 = 128 k * 8 d-chunks
    int k = bx >> 3, dc = bx & 7;
    int d = dc * 256 + tid;
    float acc[NP];
#pragma unroll
    for (int p = 0; p < NP; ++p) acc[p] = 0.f;
    for (int j = 0; j < 64; ++j) {
        float v = pn[(size_t)(k * BLK + j) * SD + d];
#pragma unroll
        for (int p = 0; p < NP; ++p) acc[p] += ws[p * 64 + j] * v;
    }
#pragma unroll
    for (int p = 0; p < 6; ++p) W[((size_t)p * SD + d) * KB + k] = acc[p];
    V32[(size_t)d * KB + k] = acc[6];
    Vbf[(size_t)d * KB + k] = f2bf(acc[6]);
}

// ---------------- Horner step: V' = E @ V + W_p   (2048 x 128, K=2048) ----------------
__global__ __launch_bounds__(256) void k_horner(const unsigned short* __restrict__ Ebf,
                                                const unsigned short* __restrict__ Xbf,
                                                const float* __restrict__ Wp,
                                                float* __restrict__ X32o,
                                                unsigned short* __restrict__ Xbfo) {
    __shared__ __align__(16) unsigned short Al[32 * 72];
    __shared__ __align__(16) unsigned short Xt[32 * 72];
    int bx = blockIdx.x;
    int tM = (bx & 63) * 32, tN = (bx >> 6) * 32;
    int tid = threadIdx.x, lane = tid & 63, w = tid >> 6;
    int m16 = lane & 15, q = lane >> 4;
    int ar = tid >> 3, ao = (tid & 7) * 8;
    int xk = tid >> 2, xn = (tid & 3) * 8;
    int qb = xk >> 3;
    v4f acc = {0, 0, 0, 0};
    v8s av = *(const v8s*)(Ebf + (size_t)(tM + ar) * SD + ao);
    v8s xv = *(const v8s*)(Xbf + (size_t)xk * KB + tN + xn);
    int nl = (w & 1) * 16 + m16;
    int swn = (nl >> 3) & 3;
    int rl = (w >> 1) * 16 + m16;
    for (int k0 = 0; k0 < SD; k0 += 64) {
        *(v8s*)(Al + ar * 72 + ao) = av;
#pragma unroll
        for (int c = 0; c < 8; ++c) {
            int n = xn + c, sw = (n >> 3) & 3;
            Xt[n * 72 + (((qb ^ sw) << 3) | (xk & 7))] = xv[c];
        }
        __syncthreads();
        if (k0 + 64 < SD) {
            av = *(const v8s*)(Ebf + (size_t)(tM + ar) * SD + (k0 + 64) + ao);
            xv = *(const v8s*)(Xbf + (size_t)(k0 + 64 + xk) * KB + tN + xn);
        }
#pragma unroll
        for (int ch = 0; ch < 2; ++ch) {
            v8s a = *(const v8s*)(Al + rl * 72 + ch * 32 + q * 8);
            int q2 = ch * 4 + q;
            v8s b = *(const v8s*)(Xt + nl * 72 + ((q2 ^ swn) << 3));
            acc = __builtin_amdgcn_mfma_f32_16x16x32_bf16(a, b, acc, 0, 0, 0);
        }
        __syncthreads();
    }
#pragma unroll
    for (int j = 0; j < 4; ++j) {
        int r = tM + (w >> 1) * 16 + q * 4 + j;
        int kc = tN + (w & 1) * 16 + m16;
        int idx = r * KB + kc;
        float v = acc[j] + Wp[idx];
        X32o[idx] = v;
        Xbfo[idx] = f2bf(v);
    }
}

// ---------------- power GEMM: acc = L @ X, M += coef*acc, Xout = bf16(acc) ---------------
__global__ __launch_bounds__(256) void k_gemm_pow(const unsigned short* __restrict__ L,
                                                  const unsigned short* __restrict__ X,
                                                  float* __restrict__ M,
                                                  unsigned short* __restrict__ Xout,
                                                  float coef) {
    __shared__ __align__(16) unsigned short Al[64 * 40];
    __shared__ __align__(16) unsigned short Xt[64 * 40];
    int tid = threadIdx.x, lane = tid & 63, w = tid >> 6;
    int m16 = lane & 15, q = lane >> 4;
    int bx = blockIdx.x;
    int tM = (bx & 31) * 64, tN = (bx >> 5) * 64;
    int ar = tid >> 2, ao = (tid & 3) * 8;
    int xk = tid >> 3, xn = (tid & 7) * 8;
    int qb = xk >> 3;
    v4f acc[4] = {{0,0,0,0},{0,0,0,0},{0,0,0,0},{0,0,0,0}};

    v8s av = *(const v8s*)(L + (size_t)(tM + ar) * SD + ao);
    v8s xv = *(const v8s*)(X + (size_t)xk * SD + tN + xn);
    for (int k0 = 0; k0 < SD; k0 += 32) {
        *(v8s*)(Al + ar * 40 + ao) = av;
#pragma unroll
        for (int c = 0; c < 8; ++c) {
            int n = xn + c, sw = (n >> 3) & 3;
            Xt[n * 40 + (((qb ^ sw) << 3) | (xk & 7))] = xv[c];
        }
        __syncthreads();
        if (k0 + 32 < SD) {
            av = *(const v8s*)(L + (size_t)(tM + ar) * SD + (k0 + 32) + ao);
            xv = *(const v8s*)(X + (size_t)(k0 + 32 + xk) * SD + tN + xn);
        }
        v8s a = *(const v8s*)(Al + (w * 16 + m16) * 40 + q * 8);
#pragma unroll
        for (int c = 0; c < 4; ++c) {
            int nl = c * 16 + m16, swn = (nl >> 3) & 3;
            v8s b = *(const v8s*)(Xt + nl * 40 + ((q ^ swn) << 3));
            acc[c] = __builtin_amdgcn_mfma_f32_16x16x32_bf16(a, b, acc[c], 0, 0, 0);
        }
        __syncthreads();
    }
#pragma unroll
    for (int c = 0; c < 4; ++c) {
#pragma unroll
        for (int j = 0; j < 4; ++j) {
            int r = tM + w * 16 + q * 4 + j;
            int col = tN + c * 16 + m16;
            size_t idx = (size_t)r * SD + col;
            float v = acc[c][j];
            M[idx] += coef * v;
            Xout[idx] = f2bf(v);
        }
    }
}

// ---------------- generic 512-row GEMM: out = A(512x2048) @ B(2048xN, row stride ldb) ----
__global__ __launch_bounds__(256) void k_gemm2(const unsigned short* __restrict__ A,
                                               const unsigned short* __restrict__ B,
                                               int ldb,
                                               unsigned short* __restrict__ obf,
                                               float* __restrict__ o32,
                                               int ldo, int accum) {
    __shared__ __align__(16) unsigned short Al[64 * 40];
    __shared__ __align__(16) unsigned short Xt[64 * 40];
    int tid = threadIdx.x, lane = tid & 63, w = tid >> 6;
    int m16 = lane & 15, q = lane >> 4;
    int bx = blockIdx.x;
    int tM = (bx & 7) * 64, tN = (bx >> 3) * 64;
    A += (size_t)blockIdx.y * OD * SD;
    if (o32) o32 += (size_t)blockIdx.y * OD * ldo;
    int ar = tid >> 2, ao = (tid & 3) * 8;
    int xk = tid >> 3, xn = (tid & 7) * 8;
    int qb = xk >> 3;
    v4f acc[4] = {{0,0,0,0},{0,0,0,0},{0,0,0,0},{0,0,0,0}};

    v8s av = *(const v8s*)(A + (size_t)(tM + ar) * SD + ao);
    v8s xv = *(const v8s*)(B + (size_t)xk * ldb + tN + xn);
    for (int k0 = 0; k0 < SD; k0 += 32) {
        *(v8s*)(Al + ar * 40 + ao) = av;
#pragma unroll
        for (int c = 0; c < 8; ++c) {
            int n = xn + c, sw = (n >> 3) & 3;
            Xt[n * 40 + (((qb ^ sw) << 3) | (xk & 7))] = xv[c];
        }
        __syncthreads();
        if (k0 + 32 < SD) {
            av = *(const v8s*)(A + (size_t)(tM + ar) * SD + (k0 + 32) + ao);
            xv = *(const v8s*)(B + (size_t)(k0 + 32 + xk) * ldb + tN + xn);
        }
        v8s a = *(const v8s*)(Al + (w * 16 + m16) * 40 + q * 8);
#pragma unroll
        for (int c = 0; c < 4; ++c) {
            int nl = c * 16 + m16, swn = (nl >> 3) & 3;
            v8s b = *(const v8s*)(Xt + nl * 40 + ((q ^ swn) << 3));
            acc[c] = __builtin_amdgcn_mfma_f32_16x16x32_bf16(a, b, acc[c], 0, 0, 0);
        }
        __syncthreads();
    }
#pragma unroll
    for (int c = 0; c < 4; ++c) {
#pragma unroll
        for (int j = 0; j < 4; ++j) {
            int r = tM + w * 16 + q * 4 + j;
            int col = tN + c * 16 + m16;
            float v = acc[c][j];
            if (o32) {
                size_t idx = (size_t)r * ldo + col;
                if (accum) o32[idx] += v; else o32[idx] = v;
            }
            if (obf) obf[(size_t)r * ldo + col] = f2bf(v);
        }
    }
}

// ---------------- noise prefix weights: Zbf[d][64k+i] = sum_j T[j][i]*pn[(64k+j),d] ------
__global__ __launch_bounds__(256) void k_applyT(const float* __restrict__ pn,
                                                const float* __restrict__ Tp,
                                                unsigned short* __restrict__ Zbf) {
    __shared__ float pt[64][64];
    int bx = blockIdx.x;                 // 4096 = 128 k * 32 d-chunks(64)
    int k = bx >> 5, dc = bx & 31;
    int d0 = dc * 64;
    int tid = threadIdx.x, il = tid & 63, dg = tid >> 6;
#pragma unroll
    for (int r = 0; r < 16; ++r) {
        int j = r * 4 + dg;
        pt[j][il] = pn[(size_t)(k * BLK + j) * SD + d0 + il];
    }
    __syncthreads();
    float z[16];
#pragma unroll
    for (int u = 0; u < 16; ++u) z[u] = 0.f;
    for (int j = 0; j < 63; ++j) {       // T[j][i]==0 for j>=i; j=63 row all-zero
        float tv = Tp[j * 64 + il];
#pragma unroll
        for (int u = 0; u < 16; ++u) z[u] += tv * pt[j][dg * 16 + u];
    }
#pragma unroll
    for (int u = 0; u < 16; ++u)
        Zbf[(size_t)(d0 + dg * 16 + u) * NT + k * BLK + il] = f2bf(z[u]);
}

// ---------------- pass 2 fused: 127-step boundary chain in ONE cooperative kernel --------
// block bid owns rows [8*bid, 8*bid+8); its 8 M-rows are staged in LDS once (64 KB).
// per step: s_{k+1}[r] = a64*s_k[r] + Mlds[r]·s_k + Ufin[r][k];  grid.sync() between steps.
__global__ __launch_bounds__(256) void k_stitch(const float* __restrict__ M,
                                                float* __restrict__ Sb,
                                                const float* __restrict__ Ufin,
                                                float a64) {
    __shared__ float Ml[8][SD];          // 64 KB
    cg::grid_group grid = cg::this_grid();
    int bid = blockIdx.x;                // 0..255
    int r0 = bid * 8;
    int tid = threadIdx.x, lane = tid & 63, w = tid >> 6;
    const float4* M4 = (const float4*)(M + (size_t)r0 * SD);
    float4* Ml4 = (float4*)&Ml[0][0];
    for (int t = tid; t < 8 * SD / 4; t += 256) Ml4[t] = M4[t];
    __syncthreads();
    for (int k = 0; k < KB - 1; ++k) {
        const float* s = Sb + (size_t)k * SD;
        float* so = Sb + (size_t)(k + 1) * SD;
        const float4* S4 = (const float4*)s;
#pragma unroll
        for (int rep = 0; rep < 2; ++rep) {
            int rl = w * 2 + rep;        // local row 0..7
            const float4* Mr = (const float4*)&Ml[rl][0];
            float acc = 0.f;
#pragma unroll
            for (int it = 0; it < 8; ++it) {
                float4 m4 = Mr[lane + it * 64];
                float4 s4 = S4[lane + it * 64];
                acc += m4.x * s4.x + m4.y * s4.y + m4.z * s4.z + m4.w * s4.w;
            }
#pragma unroll
            for (int off = 32; off; off >>= 1) acc += __shfl_down(acc, off);
            if (lane == 0) {
                int r = r0 + rl;
                so[r] = a64 * s[r] + acc + Ufin[r * KB + k];
            }
        }
        grid.sync();
    }
}

// ---------------- pass 2 fallback: single boundary matvec (127 launches) -----------------
__global__ __launch_bounds__(256) void k_matvec(const float* __restrict__ M,
                                                const float* __restrict__ Sb_in,
                                                const float* __restrict__ Ufin,
                                                float* __restrict__ Sb_out,
                                                int k, float a64) {
    int lane = threadIdx.x & 63;
    int wg = blockIdx.x * 4 + (threadIdx.x >> 6);
    const float4* S4 = (const float4*)Sb_in;
#pragma unroll
    for (int rep = 0; rep < 2; ++rep) {
        int r = wg + rep * 1024;
        const float4* Mr = (const float4*)(M + (size_t)r * SD);
        float acc = 0.f;
#pragma unroll
        for (int it = 0; it < 8; ++it) {
            float4 m4 = Mr[lane + it * 64];
            float4 s4 = S4[lane + it * 64];
            acc += m4.x * s4.x + m4.y * s4.y + m4.z * s4.z + m4.w * s4.w;
        }
#pragma unroll
        for (int off = 32; off; off >>= 1) acc += __shfl_down(acc, off);
        if (lane == 0) Sb_out[r] = a64 * Sb_in[r] + acc + Ufin[r * KB + k];
    }
}

// ---------------- final: out[t][o] = OBSn[o][t] + sum_p cW[p][i]*H[p][o][k] + sig*on ----
__global__ __launch_bounds__(256) void k_final(const float* __restrict__ OBSn,
                                               const float* __restrict__ H,
                                               const float* __restrict__ cW,
                                               const float* __restrict__ on,
                                               float* __restrict__ out) {
    __shared__ float tile[64][65];
    int bx = blockIdx.x;                 // 1024 = 128 t-tiles * 8 o-tiles
    int tkb = bx >> 3, ob = bx & 7;
    int t0 = tkb * 64, o0 = ob * 64;
    int tid = threadIdx.x, lane = tid & 63, g = tid >> 6;
#pragma unroll
    for (int r = 0; r < 16; ++r) {
        int oo = r * 4 + g;
        tile[oo][lane] = OBSn[(size_t)(o0 + oo) * NT + t0 + lane];
    }
    float Hv[NPH];
#pragma unroll
    for (int p = 0; p < NPH; ++p)
        Hv[p] = H[((size_t)p * OD + o0 + lane) * KB + tkb];
    __syncthreads();
#pragma unroll
    for (int r = 0; r < 16; ++r) {
        int trow = r * 4 + g;            // i within block
        float acc = tile[lane][trow];
#pragma unroll
        for (int p = 0; p < NPH; ++p) acc += cW[p * 64 + trow] * Hv[p];
        size_t oidx = (size_t)(t0 + trow) * OD + o0 + lane;
        out[oidx] = acc + OBS_STD * on[oidx];
    }
}

// ---------------- host ----------------
extern "C" void kernel_launch(void* const* d_in, const int* in_sizes, int n_in,
                              void* d_out, int out_size, void* d_ws, size_t ws_size,
                              hipStream_t stream) {
    const float* s0 = (const float*)d_in[0];
    const float* A  = (const float*)d_in[1];
    const float* C  = (const float*)d_in[2];
    const float* pn = (const float*)d_in[3];
    const float* on = (const float*)d_in[4];
    float* out = (float*)d_out;

    char* p = (char*)d_ws;
    auto take = [&](size_t n) { char* r = p; p += (n + 255) & ~(size_t)255; return r; };
    unsigned short* Ebf   = (unsigned short*)take((size_t)SD * SD * 2);
    unsigned short* CEall = (unsigned short*)take((size_t)NPH * OD * SD * 2);  // CE_0..CE_5
    // M, Xp0, Xp1 are contiguous (33.55 MB); dead after the stitch -> reused as Zbf
    float* M            = (float*)take((size_t)SD * SD * 4);
    unsigned short* Xp0 = (unsigned short*)take((size_t)SD * SD * 2);
    unsigned short* Xp1 = (unsigned short*)take((size_t)SD * SD * 2);
    unsigned short* Zbf = (unsigned short*)M;                 // SD*NT*2 == 33,554,432 B
    float* W      = (float*)take((size_t)6 * SD * KB * 4);
    float* V32[2] = {(float*)take((size_t)SD * KB * 4), (float*)take((size_t)SD * KB * 4)};
    unsigned short* Vbf[2] = {(unsigned short*)take((size_t)SD * KB * 2),
                              (unsigned short*)take((size_t)SD * KB * 2)};
    float* Sb   = (float*)take((size_t)KB * SD * 4);
    float* S32  = (float*)take((size_t)SD * KB * 4);
    unsigned short* Sbf = (unsigned short*)take((size_t)SD * KB * 2);
    float* wW   = (float*)take((size_t)NP * 64 * 4);
    float* cW   = (float*)take((size_t)NP * 64 * 4);
    float* wT   = (float*)take((size_t)NP * 64 * 64 * 4);
    float* OBSn = (float*)take((size_t)OD * NT * 4);
    float* H    = (float*)take((size_t)NPH * OD * KB * 4);

    // A^64 = 0.99^64 I + sum_{m=1..6} C(64,m) 0.99^(64-m) E^m   (tail ~2e-6)
    double pw[65]; pw[0] = 1.0;
    for (int m = 1; m <= 64; ++m) pw[m] = pw[m - 1] * 0.99;
    const double bin[7] = {1, 64, 2016, 41664, 635376, 7624512, 74974368};
    float cf[7];
    for (int m = 1; m <= 6; ++m) cf[m] = (float)(bin[m] * pw[64 - m]);
    float a64 = (float)pw[64];

    k_weights2<<<NP * 64 * 64 / 256, 256, 0, stream>>>(wW, cW, wT);
    k_prep_A<<<SD * SD / 256, 256, 0, stream>>>(A, Ebf, M, cf[1]);
    k_prep_C<<<OD * SD / 256, 256, 0, stream>>>(C, CEall);    // CE_0 = bf16(C)
    k_prep_S0<<<SD / 256, 256, 0, stream>>>(s0, Sb);

    // powers E^2..E^6 (bf16 MFMA), accumulate into M
    k_gemm_pow<<<1024, 256, 0, stream>>>(Ebf, Ebf, M, Xp0, cf[2]);
    k_gemm_pow<<<1024, 256, 0, stream>>>(Ebf, Xp0, M, Xp1, cf[3]);
    k_gemm_pow<<<1024, 256, 0, stream>>>(Ebf, Xp1, M, Xp0, cf[4]);
    k_gemm_pow<<<1024, 256, 0, stream>>>(Ebf, Xp0, M, Xp1, cf[5]);
    k_gemm_pow<<<1024, 256, 0, stream>>>(Ebf, Xp1, M, Xp0, cf[6]);

    // pass 1: u_k = sum_p E^p W_p via Horner (V init = W_6)
    k_wsum<<<1024, 256, 0, stream>>>(pn, wW, W, V32[0], Vbf[0]);
    int cur = 0;
    for (int pp = 5; pp >= 0; --pp) {
        k_horner<<<256, 256, 0, stream>>>(Ebf, Vbf[cur], W + (size_t)pp * SD * KB,
                                          V32[cur ^ 1], Vbf[cur ^ 1]);
        cur ^= 1;
    }  // cur == 0: V32[0] = u_k in [d][k]

    // pass 2: fused cooperative boundary stitch with A^64 (fallback: 127 matvec launches)
    {
        const float* Marg = M;
        float* Sbarg = Sb;
        const float* Uarg = V32[cur];
        void* args[] = {(void*)&Marg, (void*)&Sbarg, (void*)&Uarg, (void*)&a64};
        hipError_t e = hipLaunchCooperativeKernel((void*)k_stitch, dim3(256), dim3(256),
                                                  args, 0, stream);
        if (e != hipSuccess) {
            for (int k = 0; k < KB - 1; ++k)
                k_matvec<<<256, 256, 0, stream>>>(M, Sb + (size_t)k * SD, V32[cur],
                                                  Sb + (size_t)(k + 1) * SD, k, a64);
        }
    }

    // pass 3: polynomial observation assembly
    k_init_S<<<SD * KB / 256, 256, 0, stream>>>(Sb, S32, Sbf);
    // CE_p = CE_{p-1} @ E
    for (int pp = 1; pp < NPH; ++pp)
        k_gemm2<<<dim3(256, 1), 256, 0, stream>>>(CEall + (size_t)(pp - 1) * OD * SD, Ebf, SD,
                                                  CEall + (size_t)pp * OD * SD,
                                                  (float*)nullptr, SD, 0);
    // H[p] = CE_p @ S_bound  (batched over p)
    k_gemm2<<<dim3(16, NPH), 256, 0, stream>>>(CEall, Sbf, KB,
                                               (unsigned short*)nullptr, H, KB, 0);
    // OBSn = sum_p CE_p @ Z_p   (Z_p regenerated per p into aliased M/Xp region)
    for (int pp = 0; pp < NPN; ++pp) {
        k_applyT<<<4096, 256, 0, stream>>>(pn, wT + (size_t)pp * 4096, Zbf);
        k_gemm2<<<dim3(1024, 1), 256, 0, stream>>>(CEall + (size_t)pp * OD * SD, Zbf, NT,
                                                   (unsigned short*)nullptr, OBSn, NT, pp ? 1 : 0);
    }
    k_final<<<1024, 256, 0, stream>>>(OBSn, H, cW, on, out);
}

// Round 3
// 1518.791 us; speedup vs baseline: 3.2138x; 3.2138x over previous
//
#include <hip/hip_runtime.h>

// SimpleStateSpaceModel restructure v4:
//   v3 lesson: grid.sync() ~28us/iter on gfx950 (XCD L2 flush) -> cooperative stitch removed.
//   pass2: 127 seq matvec launches -> 5-round Hillis-Steele scan (A64^32 ~ 1e-9, truncate):
//     S'[:,k] = S[:,k] + a_r*S[:,k-2^r] + M_r @ S[:,k-2^r], M_{r+1} = 2 a_r M_r + M_r^2
//     scalar diagonal exact fp32; only ||M_r||~0.4 correction in bf16. 10 launches total.
// Next-round candidates: 128^2-tile structure for the 9 full 2048^3 GEMMs + 5 big obs GEMMs.

#define SD 2048      // state dim
#define OD 512       // obs dim
#define NT 8192      // steps
#define BLK 64       // steps per block
#define KB 128       // number of blocks = NT/BLK
#define KBP (KB+16)  // padded column stride for scan bf16 buffers (16 zero cols in front)
#define NP 7         // binomial terms p=0..6 (pass1 / M)
#define NPH 6        // homogeneous obs terms p=0..5
#define NPN 5        // noise obs terms p=0..4
#define PROC_STD 0.31622776601683794f
#define OBS_STD  0.7071067811865476f

typedef __attribute__((ext_vector_type(8))) short v8s;
typedef __attribute__((ext_vector_type(4))) float v4f;

__device__ __forceinline__ unsigned short f2bf(float f) {
    union { float f; unsigned int u; } v; v.f = f;
    unsigned int r = v.u + 0x7fffu + ((v.u >> 16) & 1u);
    return (unsigned short)(r >> 16);
}

// ---------------- weights (device-computed, double precision, grid-parallel) -------------
__device__ double d_binom(int m, int p) {
    if (p < 0 || p > m) return 0.0;
    double c = 1.0;
    for (int q = 1; q <= p; ++q) c = c * (double)(m - p + q) / (double)q;
    return c;
}
__device__ double d_p99(int n) {
    double r = 1.0;
    for (int q = 0; q < n; ++q) r *= 0.99;
    return r;
}
__global__ __launch_bounds__(256) void k_weights2(float* __restrict__ wW,
                                                  float* __restrict__ cW,
                                                  float* __restrict__ T) {
    int idx = blockIdx.x * 256 + threadIdx.x;     // 0 .. NP*64*64-1
    if (idx < NP * 64) {
        int p = idx >> 6, j = idx & 63;
        int m = 63 - j;
        wW[idx] = (p <= m) ? (float)((double)PROC_STD * d_binom(m, p) * d_p99(m - p)) : 0.f;
        cW[idx] = (p <= j) ? (float)(d_binom(j, p) * d_p99(j - p)) : 0.f;
    }
    if (idx < NP * 64 * 64) {
        int p = idx >> 12, j = (idx >> 6) & 63, i = idx & 63;
        int mm = i - 1 - j;
        T[idx] = (mm >= p) ? (float)((double)PROC_STD * d_binom(mm, p) * d_p99(mm - p)) : 0.f;
    }
}

// ---------------- prep kernels ----------------
__global__ __launch_bounds__(256) void k_prep_A(const float* __restrict__ A,
                                                unsigned short* __restrict__ Ebf,
                                                float* __restrict__ M, float c1) {
    int idx = blockIdx.x * 256 + threadIdx.x;
    int r = idx >> 11, c = idx & 2047;
    float e = A[idx] - (r == c ? 0.99f : 0.0f);
    Ebf[idx] = f2bf(e);
    M[idx] = c1 * e;
}

__global__ __launch_bounds__(256) void k_prep_C(const float* __restrict__ C,
                                                unsigned short* __restrict__ Cbf) {
    int idx = blockIdx.x * 256 + threadIdx.x;
    Cbf[idx] = f2bf(C[idx]);
}

// bf16 cast of M (scan round-0 GEMM input)
__global__ __launch_bounds__(256) void k_castM(const float* __restrict__ M,
                                               unsigned short* __restrict__ Mbf) {
    int idx = blockIdx.x * 256 + threadIdx.x;
    Mbf[idx] = f2bf(M[idx]);
}

// ---------------- pass1 reduction: W_p[d][k] = sum_j wW[p][j]*pn[(k*64+j),d] -------------
__global__ __launch_bounds__(256) void k_wsum(const float* __restrict__ pn,
                                              const float* __restrict__ wW,
                                              float* __restrict__ W,
                                              float* __restrict__ V32,
                                              unsigned short* __restrict__ Vbf) {
    __shared__ float ws[NP * 64];
    int tid = threadIdx.x;
    for (int t = tid; t < NP * 64; t += 256) ws[t] = wW[t];
    __syncthreads();
    int bx = blockIdx.x;                 // 1024 = 128 k * 8 d-chunks
    int k = bx >> 3, dc = bx & 7;
    int d = dc * 256 + tid;
    float acc[NP];
#pragma unroll
    for (int p = 0; p < NP; ++p) acc[p] = 0.f;
    for (int j = 0; j < 64; ++j) {
        float v = pn[(size_t)(k * BLK + j) * SD + d];
#pragma unroll
        for (int p = 0; p < NP; ++p) acc[p] += ws[p * 64 + j] * v;
    }
#pragma unroll
    for (int p = 0; p < 6; ++p) W[((size_t)p * SD + d) * KB + k] = acc[p];
    V32[(size_t)d * KB + k] = acc[6];
    Vbf[(size_t)d * KB + k] = f2bf(acc[6]);
}

// ---------------- Horner step: V' = E @ V + W_p   (2048 x 128, K=2048) ----------------
__global__ __launch_bounds__(256) void k_horner(const unsigned short* __restrict__ Ebf,
                                                const unsigned short* __restrict__ Xbf,
                                                const float* __restrict__ Wp,
                                                float* __restrict__ X32o,
                                                unsigned short* __restrict__ Xbfo) {
    __shared__ __align__(16) unsigned short Al[32 * 72];
    __shared__ __align__(16) unsigned short Xt[32 * 72];
    int bx = blockIdx.x;
    int tM = (bx & 63) * 32, tN = (bx >> 6) * 32;
    int tid = threadIdx.x, lane = tid & 63, w = tid >> 6;
    int m16 = lane & 15, q = lane >> 4;
    int ar = tid >> 3, ao = (tid & 7) * 8;
    int xk = tid >> 2, xn = (tid & 3) * 8;
    int qb = xk >> 3;
    v4f acc = {0, 0, 0, 0};
    v8s av = *(const v8s*)(Ebf + (size_t)(tM + ar) * SD + ao);
    v8s xv = *(const v8s*)(Xbf + (size_t)xk * KB + tN + xn);
    int nl = (w & 1) * 16 + m16;
    int swn = (nl >> 3) & 3;
    int rl = (w >> 1) * 16 + m16;
    for (int k0 = 0; k0 < SD; k0 += 64) {
        *(v8s*)(Al + ar * 72 + ao) = av;
#pragma unroll
        for (int c = 0; c < 8; ++c) {
            int n = xn + c, sw = (n >> 3) & 3;
            Xt[n * 72 + (((qb ^ sw) << 3) | (xk & 7))] = xv[c];
        }
        __syncthreads();
        if (k0 + 64 < SD) {
            av = *(const v8s*)(Ebf + (size_t)(tM + ar) * SD + (k0 + 64) + ao);
            xv = *(const v8s*)(Xbf + (size_t)(k0 + 64 + xk) * KB + tN + xn);
        }
#pragma unroll
        for (int ch = 0; ch < 2; ++ch) {
            v8s a = *(const v8s*)(Al + rl * 72 + ch * 32 + q * 8);
            int q2 = ch * 4 + q;
            v8s b = *(const v8s*)(Xt + nl * 72 + ((q2 ^ swn) << 3));
            acc = __builtin_amdgcn_mfma_f32_16x16x32_bf16(a, b, acc, 0, 0, 0);
        }
        __syncthreads();
    }
#pragma unroll
    for (int j = 0; j < 4; ++j) {
        int r = tM + (w >> 1) * 16 + q * 4 + j;
        int kc = tN + (w & 1) * 16 + m16;
        int idx = r * KB + kc;
        float v = acc[j] + Wp[idx];
        X32o[idx] = v;
        Xbfo[idx] = f2bf(v);
    }
}

// ---------------- power GEMM: acc = L @ X, M += coef*acc, Xout = bf16(acc) ---------------
__global__ __launch_bounds__(256) void k_gemm_pow(const unsigned short* __restrict__ L,
                                                  const unsigned short* __restrict__ X,
                                                  float* __restrict__ M,
                                                  unsigned short* __restrict__ Xout,
                                                  float coef) {
    __shared__ __align__(16) unsigned short Al[64 * 40];
    __shared__ __align__(16) unsigned short Xt[64 * 40];
    int tid = threadIdx.x, lane = tid & 63, w = tid >> 6;
    int m16 = lane & 15, q = lane >> 4;
    int bx = blockIdx.x;
    int tM = (bx & 31) * 64, tN = (bx >> 5) * 64;
    int ar = tid >> 2, ao = (tid & 3) * 8;
    int xk = tid >> 3, xn = (tid & 7) * 8;
    int qb = xk >> 3;
    v4f acc[4] = {{0,0,0,0},{0,0,0,0},{0,0,0,0},{0,0,0,0}};

    v8s av = *(const v8s*)(L + (size_t)(tM + ar) * SD + ao);
    v8s xv = *(const v8s*)(X + (size_t)xk * SD + tN + xn);
    for (int k0 = 0; k0 < SD; k0 += 32) {
        *(v8s*)(Al + ar * 40 + ao) = av;
#pragma unroll
        for (int c = 0; c < 8; ++c) {
            int n = xn + c, sw = (n >> 3) & 3;
            Xt[n * 40 + (((qb ^ sw) << 3) | (xk & 7))] = xv[c];
        }
        __syncthreads();
        if (k0 + 32 < SD) {
            av = *(const v8s*)(L + (size_t)(tM + ar) * SD + (k0 + 32) + ao);
            xv = *(const v8s*)(X + (size_t)(k0 + 32 + xk) * SD + tN + xn);
        }
        v8s a = *(const v8s*)(Al + (w * 16 + m16) * 40 + q * 8);
#pragma unroll
        for (int c = 0; c < 4; ++c) {
            int nl = c * 16 + m16, swn = (nl >> 3) & 3;
            v8s b = *(const v8s*)(Xt + nl * 40 + ((q ^ swn) << 3));
            acc[c] = __builtin_amdgcn_mfma_f32_16x16x32_bf16(a, b, acc[c], 0, 0, 0);
        }
        __syncthreads();
    }
#pragma unroll
    for (int c = 0; c < 4; ++c) {
#pragma unroll
        for (int j = 0; j < 4; ++j) {
            int r = tM + w * 16 + q * 4 + j;
            int col = tN + c * 16 + m16;
            size_t idx = (size_t)r * SD + col;
            float v = acc[c][j];
            M[idx] += coef * v;
            Xout[idx] = f2bf(v);
        }
    }
}

// ---------------- squaring GEMM: M' = 2a*M + Mbf@Mbf (fp32 in-place, bf16 out) -----------
__global__ __launch_bounds__(256) void k_gemm_sq(const unsigned short* __restrict__ Lbf,
                                                 float* __restrict__ M32,
                                                 unsigned short* __restrict__ Mbfo,
                                                 float twoa) {
    __shared__ __align__(16) unsigned short Al[64 * 40];
    __shared__ __align__(16) unsigned short Xt[64 * 40];
    int tid = threadIdx.x, lane = tid & 63, w = tid >> 6;
    int m16 = lane & 15, q = lane >> 4;
    int bx = blockIdx.x;
    int tM = (bx & 31) * 64, tN = (bx >> 5) * 64;
    int ar = tid >> 2, ao = (tid & 3) * 8;
    int xk = tid >> 3, xn = (tid & 7) * 8;
    int qb = xk >> 3;
    v4f acc[4] = {{0,0,0,0},{0,0,0,0},{0,0,0,0},{0,0,0,0}};

    v8s av = *(const v8s*)(Lbf + (size_t)(tM + ar) * SD + ao);
    v8s xv = *(const v8s*)(Lbf + (size_t)xk * SD + tN + xn);
    for (int k0 = 0; k0 < SD; k0 += 32) {
        *(v8s*)(Al + ar * 40 + ao) = av;
#pragma unroll
        for (int c = 0; c < 8; ++c) {
            int n = xn + c, sw = (n >> 3) & 3;
            Xt[n * 40 + (((qb ^ sw) << 3) | (xk & 7))] = xv[c];
        }
        __syncthreads();
        if (k0 + 32 < SD) {
            av = *(const v8s*)(Lbf + (size_t)(tM + ar) * SD + (k0 + 32) + ao);
            xv = *(const v8s*)(Lbf + (size_t)(k0 + 32 + xk) * SD + tN + xn);
        }
        v8s a = *(const v8s*)(Al + (w * 16 + m16) * 40 + q * 8);
#pragma unroll
        for (int c = 0; c < 4; ++c) {
            int nl = c * 16 + m16, swn = (nl >> 3) & 3;
            v8s b = *(const v8s*)(Xt + nl * 40 + ((q ^ swn) << 3));
            acc[c] = __builtin_amdgcn_mfma_f32_16x16x32_bf16(a, b, acc[c], 0, 0, 0);
        }
        __syncthreads();
    }
#pragma unroll
    for (int c = 0; c < 4; ++c) {
#pragma unroll
        for (int j = 0; j < 4; ++j) {
            int r = tM + w * 16 + q * 4 + j;
            int col = tN + c * 16 + m16;
            size_t idx = (size_t)r * SD + col;
            float v = twoa * M32[idx] + acc[c][j];   // in-place safe: owner-only RMW
            M32[idx] = v;
            Mbfo[idx] = f2bf(v);
        }
    }
}

// ---------------- scan init: X[:,0]=s0, X[:,k]=u_{k-1}; zero 16-col pads of BOTH bf bufs --
__global__ __launch_bounds__(256) void k_scan_init(const float* __restrict__ s0,
                                                   const float* __restrict__ U,
                                                   float* __restrict__ S32,
                                                   unsigned short* __restrict__ Sbf0,
                                                   unsigned short* __restrict__ Sbf1) {
    int idx = blockIdx.x * 256 + threadIdx.x;     // 0 .. SD*KBP-1
    int d = idx / KBP, c = idx - d * KBP;
    if (c < 16) { Sbf0[idx] = 0; Sbf1[idx] = 0; return; }
    int k = c - 16;
    float v = (k == 0) ? s0[d] : U[(size_t)d * KB + (k - 1)];
    S32[(size_t)d * KB + k] = v;
    Sbf0[idx] = f2bf(v);
}

// ---------------- scan round: S'[:,k] = S[:,k] + a*S[:,k-sh] + Mr@S[:,k-sh] --------------
__global__ __launch_bounds__(256) void k_scan(const unsigned short* __restrict__ Mrbf,
                                              const unsigned short* __restrict__ Sbf_in,
                                              const float* __restrict__ S32_in,
                                              float* __restrict__ S32_out,
                                              unsigned short* __restrict__ Sbf_out,
                                              float ar, int shift) {
    __shared__ __align__(16) unsigned short Al[32 * 72];
    __shared__ __align__(16) unsigned short Xt[32 * 72];
    int bx = blockIdx.x;
    int tM = (bx & 63) * 32, tN = (bx >> 6) * 32;
    int tid = threadIdx.x, lane = tid & 63, w = tid >> 6;
    int m16 = lane & 15, q = lane >> 4;
    int ar_ = tid >> 3, ao = (tid & 7) * 8;
    int xk = tid >> 2, xn = (tid & 3) * 8;
    int qb = xk >> 3;
    int coff = tN + xn + 16 - shift;               // >= 0 since shift <= 16
    v4f acc = {0, 0, 0, 0};
    v8s av = *(const v8s*)(Mrbf + (size_t)(tM + ar_) * SD + ao);
    v8s xv = *(const v8s*)(Sbf_in + (size_t)xk * KBP + coff);
    int nl = (w & 1) * 16 + m16;
    int swn = (nl >> 3) & 3;
    int rl = (w >> 1) * 16 + m16;
    for (int k0 = 0; k0 < SD; k0 += 64) {
        *(v8s*)(Al + ar_ * 72 + ao) = av;
#pragma unroll
        for (int c = 0; c < 8; ++c) {
            int n = xn + c, sw = (n >> 3) & 3;
            Xt[n * 72 + (((qb ^ sw) << 3) | (xk & 7))] = xv[c];
        }
        __syncthreads();
        if (k0 + 64 < SD) {
            av = *(const v8s*)(Mrbf + (size_t)(tM + ar_) * SD + (k0 + 64) + ao);
            xv = *(const v8s*)(Sbf_in + (size_t)(k0 + 64 + xk) * KBP + coff);
        }
#pragma unroll
        for (int ch = 0; ch < 2; ++ch) {
            v8s a = *(const v8s*)(Al + rl * 72 + ch * 32 + q * 8);
            int q2 = ch * 4 + q;
            v8s b = *(const v8s*)(Xt + nl * 72 + ((q2 ^ swn) << 3));
            acc = __builtin_amdgcn_mfma_f32_16x16x32_bf16(a, b, acc, 0, 0, 0);
        }
        __syncthreads();
    }
#pragma unroll
    for (int j = 0; j < 4; ++j) {
        int r = tM + (w >> 1) * 16 + q * 4 + j;
        int kc = tN + (w & 1) * 16 + m16;
        int idx = r * KB + kc;
        int ksh = kc - shift;
        float v = S32_in[idx] + acc[j] + (ksh >= 0 ? ar * S32_in[r * KB + ksh] : 0.f);
        S32_out[idx] = v;
        Sbf_out[(size_t)r * KBP + kc + 16] = f2bf(v);
    }
}

// ---------------- generic 512-row GEMM: out = A(512x2048) @ B(2048xN, row stride ldb) ----
__global__ __launch_bounds__(256) void k_gemm2(const unsigned short* __restrict__ A,
                                               const unsigned short* __restrict__ B,
                                               int ldb,
                                               unsigned short* __restrict__ obf,
                                               float* __restrict__ o32,
                                               int ldo, int accum) {
    __shared__ __align__(16) unsigned short Al[64 * 40];
    __shared__ __align__(16) unsigned short Xt[64 * 40];
    int tid = threadIdx.x, lane = tid & 63, w = tid >> 6;
    int m16 = lane & 15, q = lane >> 4;
    int bx = blockIdx.x;
    int tM = (bx & 7) * 64, tN = (bx >> 3) * 64;
    A += (size_t)blockIdx.y * OD * SD;
    if (o32) o32 += (size_t)blockIdx.y * OD * ldo;
    int ar = tid >> 2, ao = (tid & 3) * 8;
    int xk = tid >> 3, xn = (tid & 7) * 8;
    int qb = xk >> 3;
    v4f acc[4] = {{0,0,0,0},{0,0,0,0},{0,0,0,0},{0,0,0,0}};

    v8s av = *(const v8s*)(A + (size_t)(tM + ar) * SD + ao);
    v8s xv = *(const v8s*)(B + (size_t)xk * ldb + tN + xn);
    for (int k0 = 0; k0 < SD; k0 += 32) {
        *(v8s*)(Al + ar * 40 + ao) = av;
#pragma unroll
        for (int c = 0; c < 8; ++c) {
            int n = xn + c, sw = (n >> 3) & 3;
            Xt[n * 40 + (((qb ^ sw) << 3) | (xk & 7))] = xv[c];
        }
        __syncthreads();
        if (k0 + 32 < SD) {
            av = *(const v8s*)(A + (size_t)(tM + ar) * SD + (k0 + 32) + ao);
            xv = *(const v8s*)(B + (size_t)(k0 + 32 + xk) * ldb + tN + xn);
        }
        v8s a = *(const v8s*)(Al + (w * 16 + m16) * 40 + q * 8);
#pragma unroll
        for (int c = 0; c < 4; ++c) {
            int nl = c * 16 + m16, swn = (nl >> 3) & 3;
            v8s b = *(const v8s*)(Xt + nl * 40 + ((q ^ swn) << 3));
            acc[c] = __builtin_amdgcn_mfma_f32_16x16x32_bf16(a, b, acc[c], 0, 0, 0);
        }
        __syncthreads();
    }
#pragma unroll
    for (int c = 0; c < 4; ++c) {
#pragma unroll
        for (int j = 0; j < 4; ++j) {
            int r = tM + w * 16 + q * 4 + j;
            int col = tN + c * 16 + m16;
            float v = acc[c][j];
            if (o32) {
                size_t idx = (size_t)r * ldo + col;
                if (accum) o32[idx] += v; else o32[idx] = v;
            }
            if (obf) obf[(size_t)r * ldo + col] = f2bf(v);
        }
    }
}

// ---------------- noise prefix weights: Zbf[d][64k+i] = sum_j T[j][i]*pn[(64k+j),d] ------
__global__ __launch_bounds__(256) void k_applyT(const float* __restrict__ pn,
                                                const float* __restrict__ Tp,
                                                unsigned short* __restrict__ Zbf) {
    __shared__ float pt[64][64];
    int bx = blockIdx.x;                 // 4096 = 128 k * 32 d-chunks(64)
    int k = bx >> 5, dc = bx & 31;
    int d0 = dc * 64;
    int tid = threadIdx.x, il = tid & 63, dg = tid >> 6;
#pragma unroll
    for (int r = 0; r < 16; ++r) {
        int j = r * 4 + dg;
        pt[j][il] = pn[(size_t)(k * BLK + j) * SD + d0 + il];
    }
    __syncthreads();
    float z[16];
#pragma unroll
    for (int u = 0; u < 16; ++u) z[u] = 0.f;
    for (int j = 0; j < 63; ++j) {       // T[j][i]==0 for j>=i; j=63 row all-zero
        float tv = Tp[j * 64 + il];
#pragma unroll
        for (int u = 0; u < 16; ++u) z[u] += tv * pt[j][dg * 16 + u];
    }
#pragma unroll
    for (int u = 0; u < 16; ++u)
        Zbf[(size_t)(d0 + dg * 16 + u) * NT + k * BLK + il] = f2bf(z[u]);
}

// ---------------- final: out[t][o] = OBSn[o][t] + sum_p cW[p][i]*H[p][o][k] + sig*on ----
__global__ __launch_bounds__(256) void k_final(const float* __restrict__ OBSn,
                                               const float* __restrict__ H,
                                               const float* __restrict__ cW,
                                               const float* __restrict__ on,
                                               float* __restrict__ out) {
    __shared__ float tile[64][65];
    int bx = blockIdx.x;                 // 1024 = 128 t-tiles * 8 o-tiles
    int tkb = bx >> 3, ob = bx & 7;
    int t0 = tkb * 64, o0 = ob * 64;
    int tid = threadIdx.x, lane = tid & 63, g = tid >> 6;
#pragma unroll
    for (int r = 0; r < 16; ++r) {
        int oo = r * 4 + g;
        tile[oo][lane] = OBSn[(size_t)(o0 + oo) * NT + t0 + lane];
    }
    float Hv[NPH];
#pragma unroll
    for (int p = 0; p < NPH; ++p)
        Hv[p] = H[((size_t)p * OD + o0 + lane) * KB + tkb];
    __syncthreads();
#pragma unroll
    for (int r = 0; r < 16; ++r) {
        int trow = r * 4 + g;            // i within block
        float acc = tile[lane][trow];
#pragma unroll
        for (int p = 0; p < NPH; ++p) acc += cW[p * 64 + trow] * Hv[p];
        size_t oidx = (size_t)(t0 + trow) * OD + o0 + lane;
        out[oidx] = acc + OBS_STD * on[oidx];
    }
}

// ---------------- host ----------------
extern "C" void kernel_launch(void* const* d_in, const int* in_sizes, int n_in,
                              void* d_out, int out_size, void* d_ws, size_t ws_size,
                              hipStream_t stream) {
    const float* s0 = (const float*)d_in[0];
    const float* A  = (const float*)d_in[1];
    const float* C  = (const float*)d_in[2];
    const float* pn = (const float*)d_in[3];
    const float* on = (const float*)d_in[4];
    float* out = (float*)d_out;

    char* p = (char*)d_ws;
    auto take = [&](size_t n) { char* r = p; p += (n + 255) & ~(size_t)255; return r; };
    unsigned short* Ebf   = (unsigned short*)take((size_t)SD * SD * 2);
    unsigned short* CEall = (unsigned short*)take((size_t)NPH * OD * SD * 2);  // CE_0..CE_5
    // M, Xp0, Xp1 contiguous (33.55 MB); dead after scan -> reused as Zbf in pass 3
    float* M            = (float*)take((size_t)SD * SD * 4);
    unsigned short* Xp0 = (unsigned short*)take((size_t)SD * SD * 2);
    unsigned short* Xp1 = (unsigned short*)take((size_t)SD * SD * 2);
    unsigned short* Zbf = (unsigned short*)M;                 // SD*NT*2 == 33,554,432 B
    float* W      = (float*)take((size_t)6 * SD * KB * 4);
    float* V32[2] = {(float*)take((size_t)SD * KB * 4), (float*)take((size_t)SD * KB * 4)};
    unsigned short* Vbf[2] = {(unsigned short*)take((size_t)SD * KB * 2),
                              (unsigned short*)take((size_t)SD * KB * 2)};
    float* SC32[2] = {(float*)take((size_t)SD * KB * 4), (float*)take((size_t)SD * KB * 4)};
    unsigned short* SCbf[2] = {(unsigned short*)take((size_t)SD * KBP * 2),
                               (unsigned short*)take((size_t)SD * KBP * 2)};
    float* wW   = (float*)take((size_t)NP * 64 * 4);
    float* cW   = (float*)take((size_t)NP * 64 * 4);
    float* wT   = (float*)take((size_t)NP * 64 * 64 * 4);
    float* OBSn = (float*)take((size_t)OD * NT * 4);
    float* H    = (float*)take((size_t)NPH * OD * KB * 4);

    // A^64 = 0.99^64 I + sum_{m=1..6} C(64,m) 0.99^(64-m) E^m   (tail ~2e-6)
    double pw[65]; pw[0] = 1.0;
    for (int m = 1; m <= 64; ++m) pw[m] = pw[m - 1] * 0.99;
    const double bin[7] = {1, 64, 2016, 41664, 635376, 7624512, 74974368};
    float cf[7];
    for (int m = 1; m <= 6; ++m) cf[m] = (float)(bin[m] * pw[64 - m]);
    float a64 = (float)pw[64];

    k_weights2<<<NP * 64 * 64 / 256, 256, 0, stream>>>(wW, cW, wT);
    k_prep_A<<<SD * SD / 256, 256, 0, stream>>>(A, Ebf, M, cf[1]);
    k_prep_C<<<OD * SD / 256, 256, 0, stream>>>(C, CEall);    // CE_0 = bf16(C)

    // powers E^2..E^6 (bf16 MFMA), accumulate into M = A64 - a64*I
    k_gemm_pow<<<1024, 256, 0, stream>>>(Ebf, Ebf, M, Xp0, cf[2]);
    k_gemm_pow<<<1024, 256, 0, stream>>>(Ebf, Xp0, M, Xp1, cf[3]);
    k_gemm_pow<<<1024, 256, 0, stream>>>(Ebf, Xp1, M, Xp0, cf[4]);
    k_gemm_pow<<<1024, 256, 0, stream>>>(Ebf, Xp0, M, Xp1, cf[5]);
    k_gemm_pow<<<1024, 256, 0, stream>>>(Ebf, Xp1, M, Xp0, cf[6]);

    // pass 1: u_k = sum_p E^p W_p via Horner (V init = W_6)
    k_wsum<<<1024, 256, 0, stream>>>(pn, wW, W, V32[0], Vbf[0]);
    int cur = 0;
    for (int pp = 5; pp >= 0; --pp) {
        k_horner<<<256, 256, 0, stream>>>(Ebf, Vbf[cur], W + (size_t)pp * SD * KB,
                                          V32[cur ^ 1], Vbf[cur ^ 1]);
        cur ^= 1;
    }  // cur == 0: V32[0] = u_k in [d][k]

    // pass 2: boundary states via 5-round matrix scan (shifts 1,2,4,8,16; A64^32 ~ 1e-9)
    k_scan_init<<<SD * KBP / 256, 256, 0, stream>>>(s0, V32[cur], SC32[0], SCbf[0], SCbf[1]);
    k_castM<<<SD * SD / 256, 256, 0, stream>>>(M, Xp1);       // M_0 bf16 (Xp1 dead)
    unsigned short* MbfA = Xp1;
    unsigned short* MbfB = Xp0;
    float a = a64;
    int sc = 0;
    for (int r = 0; r < 5; ++r) {
        k_scan<<<256, 256, 0, stream>>>(MbfA, SCbf[sc], SC32[sc],
                                        SC32[sc ^ 1], SCbf[sc ^ 1], a, 1 << r);
        sc ^= 1;
        if (r < 4) {
            k_gemm_sq<<<1024, 256, 0, stream>>>(MbfA, M, MbfB, 2.f * a);
            unsigned short* t = MbfA; MbfA = MbfB; MbfB = t;
            a = a * a;
        }
    }  // SC32[sc] = s_k boundary states [d][k]; SCbf[sc] padded bf16

    // pass 3: polynomial observation assembly
    // CE_p = CE_{p-1} @ E
    for (int pp = 1; pp < NPH; ++pp)
        k_gemm2<<<dim3(256, 1), 256, 0, stream>>>(CEall + (size_t)(pp - 1) * OD * SD, Ebf, SD,
                                                  CEall + (size_t)pp * OD * SD,
                                                  (float*)nullptr, SD, 0);
    // H[p] = CE_p @ S_bound  (batched over p; B = padded scan output + 16-col offset)
    k_gemm2<<<dim3(16, NPH), 256, 0, stream>>>(CEall, SCbf[sc] + 16, KBP,
                                               (unsigned short*)nullptr, H, KB, 0);
    // OBSn = sum_p CE_p @ Z_p   (Z_p regenerated per p into aliased M/Xp region)
    for (int pp = 0; pp < NPN; ++pp) {
        k_applyT<<<4096, 256, 0, stream>>>(pn, wT + (size_t)pp * 4096, Zbf);
        k_gemm2<<<dim3(1024, 1), 256, 0, stream>>>(CEall + (size_t)pp * OD * SD, Zbf, NT,
                                                   (unsigned short*)nullptr, OBSn, NT, pp ? 1 : 0);
    }
    k_final<<<1024, 256, 0, stream>>>(OBSn, H, cW, on, out);
}

// Round 4
// 1173.002 us; speedup vs baseline: 4.1611x; 1.2948x over previous
//
#include <hip/hip_runtime.h>

// SimpleStateSpaceModel restructure v5:
//   v4 profile: 5 big k_gemm2 (64us, 31% HBM, 140MB fetch) + 5 applyT (~90us) + 9 full
//   2048^3 GEMMs (~450us).
//   (1) noise path commuted: CE_p@Z_p = (CE_p@pn^T)*T_p -> ONE GEMM Pall=CEcat@pnT
//       (pnT emitted free inside k_wsum) + K=320 MFMA transform fused into k_final2.
//   (2) E-powers: 5 GEMMs -> 3 (E2, E3, E3@(cf4 E+cf5 E2+cf6 E3)); M RMW once, emits Mbf.
//   Pall aliases dead M/Xp region exactly (41,943,040 B); Mbf reuses dead Ebf.
// Next-round candidate: 128^2-tile GEMM core for gemmNN/gemm_sq/gemmP.

#define SD 2048      // state dim
#define OD 512       // obs dim
#define NT 8192      // steps
#define BLK 64       // steps per block
#define KB 128       // number of blocks = NT/BLK
#define KBP (KB+16)  // padded column stride for scan bf16 buffers (16 zero cols in front)
#define NP 7         // binomial terms p=0..6 (pass1 / M)
#define NPH 6        // homogeneous obs terms p=0..5
#define NPN 5        // noise obs terms p=0..4
#define PROC_STD 0.31622776601683794f
#define OBS_STD  0.7071067811865476f

typedef __attribute__((ext_vector_type(8))) short v8s;
typedef __attribute__((ext_vector_type(4))) float v4f;

__device__ __forceinline__ unsigned short f2bf(float f) {
    union { float f; unsigned int u; } v; v.f = f;
    unsigned int r = v.u + 0x7fffu + ((v.u >> 16) & 1u);
    return (unsigned short)(r >> 16);
}
__device__ __forceinline__ float bf2f(unsigned short u) {
    union { unsigned int ui; float f; } cv; cv.ui = (unsigned int)u << 16;
    return cv.f;
}

// ---------------- weights (device-computed, double precision, grid-parallel) -------------
__device__ double d_binom(int m, int p) {
    if (p < 0 || p > m) return 0.0;
    double c = 1.0;
    for (int q = 1; q <= p; ++q) c = c * (double)(m - p + q) / (double)q;
    return c;
}
__device__ double d_p99(int n) {
    double r = 1.0;
    for (int q = 0; q < n; ++q) r *= 0.99;
    return r;
}
// wW[p][j] = sigma*C(63-j,p)*0.99^(63-j-p)        (pass1 reduction weights)
// cW[p][i] = C(i,p)*0.99^(i-p)                    (homogeneous obs coeffs)
// Tbf[p][j][i] = bf16(sigma*C(i-1-j,p)*0.99^(i-1-j-p))  (noise prefix weights)
__global__ __launch_bounds__(256) void k_weights2(float* __restrict__ wW,
                                                  float* __restrict__ cW,
                                                  unsigned short* __restrict__ Tbf) {
    int idx = blockIdx.x * 256 + threadIdx.x;     // 0 .. NP*64*64-1
    if (idx < NP * 64) {
        int p = idx >> 6, j = idx & 63;
        int m = 63 - j;
        wW[idx] = (p <= m) ? (float)((double)PROC_STD * d_binom(m, p) * d_p99(m - p)) : 0.f;
        cW[idx] = (p <= j) ? (float)(d_binom(j, p) * d_p99(j - p)) : 0.f;
    }
    if (idx < NP * 64 * 64) {
        int p = idx >> 12, j = (idx >> 6) & 63, i = idx & 63;
        int mm = i - 1 - j;
        float t = (mm >= p) ? (float)((double)PROC_STD * d_binom(mm, p) * d_p99(mm - p)) : 0.f;
        Tbf[idx] = f2bf(t);
    }
}

// ---------------- prep kernels ----------------
__global__ __launch_bounds__(256) void k_prep_A(const float* __restrict__ A,
                                                unsigned short* __restrict__ Ebf,
                                                float* __restrict__ M, float c1) {
    int idx = blockIdx.x * 256 + threadIdx.x;
    int r = idx >> 11, c = idx & 2047;
    float e = A[idx] - (r == c ? 0.99f : 0.0f);
    Ebf[idx] = f2bf(e);
    M[idx] = c1 * e;
}

__global__ __launch_bounds__(256) void k_prep_C(const float* __restrict__ C,
                                                unsigned short* __restrict__ Cbf) {
    int idx = blockIdx.x * 256 + threadIdx.x;
    Cbf[idx] = f2bf(C[idx]);
}

// P = bf16(cf4*E + cf5*E2 + cf6*E3)
__global__ __launch_bounds__(256) void k_combP(const unsigned short* __restrict__ Ebf,
                                               const unsigned short* __restrict__ E2,
                                               const unsigned short* __restrict__ E3,
                                               unsigned short* __restrict__ P,
                                               float c4, float c5, float c6) {
    int idx = blockIdx.x * 256 + threadIdx.x;
    P[idx] = f2bf(c4 * bf2f(Ebf[idx]) + c5 * bf2f(E2[idx]) + c6 * bf2f(E3[idx]));
}

// ---------------- pass1 reduction + pnT emission -----------------------------------------
// W_p[d][k] = sum_j wW[p][j]*pn[(k*64+j),d]; p=0..5 -> W, p=6 -> V32/Vbf (Horner init)
// pnT[d][64k+j] = bf16(pn[(k*64+j),d])
__global__ __launch_bounds__(256) void k_wsum(const float* __restrict__ pn,
                                              const float* __restrict__ wW,
                                              float* __restrict__ W,
                                              float* __restrict__ V32,
                                              unsigned short* __restrict__ Vbf,
                                              unsigned short* __restrict__ pnT) {
    __shared__ float ws[NP * 64];
    int tid = threadIdx.x;
    for (int t = tid; t < NP * 64; t += 256) ws[t] = wW[t];
    __syncthreads();
    int bx = blockIdx.x;                 // 1024 = 128 k * 8 d-chunks
    int k = bx >> 3, dc = bx & 7;
    int d = dc * 256 + tid;
    float acc[NP];
#pragma unroll
    for (int p = 0; p < NP; ++p) acc[p] = 0.f;
    v8s pv;
#pragma unroll
    for (int j = 0; j < 64; ++j) {
        float v = pn[(size_t)(k * BLK + j) * SD + d];
        pv[j & 7] = (short)f2bf(v);
        if ((j & 7) == 7)
            *(v8s*)(pnT + (size_t)d * NT + k * BLK + (j & ~7)) = pv;
#pragma unroll
        for (int p = 0; p < NP; ++p) acc[p] += ws[p * 64 + j] * v;
    }
#pragma unroll
    for (int p = 0; p < 6; ++p) W[((size_t)p * SD + d) * KB + k] = acc[p];
    V32[(size_t)d * KB + k] = acc[6];
    Vbf[(size_t)d * KB + k] = f2bf(acc[6]);
}

// ---------------- Horner step: V' = E @ V + W_p   (2048 x 128, K=2048) ----------------
__global__ __launch_bounds__(256) void k_horner(const unsigned short* __restrict__ Ebf,
                                                const unsigned short* __restrict__ Xbf,
                                                const float* __restrict__ Wp,
                                                float* __restrict__ X32o,
                                                unsigned short* __restrict__ Xbfo) {
    __shared__ __align__(16) unsigned short Al[32 * 72];
    __shared__ __align__(16) unsigned short Xt[32 * 72];
    int bx = blockIdx.x;
    int tM = (bx & 63) * 32, tN = (bx >> 6) * 32;
    int tid = threadIdx.x, lane = tid & 63, w = tid >> 6;
    int m16 = lane & 15, q = lane >> 4;
    int ar = tid >> 3, ao = (tid & 7) * 8;
    int xk = tid >> 2, xn = (tid & 3) * 8;
    int qb = xk >> 3;
    v4f acc = {0, 0, 0, 0};
    v8s av = *(const v8s*)(Ebf + (size_t)(tM + ar) * SD + ao);
    v8s xv = *(const v8s*)(Xbf + (size_t)xk * KB + tN + xn);
    int nl = (w & 1) * 16 + m16;
    int swn = (nl >> 3) & 3;
    int rl = (w >> 1) * 16 + m16;
    for (int k0 = 0; k0 < SD; k0 += 64) {
        *(v8s*)(Al + ar * 72 + ao) = av;
#pragma unroll
        for (int c = 0; c < 8; ++c) {
            int n = xn + c, sw = (n >> 3) & 3;
            Xt[n * 72 + (((qb ^ sw) << 3) | (xk & 7))] = xv[c];
        }
        __syncthreads();
        if (k0 + 64 < SD) {
            av = *(const v8s*)(Ebf + (size_t)(tM + ar) * SD + (k0 + 64) + ao);
            xv = *(const v8s*)(Xbf + (size_t)(k0 + 64 + xk) * KB + tN + xn);
        }
#pragma unroll
        for (int ch = 0; ch < 2; ++ch) {
            v8s a = *(const v8s*)(Al + rl * 72 + ch * 32 + q * 8);
            int q2 = ch * 4 + q;
            v8s b = *(const v8s*)(Xt + nl * 72 + ((q2 ^ swn) << 3));
            acc = __builtin_amdgcn_mfma_f32_16x16x32_bf16(a, b, acc, 0, 0, 0);
        }
        __syncthreads();
    }
#pragma unroll
    for (int j = 0; j < 4; ++j) {
        int r = tM + (w >> 1) * 16 + q * 4 + j;
        int kc = tN + (w & 1) * 16 + m16;
        int idx = r * KB + kc;
        float v = acc[j] + Wp[idx];
        X32o[idx] = v;
        Xbfo[idx] = f2bf(v);
    }
}

// ---------------- plain NN GEMM (2048^3): out = bf16(A @ B) ------------------------------
__global__ __launch_bounds__(256) void k_gemmNN(const unsigned short* __restrict__ L,
                                                const unsigned short* __restrict__ X,
                                                unsigned short* __restrict__ Xout) {
    __shared__ __align__(16) unsigned short Al[64 * 40];
    __shared__ __align__(16) unsigned short Xt[64 * 40];
    int tid = threadIdx.x, lane = tid & 63, w = tid >> 6;
    int m16 = lane & 15, q = lane >> 4;
    int bx = blockIdx.x;
    int tM = (bx & 31) * 64, tN = (bx >> 5) * 64;
    int ar = tid >> 2, ao = (tid & 3) * 8;
    int xk = tid >> 3, xn = (tid & 7) * 8;
    int qb = xk >> 3;
    v4f acc[4] = {{0,0,0,0},{0,0,0,0},{0,0,0,0},{0,0,0,0}};

    v8s av = *(const v8s*)(L + (size_t)(tM + ar) * SD + ao);
    v8s xv = *(const v8s*)(X + (size_t)xk * SD + tN + xn);
    for (int k0 = 0; k0 < SD; k0 += 32) {
        *(v8s*)(Al + ar * 40 + ao) = av;
#pragma unroll
        for (int c = 0; c < 8; ++c) {
            int n = xn + c, sw = (n >> 3) & 3;
            Xt[n * 40 + (((qb ^ sw) << 3) | (xk & 7))] = xv[c];
        }
        __syncthreads();
        if (k0 + 32 < SD) {
            av = *(const v8s*)(L + (size_t)(tM + ar) * SD + (k0 + 32) + ao);
            xv = *(const v8s*)(X + (size_t)(k0 + 32 + xk) * SD + tN + xn);
        }
        v8s a = *(const v8s*)(Al + (w * 16 + m16) * 40 + q * 8);
#pragma unroll
        for (int c = 0; c < 4; ++c) {
            int nl = c * 16 + m16, swn = (nl >> 3) & 3;
            v8s b = *(const v8s*)(Xt + nl * 40 + ((q ^ swn) << 3));
            acc[c] = __builtin_amdgcn_mfma_f32_16x16x32_bf16(a, b, acc[c], 0, 0, 0);
        }
        __syncthreads();
    }
#pragma unroll
    for (int c = 0; c < 4; ++c) {
#pragma unroll
        for (int j = 0; j < 4; ++j) {
            int r = tM + w * 16 + q * 4 + j;
            int col = tN + c * 16 + m16;
            Xout[(size_t)r * SD + col] = f2bf(acc[c][j]);
        }
    }
}

// ---------------- M GEMM: M = (cf1 E in M32) + cf2 E2 + cf3 E3 + E3@P; Mbf = bf16(M) -----
__global__ __launch_bounds__(256) void k_gemm_M(const unsigned short* __restrict__ E3,
                                                const unsigned short* __restrict__ P,
                                                float* __restrict__ M32,
                                                const unsigned short* __restrict__ E2,
                                                unsigned short* __restrict__ Mbf,
                                                float c2, float c3) {
    __shared__ __align__(16) unsigned short Al[64 * 40];
    __shared__ __align__(16) unsigned short Xt[64 * 40];
    int tid = threadIdx.x, lane = tid & 63, w = tid >> 6;
    int m16 = lane & 15, q = lane >> 4;
    int bx = blockIdx.x;
    int tM = (bx & 31) * 64, tN = (bx >> 5) * 64;
    int ar = tid >> 2, ao = (tid & 3) * 8;
    int xk = tid >> 3, xn = (tid & 7) * 8;
    int qb = xk >> 3;
    v4f acc[4] = {{0,0,0,0},{0,0,0,0},{0,0,0,0},{0,0,0,0}};

    v8s av = *(const v8s*)(E3 + (size_t)(tM + ar) * SD + ao);
    v8s xv = *(const v8s*)(P + (size_t)xk * SD + tN + xn);
    for (int k0 = 0; k0 < SD; k0 += 32) {
        *(v8s*)(Al + ar * 40 + ao) = av;
#pragma unroll
        for (int c = 0; c < 8; ++c) {
            int n = xn + c, sw = (n >> 3) & 3;
            Xt[n * 40 + (((qb ^ sw) << 3) | (xk & 7))] = xv[c];
        }
        __syncthreads();
        if (k0 + 32 < SD) {
            av = *(const v8s*)(E3 + (size_t)(tM + ar) * SD + (k0 + 32) + ao);
            xv = *(const v8s*)(P + (size_t)(k0 + 32 + xk) * SD + tN + xn);
        }
        v8s a = *(const v8s*)(Al + (w * 16 + m16) * 40 + q * 8);
#pragma unroll
        for (int c = 0; c < 4; ++c) {
            int nl = c * 16 + m16, swn = (nl >> 3) & 3;
            v8s b = *(const v8s*)(Xt + nl * 40 + ((q ^ swn) << 3));
            acc[c] = __builtin_amdgcn_mfma_f32_16x16x32_bf16(a, b, acc[c], 0, 0, 0);
        }
        __syncthreads();
    }
#pragma unroll
    for (int c = 0; c < 4; ++c) {
#pragma unroll
        for (int j = 0; j < 4; ++j) {
            int r = tM + w * 16 + q * 4 + j;
            int col = tN + c * 16 + m16;
            size_t idx = (size_t)r * SD + col;
            float v = M32[idx] + c2 * bf2f(E2[idx]) + c3 * bf2f(E3[idx]) + acc[c][j];
            M32[idx] = v;
            Mbf[idx] = f2bf(v);
        }
    }
}

// ---------------- squaring GEMM: M' = 2a*M + Mbf@Mbf (fp32 in-place, bf16 out) -----------
__global__ __launch_bounds__(256) void k_gemm_sq(const unsigned short* __restrict__ Lbf,
                                                 float* __restrict__ M32,
                                                 unsigned short* __restrict__ Mbfo,
                                                 float twoa) {
    __shared__ __align__(16) unsigned short Al[64 * 40];
    __shared__ __align__(16) unsigned short Xt[64 * 40];
    int tid = threadIdx.x, lane = tid & 63, w = tid >> 6;
    int m16 = lane & 15, q = lane >> 4;
    int bx = blockIdx.x;
    int tM = (bx & 31) * 64, tN = (bx >> 5) * 64;
    int ar = tid >> 2, ao = (tid & 3) * 8;
    int xk = tid >> 3, xn = (tid & 7) * 8;
    int qb = xk >> 3;
    v4f acc[4] = {{0,0,0,0},{0,0,0,0},{0,0,0,0},{0,0,0,0}};

    v8s av = *(const v8s*)(Lbf + (size_t)(tM + ar) * SD + ao);
    v8s xv = *(const v8s*)(Lbf + (size_t)xk * SD + tN + xn);
    for (int k0 = 0; k0 < SD; k0 += 32) {
        *(v8s*)(Al + ar * 40 + ao) = av;
#pragma unroll
        for (int c = 0; c < 8; ++c) {
            int n = xn + c, sw = (n >> 3) & 3;
            Xt[n * 40 + (((qb ^ sw) << 3) | (xk & 7))] = xv[c];
        }
        __syncthreads();
        if (k0 + 32 < SD) {
            av = *(const v8s*)(Lbf + (size_t)(tM + ar) * SD + (k0 + 32) + ao);
            xv = *(const v8s*)(Lbf + (size_t)(k0 + 32 + xk) * SD + tN + xn);
        }
        v8s a = *(const v8s*)(Al + (w * 16 + m16) * 40 + q * 8);
#pragma unroll
        for (int c = 0; c < 4; ++c) {
            int nl = c * 16 + m16, swn = (nl >> 3) & 3;
            v8s b = *(const v8s*)(Xt + nl * 40 + ((q ^ swn) << 3));
            acc[c] = __builtin_amdgcn_mfma_f32_16x16x32_bf16(a, b, acc[c], 0, 0, 0);
        }
        __syncthreads();
    }
#pragma unroll
    for (int c = 0; c < 4; ++c) {
#pragma unroll
        for (int j = 0; j < 4; ++j) {
            int r = tM + w * 16 + q * 4 + j;
            int col = tN + c * 16 + m16;
            size_t idx = (size_t)r * SD + col;
            float v = twoa * M32[idx] + acc[c][j];   // in-place safe: owner-only RMW
            M32[idx] = v;
            Mbfo[idx] = f2bf(v);
        }
    }
}

// ---------------- scan init: X[:,0]=s0, X[:,k]=u_{k-1}; zero 16-col pads of BOTH bf bufs --
__global__ __launch_bounds__(256) void k_scan_init(const float* __restrict__ s0,
                                                   const float* __restrict__ U,
                                                   float* __restrict__ S32,
                                                   unsigned short* __restrict__ Sbf0,
                                                   unsigned short* __restrict__ Sbf1) {
    int idx = blockIdx.x * 256 + threadIdx.x;     // 0 .. SD*KBP-1
    int d = idx / KBP, c = idx - d * KBP;
    if (c < 16) { Sbf0[idx] = 0; Sbf1[idx] = 0; return; }
    int k = c - 16;
    float v = (k == 0) ? s0[d] : U[(size_t)d * KB + (k - 1)];
    S32[(size_t)d * KB + k] = v;
    Sbf0[idx] = f2bf(v);
}

// ---------------- scan round: S'[:,k] = S[:,k] + a*S[:,k-sh] + Mr@S[:,k-sh] --------------
__global__ __launch_bounds__(256) void k_scan(const unsigned short* __restrict__ Mrbf,
                                              const unsigned short* __restrict__ Sbf_in,
                                              const float* __restrict__ S32_in,
                                              float* __restrict__ S32_out,
                                              unsigned short* __restrict__ Sbf_out,
                                              float ar, int shift) {
    __shared__ __align__(16) unsigned short Al[32 * 72];
    __shared__ __align__(16) unsigned short Xt[32 * 72];
    int bx = blockIdx.x;
    int tM = (bx & 63) * 32, tN = (bx >> 6) * 32;
    int tid = threadIdx.x, lane = tid & 63, w = tid >> 6;
    int m16 = lane & 15, q = lane >> 4;
    int ar_ = tid >> 3, ao = (tid & 7) * 8;
    int xk = tid >> 2, xn = (tid & 3) * 8;
    int qb = xk >> 3;
    int coff = tN + xn + 16 - shift;               // >= 0 since shift <= 16
    v4f acc = {0, 0, 0, 0};
    v8s av = *(const v8s*)(Mrbf + (size_t)(tM + ar_) * SD + ao);
    v8s xv = *(const v8s*)(Sbf_in + (size_t)xk * KBP + coff);
    int nl = (w & 1) * 16 + m16;
    int swn = (nl >> 3) & 3;
    int rl = (w >> 1) * 16 + m16;
    for (int k0 = 0; k0 < SD; k0 += 64) {
        *(v8s*)(Al + ar_ * 72 + ao) = av;
#pragma unroll
        for (int c = 0; c < 8; ++c) {
            int n = xn + c, sw = (n >> 3) & 3;
            Xt[n * 72 + (((qb ^ sw) << 3) | (xk & 7))] = xv[c];
        }
        __syncthreads();
        if (k0 + 64 < SD) {
            av = *(const v8s*)(Mrbf + (size_t)(tM + ar_) * SD + (k0 + 64) + ao);
            xv = *(const v8s*)(Sbf_in + (size_t)(k0 + 64 + xk) * KBP + coff);
        }
#pragma unroll
        for (int ch = 0; ch < 2; ++ch) {
            v8s a = *(const v8s*)(Al + rl * 72 + ch * 32 + q * 8);
            int q2 = ch * 4 + q;
            v8s b = *(const v8s*)(Xt + nl * 72 + ((q2 ^ swn) << 3));
            acc = __builtin_amdgcn_mfma_f32_16x16x32_bf16(a, b, acc, 0, 0, 0);
        }
        __syncthreads();
    }
#pragma unroll
    for (int j = 0; j < 4; ++j) {
        int r = tM + (w >> 1) * 16 + q * 4 + j;
        int kc = tN + (w & 1) * 16 + m16;
        int idx = r * KB + kc;
        int ksh = kc - shift;
        float v = S32_in[idx] + acc[j] + (ksh >= 0 ? ar * S32_in[r * KB + ksh] : 0.f);
        S32_out[idx] = v;
        Sbf_out[(size_t)r * KBP + kc + 16] = f2bf(v);
    }
}

// ---------------- generic 512-row GEMM: out = A(512x2048) @ B(2048xN, row stride ldb) ----
// (CE chain, grid(256,1), obf; and H = CE_p @ S_bound, grid(16,NPH), o32)
__global__ __launch_bounds__(256) void k_gemm2(const unsigned short* __restrict__ A,
                                               const unsigned short* __restrict__ B,
                                               int ldb,
                                               unsigned short* __restrict__ obf,
                                               float* __restrict__ o32,
                                               int ldo, int accum) {
    __shared__ __align__(16) unsigned short Al[64 * 40];
    __shared__ __align__(16) unsigned short Xt[64 * 40];
    int tid = threadIdx.x, lane = tid & 63, w = tid >> 6;
    int m16 = lane & 15, q = lane >> 4;
    int bx = blockIdx.x;
    int tM = (bx & 7) * 64, tN = (bx >> 3) * 64;
    A += (size_t)blockIdx.y * OD * SD;
    if (o32) o32 += (size_t)blockIdx.y * OD * ldo;
    int ar = tid >> 2, ao = (tid & 3) * 8;
    int xk = tid >> 3, xn = (tid & 7) * 8;
    int qb = xk >> 3;
    v4f acc[4] = {{0,0,0,0},{0,0,0,0},{0,0,0,0},{0,0,0,0}};

    v8s av = *(const v8s*)(A + (size_t)(tM + ar) * SD + ao);
    v8s xv = *(const v8s*)(B + (size_t)xk * ldb + tN + xn);
    for (int k0 = 0; k0 < SD; k0 += 32) {
        *(v8s*)(Al + ar * 40 + ao) = av;
#pragma unroll
        for (int c = 0; c < 8; ++c) {
            int n = xn + c, sw = (n >> 3) & 3;
            Xt[n * 40 + (((qb ^ sw) << 3) | (xk & 7))] = xv[c];
        }
        __syncthreads();
        if (k0 + 32 < SD) {
            av = *(const v8s*)(A + (size_t)(tM + ar) * SD + (k0 + 32) + ao);
            xv = *(const v8s*)(B + (size_t)(k0 + 32 + xk) * ldb + tN + xn);
        }
        v8s a = *(const v8s*)(Al + (w * 16 + m16) * 40 + q * 8);
#pragma unroll
        for (int c = 0; c < 4; ++c) {
            int nl = c * 16 + m16, swn = (nl >> 3) & 3;
            v8s b = *(const v8s*)(Xt + nl * 40 + ((q ^ swn) << 3));
            acc[c] = __builtin_amdgcn_mfma_f32_16x16x32_bf16(a, b, acc[c], 0, 0, 0);
        }
        __syncthreads();
    }
#pragma unroll
    for (int c = 0; c < 4; ++c) {
#pragma unroll
        for (int j = 0; j < 4; ++j) {
            int r = tM + w * 16 + q * 4 + j;
            int col = tN + c * 16 + m16;
            float v = acc[c][j];
            if (o32) {
                size_t idx = (size_t)r * ldo + col;
                if (accum) o32[idx] += v; else o32[idx] = v;
            }
            if (obf) obf[(size_t)r * ldo + col] = f2bf(v);
        }
    }
}

// ---------------- Pall = CEcat(2560x2048) @ pnT(2048x8192), bf16 out ---------------------
__global__ __launch_bounds__(256) void k_gemmP(const unsigned short* __restrict__ A,
                                               const unsigned short* __restrict__ B,
                                               unsigned short* __restrict__ out) {
    __shared__ __align__(16) unsigned short Al[64 * 40];
    __shared__ __align__(16) unsigned short Xt[64 * 40];
    int tid = threadIdx.x, lane = tid & 63, w = tid >> 6;
    int m16 = lane & 15, q = lane >> 4;
    int bid = blockIdx.x;                          // 5120
    int logical = (bid & 7) * 640 + (bid >> 3);    // XCD-chunked swizzle (bijective)
    int mT = logical % 40, nT = logical / 40;      // each XCD: 16 n-panels, m-major inner
    int tM = mT * 64, tN = nT * 64;
    int ar = tid >> 2, ao = (tid & 3) * 8;
    int xk = tid >> 3, xn = (tid & 7) * 8;
    int qb = xk >> 3;
    v4f acc[4] = {{0,0,0,0},{0,0,0,0},{0,0,0,0},{0,0,0,0}};

    v8s av = *(const v8s*)(A + (size_t)(tM + ar) * SD + ao);
    v8s xv = *(const v8s*)(B + (size_t)xk * NT + tN + xn);
    for (int k0 = 0; k0 < SD; k0 += 32) {
        *(v8s*)(Al + ar * 40 + ao) = av;
#pragma unroll
        for (int c = 0; c < 8; ++c) {
            int n = xn + c, sw = (n >> 3) & 3;
            Xt[n * 40 + (((qb ^ sw) << 3) | (xk & 7))] = xv[c];
        }
        __syncthreads();
        if (k0 + 32 < SD) {
            av = *(const v8s*)(A + (size_t)(tM + ar) * SD + (k0 + 32) + ao);
            xv = *(const v8s*)(B + (size_t)(k0 + 32 + xk) * NT + tN + xn);
        }
        v8s a = *(const v8s*)(Al + (w * 16 + m16) * 40 + q * 8);
#pragma unroll
        for (int c = 0; c < 4; ++c) {
            int nl = c * 16 + m16, swn = (nl >> 3) & 3;
            v8s b = *(const v8s*)(Xt + nl * 40 + ((q ^ swn) << 3));
            acc[c] = __builtin_amdgcn_mfma_f32_16x16x32_bf16(a, b, acc[c], 0, 0, 0);
        }
        __syncthreads();
    }
#pragma unroll
    for (int c = 0; c < 4; ++c) {
#pragma unroll
        for (int j = 0; j < 4; ++j) {
            int r = tM + w * 16 + q * 4 + j;
            int col = tN + c * 16 + m16;
            out[(size_t)r * NT + col] = f2bf(acc[c][j]);
        }
    }
}

// ---------------- final: out[64k+i][o] = sum_p (Pall_p(o,:) @ T_p(:,i)) [MFMA K=320]
//                                       + sum_p cW[p][i]*H[p][o][k] + OBS_STD*on --------
__global__ __launch_bounds__(256) void k_final2(const unsigned short* __restrict__ P,
                                                const unsigned short* __restrict__ Tbf,
                                                const float* __restrict__ H,
                                                const float* __restrict__ cW,
                                                const float* __restrict__ on,
                                                float* __restrict__ out) {
    __shared__ __align__(16) float obsT[64][65];
    unsigned short* Al = (unsigned short*)obsT;    // 64*40 u16 (aliased; dead before obsT use)
    unsigned short* Xt = Al + 64 * 40;
    int bx = blockIdx.x;                 // 1024 = 128 kb * 8 o-tiles
    int kb = bx >> 3, ob = bx & 7;
    int o0 = ob * 64;
    int tid = threadIdx.x, lane = tid & 63, w = tid >> 6;
    int m16 = lane & 15, q = lane >> 4;
    int ar = tid >> 2, ao = (tid & 3) * 8;         // A stage: 64 o x 32 j
    int xk = tid >> 3, xn = (tid & 7) * 8;         // B stage: 32 j x 64 i
    int qb = xk >> 3;
    v4f acc[4] = {{0,0,0,0},{0,0,0,0},{0,0,0,0},{0,0,0,0}};
    const unsigned short* Abase = P + (size_t)kb * 64;

    v8s av = *(const v8s*)(Abase + (size_t)(o0 + ar) * NT + ao);
    v8s xv = *(const v8s*)(Tbf + xk * 64 + xn);
    for (int kc = 0; kc < 2 * NPN; ++kc) {
        *(v8s*)(Al + ar * 40 + ao) = av;
#pragma unroll
        for (int c = 0; c < 8; ++c) {
            int n = xn + c, sw = (n >> 3) & 3;
            Xt[n * 40 + (((qb ^ sw) << 3) | (xk & 7))] = xv[c];
        }
        __syncthreads();
        if (kc + 1 < 2 * NPN) {
            int p = (kc + 1) >> 1, j0 = ((kc + 1) & 1) * 32;
            av = *(const v8s*)(Abase + (size_t)(p * OD + o0 + ar) * NT + j0 + ao);
            xv = *(const v8s*)(Tbf + p * 4096 + (j0 + xk) * 64 + xn);
        }
        v8s a = *(const v8s*)(Al + (w * 16 + m16) * 40 + q * 8);
#pragma unroll
        for (int c = 0; c < 4; ++c) {
            int nl = c * 16 + m16, swn = (nl >> 3) & 3;
            v8s b = *(const v8s*)(Xt + nl * 40 + ((q ^ swn) << 3));
            acc[c] = __builtin_amdgcn_mfma_f32_16x16x32_bf16(a, b, acc[c], 0, 0, 0);
        }
        __syncthreads();
    }
    // transpose through LDS, add homogeneous part + obs noise, write coalesced over o
#pragma unroll
    for (int c = 0; c < 4; ++c)
#pragma unroll
        for (int j = 0; j < 4; ++j)
            obsT[w * 16 + q * 4 + j][c * 16 + m16] = acc[c][j];
    __syncthreads();
    int g = tid >> 6;
    float Hv[NPH];
#pragma unroll
    for (int p = 0; p < NPH; ++p)
        Hv[p] = H[((size_t)p * OD + o0 + lane) * KB + kb];
#pragma unroll
    for (int r = 0; r < 16; ++r) {
        int trow = r * 4 + g;            // i within block
        float a2 = obsT[lane][trow];
#pragma unroll
        for (int p = 0; p < NPH; ++p) a2 += cW[p * 64 + trow] * Hv[p];
        size_t oidx = (size_t)(kb * 64 + trow) * OD + o0 + lane;
        out[oidx] = a2 + OBS_STD * on[oidx];
    }
}

// ---------------- host ----------------
extern "C" void kernel_launch(void* const* d_in, const int* in_sizes, int n_in,
                              void* d_out, int out_size, void* d_ws, size_t ws_size,
                              hipStream_t stream) {
    const float* s0 = (const float*)d_in[0];
    const float* A  = (const float*)d_in[1];
    const float* C  = (const float*)d_in[2];
    const float* pn = (const float*)d_in[3];
    const float* on = (const float*)d_in[4];
    float* out = (float*)d_out;

    char* p = (char*)d_ws;
    auto take = [&](size_t n) { char* r = p; p += (n + 255) & ~(size_t)255; return r; };
    unsigned short* Ebf   = (unsigned short*)take((size_t)SD * SD * 2);   // E -> later Mbf
    unsigned short* CEall = (unsigned short*)take((size_t)NPH * OD * SD * 2);
    // alias region: M+Xp0+Xp1+Xp2 = 41,943,040 B == Pall (2560*8192*2) exactly
    float* M            = (float*)take((size_t)SD * SD * 4);
    unsigned short* Xp0 = (unsigned short*)take((size_t)SD * SD * 2);     // E2 -> scan Mbf B
    unsigned short* Xp1 = (unsigned short*)take((size_t)SD * SD * 2);     // E3
    unsigned short* Xp2 = (unsigned short*)take((size_t)SD * SD * 2);     // P combo
    unsigned short* Pall = (unsigned short*)M;                            // after scan
    float* W      = (float*)take((size_t)6 * SD * KB * 4);
    float* V32[2] = {(float*)take((size_t)SD * KB * 4), (float*)take((size_t)SD * KB * 4)};
    unsigned short* Vbf[2] = {(unsigned short*)take((size_t)SD * KB * 2),
                              (unsigned short*)take((size_t)SD * KB * 2)};
    float* SC32[2] = {(float*)take((size_t)SD * KB * 4), (float*)take((size_t)SD * KB * 4)};
    unsigned short* SCbf[2] = {(unsigned short*)take((size_t)SD * KBP * 2),
                               (unsigned short*)take((size_t)SD * KBP * 2)};
    float* wW   = (float*)take((size_t)NP * 64 * 4);
    float* cW   = (float*)take((size_t)NP * 64 * 4);
    unsigned short* Tbf = (unsigned short*)take((size_t)NP * 64 * 64 * 2);
    unsigned short* pnTbf = (unsigned short*)take((size_t)SD * NT * 2);
    float* H    = (float*)take((size_t)NPH * OD * KB * 4);

    // A^64 = 0.99^64 I + sum_{m=1..6} C(64,m) 0.99^(64-m) E^m   (tail ~2e-6)
    double pw[65]; pw[0] = 1.0;
    for (int m = 1; m <= 64; ++m) pw[m] = pw[m - 1] * 0.99;
    const double bin[7] = {1, 64, 2016, 41664, 635376, 7624512, 74974368};
    float cf[7];
    for (int m = 1; m <= 6; ++m) cf[m] = (float)(bin[m] * pw[64 - m]);
    float a64 = (float)pw[64];

    k_weights2<<<NP * 64 * 64 / 256, 256, 0, stream>>>(wW, cW, Tbf);
    k_prep_A<<<SD * SD / 256, 256, 0, stream>>>(A, Ebf, M, cf[1]);
    k_prep_C<<<OD * SD / 256, 256, 0, stream>>>(C, CEall);    // CE_0 = bf16(C)

    // CE_p = CE_{p-1} @ E  (needs Ebf; run before Ebf is recycled as Mbf)
    for (int pp = 1; pp < NPH; ++pp)
        k_gemm2<<<dim3(256, 1), 256, 0, stream>>>(CEall + (size_t)(pp - 1) * OD * SD, Ebf, SD,
                                                  CEall + (size_t)pp * OD * SD,
                                                  (float*)nullptr, SD, 0);

    // E-powers: E2, E3, then P = cf4 E + cf5 E2 + cf6 E3
    k_gemmNN<<<1024, 256, 0, stream>>>(Ebf, Ebf, Xp0);        // E2
    k_gemmNN<<<1024, 256, 0, stream>>>(Ebf, Xp0, Xp1);        // E3
    k_combP<<<SD * SD / 256, 256, 0, stream>>>(Ebf, Xp0, Xp1, Xp2, cf[4], cf[5], cf[6]);

    // pass 1: u_k = sum_p E^p W_p via Horner (V init = W_6); also emits pnT bf16
    k_wsum<<<1024, 256, 0, stream>>>(pn, wW, W, V32[0], Vbf[0], pnTbf);
    int cur = 0;
    for (int pp = 5; pp >= 0; --pp) {
        k_horner<<<256, 256, 0, stream>>>(Ebf, Vbf[cur], W + (size_t)pp * SD * KB,
                                          V32[cur ^ 1], Vbf[cur ^ 1]);
        cur ^= 1;
    }  // cur == 0: V32[0] = u_k in [d][k]

    // M = cf1 E + cf2 E2 + cf3 E3 + E3@P  (fp32 into M, bf16 into Ebf buffer = Mbf)
    k_gemm_M<<<1024, 256, 0, stream>>>(Xp1, Xp2, M, Xp0, Ebf, cf[2], cf[3]);

    // pass 2: boundary states via 5-round matrix scan (shifts 1,2,4,8,16; A64^32 ~ 1e-9)
    k_scan_init<<<SD * KBP / 256, 256, 0, stream>>>(s0, V32[cur], SC32[0], SCbf[0], SCbf[1]);
    unsigned short* MbfA = Ebf;
    unsigned short* MbfB = Xp0;
    float a = a64;
    int sc = 0;
    for (int r = 0; r < 5; ++r) {
        k_scan<<<256, 256, 0, stream>>>(MbfA, SCbf[sc], SC32[sc],
                                        SC32[sc ^ 1], SCbf[sc ^ 1], a, 1 << r);
        sc ^= 1;
        if (r < 4) {
            k_gemm_sq<<<1024, 256, 0, stream>>>(MbfA, M, MbfB, 2.f * a);
            unsigned short* t = MbfA; MbfA = MbfB; MbfB = t;
            a = a * a;
        }
    }  // SCbf[sc] = padded bf16 boundary states

    // pass 3: H[p] = CE_p @ S_bound (batched over p)
    k_gemm2<<<dim3(16, NPH), 256, 0, stream>>>(CEall, SCbf[sc] + 16, KBP,
                                               (unsigned short*)nullptr, H, KB, 0);
    // Pall = CEcat @ pnT  (M/Xp region dead -> aliased)
    k_gemmP<<<5120, 256, 0, stream>>>(CEall, pnTbf, Pall);
    // out = (Pall * T) + homogeneous + obs noise
    k_final2<<<1024, 256, 0, stream>>>(Pall, Tbf, H, cW, on, out);
}

// Round 5
// 1170.708 us; speedup vs baseline: 4.1693x; 1.0020x over previous
//
#include <hip/hip_runtime.h>

// SimpleStateSpaceModel restructure v6:
//   v5 profile: k_gemmP 236us @ 650MB FETCH (15x ideal), 364 TF; other 2048^3 GEMMs ~310 TF.
//   -> ONE new 128^2-tile GEMM core (m97 structure): global_load_lds width-16 for BOTH
//      operands (B operands stored row-major-along-K: pnbf[t][d] natural; Et/E3t/MbfT
//      via tiled-transpose prep + dual-write epilogues; E3@P = P@E3 commutes).
//   Old 64^2 core kept only for CE chain + H (small M) + horner/scan (N=128).

#define SD 2048      // state dim
#define OD 512       // obs dim
#define NT 8192      // steps
#define BLK 64       // steps per block
#define KB 128       // number of blocks = NT/BLK
#define KBP (KB+16)  // padded column stride for scan bf16 buffers
#define NP 7         // binomial terms p=0..6
#define NPH 6        // homogeneous obs terms p=0..5
#define NPN 5        // noise obs terms p=0..4
#define PROC_STD 0.31622776601683794f
#define OBS_STD  0.7071067811865476f

typedef __attribute__((ext_vector_type(8))) short v8s;
typedef __attribute__((ext_vector_type(4))) float v4f;

__device__ __forceinline__ unsigned short f2bf(float f) {
    union { float f; unsigned int u; } v; v.f = f;
    unsigned int r = v.u + 0x7fffu + ((v.u >> 16) & 1u);
    return (unsigned short)(r >> 16);
}
__device__ __forceinline__ float bf2f(unsigned short u) {
    union { unsigned int ui; float f; } cv; cv.ui = (unsigned int)u << 16;
    return cv.f;
}

#define GLD16(g, l) __builtin_amdgcn_global_load_lds( \
    (const __attribute__((address_space(1))) unsigned int*)(g), \
    (__attribute__((address_space(3))) unsigned int*)(l), 16, 0, 0)

// ---------------- weights ----------------
__device__ double d_binom(int m, int p) {
    if (p < 0 || p > m) return 0.0;
    double c = 1.0;
    for (int q = 1; q <= p; ++q) c = c * (double)(m - p + q) / (double)q;
    return c;
}
__device__ double d_p99(int n) {
    double r = 1.0;
    for (int q = 0; q < n; ++q) r *= 0.99;
    return r;
}
__global__ __launch_bounds__(256) void k_weights2(float* __restrict__ wW,
                                                  float* __restrict__ cW,
                                                  unsigned short* __restrict__ Tbf) {
    int idx = blockIdx.x * 256 + threadIdx.x;
    if (idx < NP * 64) {
        int p = idx >> 6, j = idx & 63;
        int m = 63 - j;
        wW[idx] = (p <= m) ? (float)((double)PROC_STD * d_binom(m, p) * d_p99(m - p)) : 0.f;
        cW[idx] = (p <= j) ? (float)(d_binom(j, p) * d_p99(j - p)) : 0.f;
    }
    if (idx < NP * 64 * 64) {
        int p = idx >> 12, j = (idx >> 6) & 63, i = idx & 63;
        int mm = i - 1 - j;
        float t = (mm >= p) ? (float)((double)PROC_STD * d_binom(mm, p) * d_p99(mm - p)) : 0.f;
        Tbf[idx] = f2bf(t);
    }
}

// ---------------- prep: Ebf, Et (tiled transpose), M = c1*E ----------------
__global__ __launch_bounds__(256) void k_prep_A(const float* __restrict__ A,
                                                unsigned short* __restrict__ Ebf,
                                                unsigned short* __restrict__ Et,
                                                float* __restrict__ M, float c1) {
    __shared__ unsigned short t16[64][72];
    int bx = blockIdx.x;                 // 1024 = 32 rb x 32 cb
    int r0 = (bx & 31) * 64, c0 = (bx >> 5) * 64;
    int tid = threadIdx.x;
    int i = tid >> 2, cq = (tid & 3) * 16;
#pragma unroll
    for (int u = 0; u < 16; ++u) {
        int r = r0 + i, c = c0 + cq + u;
        float e = A[(size_t)r * SD + c] - (r == c ? 0.99f : 0.0f);
        unsigned short b = f2bf(e);
        Ebf[(size_t)r * SD + c] = b;
        M[(size_t)r * SD + c] = c1 * e;
        t16[i][cq + u] = b;
    }
    __syncthreads();
#pragma unroll
    for (int u = 0; u < 16; ++u)
        Et[(size_t)(c0 + i) * SD + r0 + cq + u] = t16[cq + u][i];
}

__global__ __launch_bounds__(256) void k_prep_C(const float* __restrict__ C,
                                                unsigned short* __restrict__ Cbf) {
    int idx = blockIdx.x * 256 + threadIdx.x;
    Cbf[idx] = f2bf(C[idx]);
}

// P = bf16(cf4*E + cf5*E2 + cf6*E3)
__global__ __launch_bounds__(256) void k_combP(const unsigned short* __restrict__ Ebf,
                                               const unsigned short* __restrict__ E2,
                                               const unsigned short* __restrict__ E3,
                                               unsigned short* __restrict__ P,
                                               float c4, float c5, float c6) {
    int idx = blockIdx.x * 256 + threadIdx.x;
    P[idx] = f2bf(c4 * bf2f(Ebf[idx]) + c5 * bf2f(E2[idx]) + c6 * bf2f(E3[idx]));
}

// ---------------- 128^2-tile GEMM core (m97 structure, gload_lds both operands) ----------
// out = A(row-major [m][k], lda) @ Bt(row-major [n][k], ldb)^T ; K = SD fixed.
// mode 0: obf only; 1: obf+obfT; 2: gemm_M epilogue; 3: squaring epilogue.
__global__ __launch_bounds__(256) void k_g128(const unsigned short* __restrict__ Aptr, int lda,
                                              const unsigned short* __restrict__ Bptr, int ldb,
                                              int mtiles, int swz, int mode,
                                              unsigned short* __restrict__ obf, size_t ldo,
                                              unsigned short* __restrict__ obfT,
                                              float* __restrict__ M32,
                                              const unsigned short* __restrict__ X1,
                                              const unsigned short* __restrict__ X2,
                                              float c1, float c2) {
    __shared__ __align__(16) unsigned short As[128 * 32];
    __shared__ __align__(16) unsigned short Bs[128 * 32];
    int tid = threadIdx.x, lane = tid & 63, w = tid >> 6;
    int bid = blockIdx.x;
    int mT, nT;
    if (swz) {
        int npx = (int)(gridDim.x >> 3) / mtiles;
        mT = (bid >> 3) % mtiles;
        nT = (bid & 7) * npx + (bid >> 3) / mtiles;
    } else {
        mT = bid % mtiles;
        nT = bid / mtiles;
    }
    int tM = mT * 128, tN = nT * 128;
    int wr = w >> 1, wc = w & 1;
    int m16 = lane & 15, q = lane >> 4;
    int srow = lane >> 2, sk8 = lane & 3;          // staging: 16 rows x 4 k8 per wave-chunk
    const unsigned short* ga0 = Aptr + (size_t)(tM + w * 16 + srow) * lda + sk8 * 8;
    const unsigned short* ga1 = ga0 + (size_t)64 * lda;
    const unsigned short* gb0 = Bptr + (size_t)(tN + w * 16 + srow) * ldb + sk8 * 8;
    const unsigned short* gb1 = gb0 + (size_t)64 * ldb;
    unsigned short* la0 = As + w * 512;            // wave-uniform LDS bases
    unsigned short* la1 = As + 2048 + w * 512;
    unsigned short* lb0 = Bs + w * 512;
    unsigned short* lb1 = Bs + 2048 + w * 512;

    v4f acc[4][4];
#pragma unroll
    for (int mi = 0; mi < 4; ++mi)
#pragma unroll
        for (int ni = 0; ni < 4; ++ni) acc[mi][ni] = (v4f){0, 0, 0, 0};

    GLD16(ga0, la0); GLD16(ga1, la1); GLD16(gb0, lb0); GLD16(gb1, lb1);
    ga0 += 32; ga1 += 32; gb0 += 32; gb1 += 32;
    __syncthreads();

    int arow = (wr * 64 + m16) * 32 + q * 8;
    int brow = (wc * 64 + m16) * 32 + q * 8;
    for (int k0 = 0; k0 < SD; k0 += 32) {
        v8s a[4], b[4];
#pragma unroll
        for (int mi = 0; mi < 4; ++mi) a[mi] = *(const v8s*)(As + arow + mi * 512);
#pragma unroll
        for (int ni = 0; ni < 4; ++ni) b[ni] = *(const v8s*)(Bs + brow + ni * 512);
        __syncthreads();                           // all reads done -> LDS reusable
        if (k0 + 32 < SD) {
            GLD16(ga0, la0); GLD16(ga1, la1); GLD16(gb0, lb0); GLD16(gb1, lb1);
            ga0 += 32; ga1 += 32; gb0 += 32; gb1 += 32;
        }
#pragma unroll
        for (int mi = 0; mi < 4; ++mi)
#pragma unroll
            for (int ni = 0; ni < 4; ++ni)
                acc[mi][ni] = __builtin_amdgcn_mfma_f32_16x16x32_bf16(a[mi], b[ni],
                                                                      acc[mi][ni], 0, 0, 0);
        __syncthreads();                           // drains vmcnt -> next tile in LDS
    }

#pragma unroll
    for (int mi = 0; mi < 4; ++mi)
#pragma unroll
        for (int ni = 0; ni < 4; ++ni)
#pragma unroll
            for (int j = 0; j < 4; ++j) {
                int row = tM + wr * 64 + mi * 16 + q * 4 + j;
                int col = tN + wc * 64 + ni * 16 + m16;
                float v = acc[mi][ni][j];
                if (mode == 2) {
                    size_t i2 = (size_t)row * SD + col;
                    v += M32[i2] + c1 * bf2f(X1[i2]) + c2 * bf2f(X2[i2]);
                    M32[i2] = v;
                } else if (mode == 3) {
                    size_t i2 = (size_t)row * SD + col;
                    v = c1 * M32[i2] + v;
                    M32[i2] = v;
                }
                obf[(size_t)row * ldo + col] = f2bf(v);
                if (mode >= 1) obfT[(size_t)col * SD + row] = f2bf(v);
            }
}

// ---------------- pass1 reduction + pnbf emission ----------------------------------------
__global__ __launch_bounds__(256) void k_wsum(const float* __restrict__ pn,
                                              const float* __restrict__ wW,
                                              float* __restrict__ W,
                                              float* __restrict__ V32,
                                              unsigned short* __restrict__ Vbf,
                                              unsigned short* __restrict__ pnbf) {
    __shared__ float ws[NP * 64];
    int tid = threadIdx.x;
    for (int t = tid; t < NP * 64; t += 256) ws[t] = wW[t];
    __syncthreads();
    int bx = blockIdx.x;                 // 1024 = 128 k * 8 d-chunks
    int k = bx >> 3, dc = bx & 7;
    int d = dc * 256 + tid;
    float acc[NP];
#pragma unroll
    for (int p = 0; p < NP; ++p) acc[p] = 0.f;
    for (int j = 0; j < 64; ++j) {
        size_t gi = (size_t)(k * BLK + j) * SD + d;
        float v = pn[gi];
        pnbf[gi] = f2bf(v);
#pragma unroll
        for (int p = 0; p < NP; ++p) acc[p] += ws[p * 64 + j] * v;
    }
#pragma unroll
    for (int p = 0; p < 6; ++p) W[((size_t)p * SD + d) * KB + k] = acc[p];
    V32[(size_t)d * KB + k] = acc[6];
    Vbf[(size_t)d * KB + k] = f2bf(acc[6]);
}

// ---------------- Horner step: V' = E @ V + W_p   (2048 x 128, K=2048) ----------------
__global__ __launch_bounds__(256) void k_horner(const unsigned short* __restrict__ Ebf,
                                                const unsigned short* __restrict__ Xbf,
                                                const float* __restrict__ Wp,
                                                float* __restrict__ X32o,
                                                unsigned short* __restrict__ Xbfo) {
    __shared__ __align__(16) unsigned short Al[32 * 72];
    __shared__ __align__(16) unsigned short Xt[32 * 72];
    int bx = blockIdx.x;
    int tM = (bx & 63) * 32, tN = (bx >> 6) * 32;
    int tid = threadIdx.x, lane = tid & 63, w = tid >> 6;
    int m16 = lane & 15, q = lane >> 4;
    int ar = tid >> 3, ao = (tid & 7) * 8;
    int xk = tid >> 2, xn = (tid & 3) * 8;
    int qb = xk >> 3;
    v4f acc = {0, 0, 0, 0};
    v8s av = *(const v8s*)(Ebf + (size_t)(tM + ar) * SD + ao);
    v8s xv = *(const v8s*)(Xbf + (size_t)xk * KB + tN + xn);
    int nl = (w & 1) * 16 + m16;
    int swn = (nl >> 3) & 3;
    int rl = (w >> 1) * 16 + m16;
    for (int k0 = 0; k0 < SD; k0 += 64) {
        *(v8s*)(Al + ar * 72 + ao) = av;
#pragma unroll
        for (int c = 0; c < 8; ++c) {
            int n = xn + c, sw = (n >> 3) & 3;
            Xt[n * 72 + (((qb ^ sw) << 3) | (xk & 7))] = xv[c];
        }
        __syncthreads();
        if (k0 + 64 < SD) {
            av = *(const v8s*)(Ebf + (size_t)(tM + ar) * SD + (k0 + 64) + ao);
            xv = *(const v8s*)(Xbf + (size_t)(k0 + 64 + xk) * KB + tN + xn);
        }
#pragma unroll
        for (int ch = 0; ch < 2; ++ch) {
            v8s a = *(const v8s*)(Al + rl * 72 + ch * 32 + q * 8);
            int q2 = ch * 4 + q;
            v8s b = *(const v8s*)(Xt + nl * 72 + ((q2 ^ swn) << 3));
            acc = __builtin_amdgcn_mfma_f32_16x16x32_bf16(a, b, acc, 0, 0, 0);
        }
        __syncthreads();
    }
#pragma unroll
    for (int j = 0; j < 4; ++j) {
        int r = tM + (w >> 1) * 16 + q * 4 + j;
        int kc = tN + (w & 1) * 16 + m16;
        int idx = r * KB + kc;
        float v = acc[j] + Wp[idx];
        X32o[idx] = v;
        Xbfo[idx] = f2bf(v);
    }
}

// ---------------- scan init ----------------
__global__ __launch_bounds__(256) void k_scan_init(const float* __restrict__ s0,
                                                   const float* __restrict__ U,
                                                   float* __restrict__ S32,
                                                   unsigned short* __restrict__ Sbf0,
                                                   unsigned short* __restrict__ Sbf1) {
    int idx = blockIdx.x * 256 + threadIdx.x;     // 0 .. SD*KBP-1
    int d = idx / KBP, c = idx - d * KBP;
    if (c < 16) { Sbf0[idx] = 0; Sbf1[idx] = 0; return; }
    int k = c - 16;
    float v = (k == 0) ? s0[d] : U[(size_t)d * KB + (k - 1)];
    S32[(size_t)d * KB + k] = v;
    Sbf0[idx] = f2bf(v);
}

// ---------------- scan round: S'[:,k] = S[:,k] + a*S[:,k-sh] + Mr@S[:,k-sh] --------------
__global__ __launch_bounds__(256) void k_scan(const unsigned short* __restrict__ Mrbf,
                                              const unsigned short* __restrict__ Sbf_in,
                                              const float* __restrict__ S32_in,
                                              float* __restrict__ S32_out,
                                              unsigned short* __restrict__ Sbf_out,
                                              float ar, int shift) {
    __shared__ __align__(16) unsigned short Al[32 * 72];
    __shared__ __align__(16) unsigned short Xt[32 * 72];
    int bx = blockIdx.x;
    int tM = (bx & 63) * 32, tN = (bx >> 6) * 32;
    int tid = threadIdx.x, lane = tid & 63, w = tid >> 6;
    int m16 = lane & 15, q = lane >> 4;
    int ar_ = tid >> 3, ao = (tid & 7) * 8;
    int xk = tid >> 2, xn = (tid & 3) * 8;
    int qb = xk >> 3;
    int coff = tN + xn + 16 - shift;
    v4f acc = {0, 0, 0, 0};
    v8s av = *(const v8s*)(Mrbf + (size_t)(tM + ar_) * SD + ao);
    v8s xv = *(const v8s*)(Sbf_in + (size_t)xk * KBP + coff);
    int nl = (w & 1) * 16 + m16;
    int swn = (nl >> 3) & 3;
    int rl = (w >> 1) * 16 + m16;
    for (int k0 = 0; k0 < SD; k0 += 64) {
        *(v8s*)(Al + ar_ * 72 + ao) = av;
#pragma unroll
        for (int c = 0; c < 8; ++c) {
            int n = xn + c, sw = (n >> 3) & 3;
            Xt[n * 72 + (((qb ^ sw) << 3) | (xk & 7))] = xv[c];
        }
        __syncthreads();
        if (k0 + 64 < SD) {
            av = *(const v8s*)(Mrbf + (size_t)(tM + ar_) * SD + (k0 + 64) + ao);
            xv = *(const v8s*)(Sbf_in + (size_t)(k0 + 64 + xk) * KBP + coff);
        }
#pragma unroll
        for (int ch = 0; ch < 2; ++ch) {
            v8s a = *(const v8s*)(Al + rl * 72 + ch * 32 + q * 8);
            int q2 = ch * 4 + q;
            v8s b = *(const v8s*)(Xt + nl * 72 + ((q2 ^ swn) << 3));
            acc = __builtin_amdgcn_mfma_f32_16x16x32_bf16(a, b, acc, 0, 0, 0);
        }
        __syncthreads();
    }
#pragma unroll
    for (int j = 0; j < 4; ++j) {
        int r = tM + (w >> 1) * 16 + q * 4 + j;
        int kc = tN + (w & 1) * 16 + m16;
        int idx = r * KB + kc;
        int ksh = kc - shift;
        float v = S32_in[idx] + acc[j] + (ksh >= 0 ? ar * S32_in[r * KB + ksh] : 0.f);
        S32_out[idx] = v;
        Sbf_out[(size_t)r * KBP + kc + 16] = f2bf(v);
    }
}

// ---------------- 64^2 core kept for CE chain (grid(256,1)) + H (grid(16,NPH)) -----------
__global__ __launch_bounds__(256) void k_gemm2(const unsigned short* __restrict__ A,
                                               const unsigned short* __restrict__ B,
                                               int ldb,
                                               unsigned short* __restrict__ obf,
                                               float* __restrict__ o32,
                                               int ldo) {
    __shared__ __align__(16) unsigned short Al[64 * 40];
    __shared__ __align__(16) unsigned short Xt[64 * 40];
    int tid = threadIdx.x, lane = tid & 63, w = tid >> 6;
    int m16 = lane & 15, q = lane >> 4;
    int bx = blockIdx.x;
    int tM = (bx & 7) * 64, tN = (bx >> 3) * 64;
    A += (size_t)blockIdx.y * OD * SD;
    if (o32) o32 += (size_t)blockIdx.y * OD * ldo;
    int ar = tid >> 2, ao = (tid & 3) * 8;
    int xk = tid >> 3, xn = (tid & 7) * 8;
    int qb = xk >> 3;
    v4f acc[4] = {{0,0,0,0},{0,0,0,0},{0,0,0,0},{0,0,0,0}};

    v8s av = *(const v8s*)(A + (size_t)(tM + ar) * SD + ao);
    v8s xv = *(const v8s*)(B + (size_t)xk * ldb + tN + xn);
    for (int k0 = 0; k0 < SD; k0 += 32) {
        *(v8s*)(Al + ar * 40 + ao) = av;
#pragma unroll
        for (int c = 0; c < 8; ++c) {
            int n = xn + c, sw = (n >> 3) & 3;
            Xt[n * 40 + (((qb ^ sw) << 3) | (xk & 7))] = xv[c];
        }
        __syncthreads();
        if (k0 + 32 < SD) {
            av = *(const v8s*)(A + (size_t)(tM + ar) * SD + (k0 + 32) + ao);
            xv = *(const v8s*)(B + (size_t)(k0 + 32 + xk) * ldb + tN + xn);
        }
        v8s a = *(const v8s*)(Al + (w * 16 + m16) * 40 + q * 8);
#pragma unroll
        for (int c = 0; c < 4; ++c) {
            int nl = c * 16 + m16, swn = (nl >> 3) & 3;
            v8s b = *(const v8s*)(Xt + nl * 40 + ((q ^ swn) << 3));
            acc[c] = __builtin_amdgcn_mfma_f32_16x16x32_bf16(a, b, acc[c], 0, 0, 0);
        }
        __syncthreads();
    }
#pragma unroll
    for (int c = 0; c < 4; ++c) {
#pragma unroll
        for (int j = 0; j < 4; ++j) {
            int r = tM + w * 16 + q * 4 + j;
            int col = tN + c * 16 + m16;
            float v = acc[c][j];
            if (o32) o32[(size_t)r * ldo + col] = v;
            if (obf) obf[(size_t)r * ldo + col] = f2bf(v);
        }
    }
}

// ---------------- final: out[64k+i][o] = Pall_p(o,:)@T_p(:,i) + hom + noise --------------
__global__ __launch_bounds__(256) void k_final2(const unsigned short* __restrict__ P,
                                                const unsigned short* __restrict__ Tbf,
                                                const float* __restrict__ H,
                                                const float* __restrict__ cW,
                                                const float* __restrict__ on,
                                                float* __restrict__ out) {
    __shared__ __align__(16) float obsT[64][65];
    unsigned short* Al = (unsigned short*)obsT;
    unsigned short* Xt = Al + 64 * 40;
    int bx = blockIdx.x;                 // 1024 = 128 kb * 8 o-tiles
    int kb = bx >> 3, ob = bx & 7;
    int o0 = ob * 64;
    int tid = threadIdx.x, lane = tid & 63, w = tid >> 6;
    int m16 = lane & 15, q = lane >> 4;
    int ar = tid >> 2, ao = (tid & 3) * 8;
    int xk = tid >> 3, xn = (tid & 7) * 8;
    int qb = xk >> 3;
    v4f acc[4] = {{0,0,0,0},{0,0,0,0},{0,0,0,0},{0,0,0,0}};
    const unsigned short* Abase = P + (size_t)kb * 64;

    v8s av = *(const v8s*)(Abase + (size_t)(o0 + ar) * NT + ao);
    v8s xv = *(const v8s*)(Tbf + xk * 64 + xn);
    for (int kc = 0; kc < 2 * NPN; ++kc) {
        *(v8s*)(Al + ar * 40 + ao) = av;
#pragma unroll
        for (int c = 0; c < 8; ++c) {
            int n = xn + c, sw = (n >> 3) & 3;
            Xt[n * 40 + (((qb ^ sw) << 3) | (xk & 7))] = xv[c];
        }
        __syncthreads();
        if (kc + 1 < 2 * NPN) {
            int p = (kc + 1) >> 1, j0 = ((kc + 1) & 1) * 32;
            av = *(const v8s*)(Abase + (size_t)(p * OD + o0 + ar) * NT + j0 + ao);
            xv = *(const v8s*)(Tbf + p * 4096 + (j0 + xk) * 64 + xn);
        }
        v8s a = *(const v8s*)(Al + (w * 16 + m16) * 40 + q * 8);
#pragma unroll
        for (int c = 0; c < 4; ++c) {
            int nl = c * 16 + m16, swn = (nl >> 3) & 3;
            v8s b = *(const v8s*)(Xt + nl * 40 + ((q ^ swn) << 3));
            acc[c] = __builtin_amdgcn_mfma_f32_16x16x32_bf16(a, b, acc[c], 0, 0, 0);
        }
        __syncthreads();
    }
#pragma unroll
    for (int c = 0; c < 4; ++c)
#pragma unroll
        for (int j = 0; j < 4; ++j)
            obsT[w * 16 + q * 4 + j][c * 16 + m16] = acc[c][j];
    __syncthreads();
    int g = tid >> 6;
    float Hv[NPH];
#pragma unroll
    for (int p = 0; p < NPH; ++p)
        Hv[p] = H[((size_t)p * OD + o0 + lane) * KB + kb];
#pragma unroll
    for (int r = 0; r < 16; ++r) {
        int trow = r * 4 + g;
        float a2 = obsT[lane][trow];
#pragma unroll
        for (int p = 0; p < NPH; ++p) a2 += cW[p * 64 + trow] * Hv[p];
        size_t oidx = (size_t)(kb * 64 + trow) * OD + o0 + lane;
        out[oidx] = a2 + OBS_STD * on[oidx];
    }
}

// ---------------- host ----------------
extern "C" void kernel_launch(void* const* d_in, const int* in_sizes, int n_in,
                              void* d_out, int out_size, void* d_ws, size_t ws_size,
                              hipStream_t stream) {
    const float* s0 = (const float*)d_in[0];
    const float* A  = (const float*)d_in[1];
    const float* C  = (const float*)d_in[2];
    const float* pn = (const float*)d_in[3];
    const float* on = (const float*)d_in[4];
    float* out = (float*)d_out;

    char* p = (char*)d_ws;
    auto take = [&](size_t n) { char* r = p; p += (n + 255) & ~(size_t)255; return r; };
    unsigned short* Ebf = (unsigned short*)take((size_t)SD * SD * 2);   // E -> later Mbf
    unsigned short* Et  = (unsigned short*)take((size_t)SD * SD * 2);   // E^T -> later MbfT
    unsigned short* CEall = (unsigned short*)take((size_t)NPH * OD * SD * 2);
    // contiguous region M+Xp0+Xp1+Xp2 = 41,943,040 B == Pall (2560*8192*2) exactly
    float* M            = (float*)take((size_t)SD * SD * 4);
    unsigned short* Xp0 = (unsigned short*)take((size_t)SD * SD * 2);   // E2 -> sq ping
    unsigned short* Xp1 = (unsigned short*)take((size_t)SD * SD * 2);   // E3
    unsigned short* Xp2 = (unsigned short*)take((size_t)SD * SD * 2);   // P
    unsigned short* Pall = (unsigned short*)M;                          // after scan
    unsigned short* E3t = (unsigned short*)take((size_t)SD * SD * 2);   // E3^T -> sq pingT
    float* W      = (float*)take((size_t)6 * SD * KB * 4);
    float* V32[2] = {(float*)take((size_t)SD * KB * 4), (float*)take((size_t)SD * KB * 4)};
    unsigned short* Vbf[2] = {(unsigned short*)take((size_t)SD * KB * 2),
                              (unsigned short*)take((size_t)SD * KB * 2)};
    float* SC32[2] = {(float*)take((size_t)SD * KB * 4), (float*)take((size_t)SD * KB * 4)};
    unsigned short* SCbf[2] = {(unsigned short*)take((size_t)SD * KBP * 2),
                               (unsigned short*)take((size_t)SD * KBP * 2)};
    float* wW   = (float*)take((size_t)NP * 64 * 4);
    float* cW   = (float*)take((size_t)NP * 64 * 4);
    unsigned short* Tbf = (unsigned short*)take((size_t)NP * 64 * 64 * 2);
    unsigned short* pnbf = (unsigned short*)take((size_t)SD * NT * 2);
    float* H    = (float*)take((size_t)NPH * OD * KB * 4);

    double pw[65]; pw[0] = 1.0;
    for (int m = 1; m <= 64; ++m) pw[m] = pw[m - 1] * 0.99;
    const double bin[7] = {1, 64, 2016, 41664, 635376, 7624512, 74974368};
    float cf[7];
    for (int m = 1; m <= 6; ++m) cf[m] = (float)(bin[m] * pw[64 - m]);
    float a64 = (float)pw[64];

    k_weights2<<<NP * 64 * 64 / 256, 256, 0, stream>>>(wW, cW, Tbf);
    k_prep_A<<<1024, 256, 0, stream>>>(A, Ebf, Et, M, cf[1]);
    k_prep_C<<<OD * SD / 256, 256, 0, stream>>>(C, CEall);    // CE_0 = bf16(C)

    // CE_p = CE_{p-1} @ E  (old core; uses Ebf before it is recycled)
    for (int pp = 1; pp < NPH; ++pp)
        k_gemm2<<<dim3(256, 1), 256, 0, stream>>>(CEall + (size_t)(pp - 1) * OD * SD, Ebf, SD,
                                                  CEall + (size_t)pp * OD * SD,
                                                  (float*)nullptr, SD);

    // E-powers via new core: E2 = E@E (B=Et), E3 = E2@E (B=Et, dual-write E3t)
    k_g128<<<256, 256, 0, stream>>>(Ebf, SD, Et, SD, 16, 0, 0, Xp0, (size_t)SD,
                                    (unsigned short*)nullptr, (float*)nullptr,
                                    (const unsigned short*)nullptr,
                                    (const unsigned short*)nullptr, 0.f, 0.f);
    k_g128<<<256, 256, 0, stream>>>(Xp0, SD, Et, SD, 16, 0, 1, Xp1, (size_t)SD,
                                    E3t, (float*)nullptr,
                                    (const unsigned short*)nullptr,
                                    (const unsigned short*)nullptr, 0.f, 0.f);
    k_combP<<<SD * SD / 256, 256, 0, stream>>>(Ebf, Xp0, Xp1, Xp2, cf[4], cf[5], cf[6]);

    // pass 1: u_k via Horner; also emits pnbf[t][d]
    k_wsum<<<1024, 256, 0, stream>>>(pn, wW, W, V32[0], Vbf[0], pnbf);
    int cur = 0;
    for (int pp = 5; pp >= 0; --pp) {
        k_horner<<<256, 256, 0, stream>>>(Ebf, Vbf[cur], W + (size_t)pp * SD * KB,
                                          V32[cur ^ 1], Vbf[cur ^ 1]);
        cur ^= 1;
    }  // cur == 0: V32[0] = u_k in [d][k]

    // M = cf1 E + cf2 E2 + cf3 E3 + P@E3   (P@E3 == E3@P, polynomials commute)
    k_g128<<<256, 256, 0, stream>>>(Xp2, SD, E3t, SD, 16, 0, 2, Ebf, (size_t)SD,
                                    Et, M, Xp0, Xp1, cf[2], cf[3]);

    // pass 2: 5-round matrix scan; squarings via new core (dual-write for next B^T)
    k_scan_init<<<SD * KBP / 256, 256, 0, stream>>>(s0, V32[cur], SC32[0], SCbf[0], SCbf[1]);
    unsigned short* MbfA = Ebf;  unsigned short* MbfAt = Et;
    unsigned short* MbfB = Xp0;  unsigned short* MbfBt = E3t;
    float a = a64;
    int sc = 0;
    for (int r = 0; r < 5; ++r) {
        k_scan<<<256, 256, 0, stream>>>(MbfA, SCbf[sc], SC32[sc],
                                        SC32[sc ^ 1], SCbf[sc ^ 1], a, 1 << r);
        sc ^= 1;
        if (r < 4) {
            k_g128<<<256, 256, 0, stream>>>(MbfA, SD, MbfAt, SD, 16, 0, 3, MbfB, (size_t)SD,
                                            MbfBt, M, (const unsigned short*)nullptr,
                                            (const unsigned short*)nullptr, 2.f * a, 0.f);
            unsigned short* t;
            t = MbfA; MbfA = MbfB; MbfB = t;
            t = MbfAt; MbfAt = MbfBt; MbfBt = t;
            a = a * a;
        }
    }  // SCbf[sc] = padded bf16 boundary states

    // pass 3: H[p] = CE_p @ S_bound (old core, batched over p)
    k_gemm2<<<dim3(16, NPH), 256, 0, stream>>>(CEall, SCbf[sc] + 16, KBP,
                                               (unsigned short*)nullptr, H, KB);
    // Pall = CEcat(2560x2048) @ pnbf^T  (pnbf is [t][d] row-major = B^T rows; XCD swizzle)
    k_g128<<<1280, 256, 0, stream>>>(CEall, SD, pnbf, SD, 20, 1, 0, Pall, (size_t)NT,
                                     (unsigned short*)nullptr, (float*)nullptr,
                                     (const unsigned short*)nullptr,
                                     (const unsigned short*)nullptr, 0.f, 0.f);
    k_final2<<<1024, 256, 0, stream>>>(Pall, Tbf, H, cW, on, out);
}

// Round 6
// 1003.665 us; speedup vs baseline: 4.8632x; 1.1664x over previous
//
#include <hip/hip_runtime.h>

// SimpleStateSpaceModel restructure v7:
//   v6 lesson: k_g128 (m97 structure) at grid 256 = 1 block/CU regresses 2048^3 GEMMs
//   (no co-resident blocks to hide barrier drain; cf. m102 shape curve 320 TF @ N=2048).
//   -> revert 2048^3 GEMMs to v5 64^2 core (4 blocks/CU, proven ~52us); k_g128 kept ONLY
//      for Pall (grid 1280 = 5/CU, 236->171us win).  CE chain 5->3 rounds via E2 batching.
//      k_wsum float4.
//   Next round: Pall via BK=64 / 8-phase 256^2 port; K-split+atomic for horner/scan chain.

#define SD 2048      // state dim
#define OD 512       // obs dim
#define NT 8192      // steps
#define BLK 64       // steps per block
#define KB 128       // number of blocks = NT/BLK
#define KBP (KB+16)  // padded column stride for scan bf16 buffers
#define NP 7         // binomial terms p=0..6
#define NPH 6        // homogeneous obs terms p=0..5
#define NPN 5        // noise obs terms p=0..4
#define PROC_STD 0.31622776601683794f
#define OBS_STD  0.7071067811865476f

typedef __attribute__((ext_vector_type(8))) short v8s;
typedef __attribute__((ext_vector_type(4))) float v4f;

__device__ __forceinline__ unsigned short f2bf(float f) {
    union { float f; unsigned int u; } v; v.f = f;
    unsigned int r = v.u + 0x7fffu + ((v.u >> 16) & 1u);
    return (unsigned short)(r >> 16);
}
__device__ __forceinline__ float bf2f(unsigned short u) {
    union { unsigned int ui; float f; } cv; cv.ui = (unsigned int)u << 16;
    return cv.f;
}

#define GLD16(g, l) __builtin_amdgcn_global_load_lds( \
    (const __attribute__((address_space(1))) unsigned int*)(g), \
    (__attribute__((address_space(3))) unsigned int*)(l), 16, 0, 0)

// ---------------- weights ----------------
__device__ double d_binom(int m, int p) {
    if (p < 0 || p > m) return 0.0;
    double c = 1.0;
    for (int q = 1; q <= p; ++q) c = c * (double)(m - p + q) / (double)q;
    return c;
}
__device__ double d_p99(int n) {
    double r = 1.0;
    for (int q = 0; q < n; ++q) r *= 0.99;
    return r;
}
__global__ __launch_bounds__(256) void k_weights2(float* __restrict__ wW,
                                                  float* __restrict__ cW,
                                                  unsigned short* __restrict__ Tbf) {
    int idx = blockIdx.x * 256 + threadIdx.x;
    if (idx < NP * 64) {
        int p = idx >> 6, j = idx & 63;
        int m = 63 - j;
        wW[idx] = (p <= m) ? (float)((double)PROC_STD * d_binom(m, p) * d_p99(m - p)) : 0.f;
        cW[idx] = (p <= j) ? (float)(d_binom(j, p) * d_p99(j - p)) : 0.f;
    }
    if (idx < NP * 64 * 64) {
        int p = idx >> 12, j = (idx >> 6) & 63, i = idx & 63;
        int mm = i - 1 - j;
        float t = (mm >= p) ? (float)((double)PROC_STD * d_binom(mm, p) * d_p99(mm - p)) : 0.f;
        Tbf[idx] = f2bf(t);
    }
}

// ---------------- prep kernels ----------------
__global__ __launch_bounds__(256) void k_prep_A(const float* __restrict__ A,
                                                unsigned short* __restrict__ Ebf,
                                                float* __restrict__ M, float c1) {
    int idx = blockIdx.x * 256 + threadIdx.x;
    int r = idx >> 11, c = idx & 2047;
    float e = A[idx] - (r == c ? 0.99f : 0.0f);
    Ebf[idx] = f2bf(e);
    M[idx] = c1 * e;
}

__global__ __launch_bounds__(256) void k_prep_C(const float* __restrict__ C,
                                                unsigned short* __restrict__ Cbf) {
    int idx = blockIdx.x * 256 + threadIdx.x;
    Cbf[idx] = f2bf(C[idx]);
}

// P = bf16(cf4*E + cf5*E2 + cf6*E3)
__global__ __launch_bounds__(256) void k_combP(const unsigned short* __restrict__ Ebf,
                                               const unsigned short* __restrict__ E2,
                                               const unsigned short* __restrict__ E3,
                                               unsigned short* __restrict__ P,
                                               float c4, float c5, float c6) {
    int idx = blockIdx.x * 256 + threadIdx.x;
    P[idx] = f2bf(c4 * bf2f(Ebf[idx]) + c5 * bf2f(E2[idx]) + c6 * bf2f(E3[idx]));
}

// ---------------- pass1 reduction + pnbf emission (float4) -------------------------------
__global__ __launch_bounds__(256) void k_wsum(const float* __restrict__ pn,
                                              const float* __restrict__ wW,
                                              float* __restrict__ W,
                                              float* __restrict__ V32,
                                              unsigned short* __restrict__ Vbf,
                                              unsigned short* __restrict__ pnbf) {
    __shared__ float ws[NP * 64];
    int tid = threadIdx.x;
    for (int t = tid; t < NP * 64; t += 256) ws[t] = wW[t];
    __syncthreads();
    int bx = blockIdx.x;                 // 256 = 128 k * 2 d-chunks
    int k = bx >> 1, dc = bx & 1;
    int d0 = dc * 1024 + tid * 4;
    float acc[NP][4];
#pragma unroll
    for (int p = 0; p < NP; ++p)
#pragma unroll
        for (int u = 0; u < 4; ++u) acc[p][u] = 0.f;
    for (int j = 0; j < 64; ++j) {
        size_t gi = (size_t)(k * BLK + j) * SD + d0;
        float4 v = *(const float4*)(pn + gi);
        ushort4 b4;
        b4.x = f2bf(v.x); b4.y = f2bf(v.y); b4.z = f2bf(v.z); b4.w = f2bf(v.w);
        *(ushort4*)(pnbf + gi) = b4;
#pragma unroll
        for (int p = 0; p < NP; ++p) {
            float wv = ws[p * 64 + j];
            acc[p][0] += wv * v.x; acc[p][1] += wv * v.y;
            acc[p][2] += wv * v.z; acc[p][3] += wv * v.w;
        }
    }
#pragma unroll
    for (int p = 0; p < 6; ++p)
#pragma unroll
        for (int u = 0; u < 4; ++u)
            W[((size_t)p * SD + d0 + u) * KB + k] = acc[p][u];
#pragma unroll
    for (int u = 0; u < 4; ++u) {
        V32[(size_t)(d0 + u) * KB + k] = acc[6][u];
        Vbf[(size_t)(d0 + u) * KB + k] = f2bf(acc[6][u]);
    }
}

// ---------------- Horner step: V' = E @ V + W_p   (2048 x 128, K=2048) ----------------
__global__ __launch_bounds__(256) void k_horner(const unsigned short* __restrict__ Ebf,
                                                const unsigned short* __restrict__ Xbf,
                                                const float* __restrict__ Wp,
                                                float* __restrict__ X32o,
                                                unsigned short* __restrict__ Xbfo) {
    __shared__ __align__(16) unsigned short Al[32 * 72];
    __shared__ __align__(16) unsigned short Xt[32 * 72];
    int bx = blockIdx.x;
    int tM = (bx & 63) * 32, tN = (bx >> 6) * 32;
    int tid = threadIdx.x, lane = tid & 63, w = tid >> 6;
    int m16 = lane & 15, q = lane >> 4;
    int ar = tid >> 3, ao = (tid & 7) * 8;
    int xk = tid >> 2, xn = (tid & 3) * 8;
    int qb = xk >> 3;
    v4f acc = {0, 0, 0, 0};
    v8s av = *(const v8s*)(Ebf + (size_t)(tM + ar) * SD + ao);
    v8s xv = *(const v8s*)(Xbf + (size_t)xk * KB + tN + xn);
    int nl = (w & 1) * 16 + m16;
    int swn = (nl >> 3) & 3;
    int rl = (w >> 1) * 16 + m16;
    for (int k0 = 0; k0 < SD; k0 += 64) {
        *(v8s*)(Al + ar * 72 + ao) = av;
#pragma unroll
        for (int c = 0; c < 8; ++c) {
            int n = xn + c, sw = (n >> 3) & 3;
            Xt[n * 72 + (((qb ^ sw) << 3) | (xk & 7))] = xv[c];
        }
        __syncthreads();
        if (k0 + 64 < SD) {
            av = *(const v8s*)(Ebf + (size_t)(tM + ar) * SD + (k0 + 64) + ao);
            xv = *(const v8s*)(Xbf + (size_t)(k0 + 64 + xk) * KB + tN + xn);
        }
#pragma unroll
        for (int ch = 0; ch < 2; ++ch) {
            v8s a = *(const v8s*)(Al + rl * 72 + ch * 32 + q * 8);
            int q2 = ch * 4 + q;
            v8s b = *(const v8s*)(Xt + nl * 72 + ((q2 ^ swn) << 3));
            acc = __builtin_amdgcn_mfma_f32_16x16x32_bf16(a, b, acc, 0, 0, 0);
        }
        __syncthreads();
    }
#pragma unroll
    for (int j = 0; j < 4; ++j) {
        int r = tM + (w >> 1) * 16 + q * 4 + j;
        int kc = tN + (w & 1) * 16 + m16;
        int idx = r * KB + kc;
        float v = acc[j] + Wp[idx];
        X32o[idx] = v;
        Xbfo[idx] = f2bf(v);
    }
}

// ---------------- plain NN GEMM (2048^3, v5 64^2 core): out = bf16(A @ B) ----------------
__global__ __launch_bounds__(256) void k_gemmNN(const unsigned short* __restrict__ L,
                                                const unsigned short* __restrict__ X,
                                                unsigned short* __restrict__ Xout) {
    __shared__ __align__(16) unsigned short Al[64 * 40];
    __shared__ __align__(16) unsigned short Xt[64 * 40];
    int tid = threadIdx.x, lane = tid & 63, w = tid >> 6;
    int m16 = lane & 15, q = lane >> 4;
    int bx = blockIdx.x;
    int tM = (bx & 31) * 64, tN = (bx >> 5) * 64;
    int ar = tid >> 2, ao = (tid & 3) * 8;
    int xk = tid >> 3, xn = (tid & 7) * 8;
    int qb = xk >> 3;
    v4f acc[4] = {{0,0,0,0},{0,0,0,0},{0,0,0,0},{0,0,0,0}};

    v8s av = *(const v8s*)(L + (size_t)(tM + ar) * SD + ao);
    v8s xv = *(const v8s*)(X + (size_t)xk * SD + tN + xn);
    for (int k0 = 0; k0 < SD; k0 += 32) {
        *(v8s*)(Al + ar * 40 + ao) = av;
#pragma unroll
        for (int c = 0; c < 8; ++c) {
            int n = xn + c, sw = (n >> 3) & 3;
            Xt[n * 40 + (((qb ^ sw) << 3) | (xk & 7))] = xv[c];
        }
        __syncthreads();
        if (k0 + 32 < SD) {
            av = *(const v8s*)(L + (size_t)(tM + ar) * SD + (k0 + 32) + ao);
            xv = *(const v8s*)(X + (size_t)(k0 + 32 + xk) * SD + tN + xn);
        }
        v8s a = *(const v8s*)(Al + (w * 16 + m16) * 40 + q * 8);
#pragma unroll
        for (int c = 0; c < 4; ++c) {
            int nl = c * 16 + m16, swn = (nl >> 3) & 3;
            v8s b = *(const v8s*)(Xt + nl * 40 + ((q ^ swn) << 3));
            acc[c] = __builtin_amdgcn_mfma_f32_16x16x32_bf16(a, b, acc[c], 0, 0, 0);
        }
        __syncthreads();
    }
#pragma unroll
    for (int c = 0; c < 4; ++c) {
#pragma unroll
        for (int j = 0; j < 4; ++j) {
            int r = tM + w * 16 + q * 4 + j;
            int col = tN + c * 16 + m16;
            Xout[(size_t)r * SD + col] = f2bf(acc[c][j]);
        }
    }
}

// ---------------- M GEMM: M = (cf1 E in M32) + cf2 E2 + cf3 E3 + E3@P; Mbf = bf16(M) -----
__global__ __launch_bounds__(256) void k_gemm_M(const unsigned short* __restrict__ E3,
                                                const unsigned short* __restrict__ P,
                                                float* __restrict__ M32,
                                                const unsigned short* __restrict__ E2,
                                                unsigned short* __restrict__ Mbf,
                                                float c2, float c3) {
    __shared__ __align__(16) unsigned short Al[64 * 40];
    __shared__ __align__(16) unsigned short Xt[64 * 40];
    int tid = threadIdx.x, lane = tid & 63, w = tid >> 6;
    int m16 = lane & 15, q = lane >> 4;
    int bx = blockIdx.x;
    int tM = (bx & 31) * 64, tN = (bx >> 5) * 64;
    int ar = tid >> 2, ao = (tid & 3) * 8;
    int xk = tid >> 3, xn = (tid & 7) * 8;
    int qb = xk >> 3;
    v4f acc[4] = {{0,0,0,0},{0,0,0,0},{0,0,0,0},{0,0,0,0}};

    v8s av = *(const v8s*)(E3 + (size_t)(tM + ar) * SD + ao);
    v8s xv = *(const v8s*)(P + (size_t)xk * SD + tN + xn);
    for (int k0 = 0; k0 < SD; k0 += 32) {
        *(v8s*)(Al + ar * 40 + ao) = av;
#pragma unroll
        for (int c = 0; c < 8; ++c) {
            int n = xn + c, sw = (n >> 3) & 3;
            Xt[n * 40 + (((qb ^ sw) << 3) | (xk & 7))] = xv[c];
        }
        __syncthreads();
        if (k0 + 32 < SD) {
            av = *(const v8s*)(E3 + (size_t)(tM + ar) * SD + (k0 + 32) + ao);
            xv = *(const v8s*)(P + (size_t)(k0 + 32 + xk) * SD + tN + xn);
        }
        v8s a = *(const v8s*)(Al + (w * 16 + m16) * 40 + q * 8);
#pragma unroll
        for (int c = 0; c < 4; ++c) {
            int nl = c * 16 + m16, swn = (nl >> 3) & 3;
            v8s b = *(const v8s*)(Xt + nl * 40 + ((q ^ swn) << 3));
            acc[c] = __builtin_amdgcn_mfma_f32_16x16x32_bf16(a, b, acc[c], 0, 0, 0);
        }
        __syncthreads();
    }
#pragma unroll
    for (int c = 0; c < 4; ++c) {
#pragma unroll
        for (int j = 0; j < 4; ++j) {
            int r = tM + w * 16 + q * 4 + j;
            int col = tN + c * 16 + m16;
            size_t idx = (size_t)r * SD + col;
            float v = M32[idx] + c2 * bf2f(E2[idx]) + c3 * bf2f(E3[idx]) + acc[c][j];
            M32[idx] = v;
            Mbf[idx] = f2bf(v);
        }
    }
}

// ---------------- squaring GEMM: M' = 2a*M + Mbf@Mbf (fp32 in-place, bf16 out) -----------
__global__ __launch_bounds__(256) void k_gemm_sq(const unsigned short* __restrict__ Lbf,
                                                 float* __restrict__ M32,
                                                 unsigned short* __restrict__ Mbfo,
                                                 float twoa) {
    __shared__ __align__(16) unsigned short Al[64 * 40];
    __shared__ __align__(16) unsigned short Xt[64 * 40];
    int tid = threadIdx.x, lane = tid & 63, w = tid >> 6;
    int m16 = lane & 15, q = lane >> 4;
    int bx = blockIdx.x;
    int tM = (bx & 31) * 64, tN = (bx >> 5) * 64;
    int ar = tid >> 2, ao = (tid & 3) * 8;
    int xk = tid >> 3, xn = (tid & 7) * 8;
    int qb = xk >> 3;
    v4f acc[4] = {{0,0,0,0},{0,0,0,0},{0,0,0,0},{0,0,0,0}};

    v8s av = *(const v8s*)(Lbf + (size_t)(tM + ar) * SD + ao);
    v8s xv = *(const v8s*)(Lbf + (size_t)xk * SD + tN + xn);
    for (int k0 = 0; k0 < SD; k0 += 32) {
        *(v8s*)(Al + ar * 40 + ao) = av;
#pragma unroll
        for (int c = 0; c < 8; ++c) {
            int n = xn + c, sw = (n >> 3) & 3;
            Xt[n * 40 + (((qb ^ sw) << 3) | (xk & 7))] = xv[c];
        }
        __syncthreads();
        if (k0 + 32 < SD) {
            av = *(const v8s*)(Lbf + (size_t)(tM + ar) * SD + (k0 + 32) + ao);
            xv = *(const v8s*)(Lbf + (size_t)(k0 + 32 + xk) * SD + tN + xn);
        }
        v8s a = *(const v8s*)(Al + (w * 16 + m16) * 40 + q * 8);
#pragma unroll
        for (int c = 0; c < 4; ++c) {
            int nl = c * 16 + m16, swn = (nl >> 3) & 3;
            v8s b = *(const v8s*)(Xt + nl * 40 + ((q ^ swn) << 3));
            acc[c] = __builtin_amdgcn_mfma_f32_16x16x32_bf16(a, b, acc[c], 0, 0, 0);
        }
        __syncthreads();
    }
#pragma unroll
    for (int c = 0; c < 4; ++c) {
#pragma unroll
        for (int j = 0; j < 4; ++j) {
            int r = tM + w * 16 + q * 4 + j;
            int col = tN + c * 16 + m16;
            size_t idx = (size_t)r * SD + col;
            float v = twoa * M32[idx] + acc[c][j];   // in-place safe: owner-only RMW
            M32[idx] = v;
            Mbfo[idx] = f2bf(v);
        }
    }
}

// ---------------- scan init ----------------
__global__ __launch_bounds__(256) void k_scan_init(const float* __restrict__ s0,
                                                   const float* __restrict__ U,
                                                   float* __restrict__ S32,
                                                   unsigned short* __restrict__ Sbf0,
                                                   unsigned short* __restrict__ Sbf1) {
    int idx = blockIdx.x * 256 + threadIdx.x;     // 0 .. SD*KBP-1
    int d = idx / KBP, c = idx - d * KBP;
    if (c < 16) { Sbf0[idx] = 0; Sbf1[idx] = 0; return; }
    int k = c - 16;
    float v = (k == 0) ? s0[d] : U[(size_t)d * KB + (k - 1)];
    S32[(size_t)d * KB + k] = v;
    Sbf0[idx] = f2bf(v);
}

// ---------------- scan round: S'[:,k] = S[:,k] + a*S[:,k-sh] + Mr@S[:,k-sh] --------------
__global__ __launch_bounds__(256) void k_scan(const unsigned short* __restrict__ Mrbf,
                                              const unsigned short* __restrict__ Sbf_in,
                                              const float* __restrict__ S32_in,
                                              float* __restrict__ S32_out,
                                              unsigned short* __restrict__ Sbf_out,
                                              float ar, int shift) {
    __shared__ __align__(16) unsigned short Al[32 * 72];
    __shared__ __align__(16) unsigned short Xt[32 * 72];
    int bx = blockIdx.x;
    int tM = (bx & 63) * 32, tN = (bx >> 6) * 32;
    int tid = threadIdx.x, lane = tid & 63, w = tid >> 6;
    int m16 = lane & 15, q = lane >> 4;
    int ar_ = tid >> 3, ao = (tid & 7) * 8;
    int xk = tid >> 2, xn = (tid & 3) * 8;
    int qb = xk >> 3;
    int coff = tN + xn + 16 - shift;
    v4f acc = {0, 0, 0, 0};
    v8s av = *(const v8s*)(Mrbf + (size_t)(tM + ar_) * SD + ao);
    v8s xv = *(const v8s*)(Sbf_in + (size_t)xk * KBP + coff);
    int nl = (w & 1) * 16 + m16;
    int swn = (nl >> 3) & 3;
    int rl = (w >> 1) * 16 + m16;
    for (int k0 = 0; k0 < SD; k0 += 64) {
        *(v8s*)(Al + ar_ * 72 + ao) = av;
#pragma unroll
        for (int c = 0; c < 8; ++c) {
            int n = xn + c, sw = (n >> 3) & 3;
            Xt[n * 72 + (((qb ^ sw) << 3) | (xk & 7))] = xv[c];
        }
        __syncthreads();
        if (k0 + 64 < SD) {
            av = *(const v8s*)(Mrbf + (size_t)(tM + ar_) * SD + (k0 + 64) + ao);
            xv = *(const v8s*)(Sbf_in + (size_t)(k0 + 64 + xk) * KBP + coff);
        }
#pragma unroll
        for (int ch = 0; ch < 2; ++ch) {
            v8s a = *(const v8s*)(Al + rl * 72 + ch * 32 + q * 8);
            int q2 = ch * 4 + q;
            v8s b = *(const v8s*)(Xt + nl * 72 + ((q2 ^ swn) << 3));
            acc = __builtin_amdgcn_mfma_f32_16x16x32_bf16(a, b, acc, 0, 0, 0);
        }
        __syncthreads();
    }
#pragma unroll
    for (int j = 0; j < 4; ++j) {
        int r = tM + (w >> 1) * 16 + q * 4 + j;
        int kc = tN + (w & 1) * 16 + m16;
        int idx = r * KB + kc;
        int ksh = kc - shift;
        float v = S32_in[idx] + acc[j] + (ksh >= 0 ? ar * S32_in[r * KB + ksh] : 0.f);
        S32_out[idx] = v;
        Sbf_out[(size_t)r * KBP + kc + 16] = f2bf(v);
    }
}

// ---------------- 512-row GEMM, batched with per-y A offset + B select -------------------
// CE rounds: grid(256,y), tM=(bx&7)*64, tN=(bx>>3)*64;  H: grid(16,NPH), o32 out.
__global__ __launch_bounds__(256) void k_gemm2b(const unsigned short* __restrict__ A,
                                                size_t astride,
                                                const unsigned short* __restrict__ B1,
                                                const unsigned short* __restrict__ B2,
                                                int ldb,
                                                unsigned short* __restrict__ obf,
                                                float* __restrict__ o32,
                                                int ldo) {
    __shared__ __align__(16) unsigned short Al[64 * 40];
    __shared__ __align__(16) unsigned short Xt[64 * 40];
    int tid = threadIdx.x, lane = tid & 63, w = tid >> 6;
    int m16 = lane & 15, q = lane >> 4;
    int bx = blockIdx.x;
    int tM = (bx & 7) * 64, tN = (bx >> 3) * 64;
    A += (size_t)blockIdx.y * astride;
    const unsigned short* B = blockIdx.y ? B2 : B1;
    if (o32) o32 += (size_t)blockIdx.y * OD * ldo;
    if (obf) obf += (size_t)blockIdx.y * OD * (size_t)ldo;
    int ar = tid >> 2, ao = (tid & 3) * 8;
    int xk = tid >> 3, xn = (tid & 7) * 8;
    int qb = xk >> 3;
    v4f acc[4] = {{0,0,0,0},{0,0,0,0},{0,0,0,0},{0,0,0,0}};

    v8s av = *(const v8s*)(A + (size_t)(tM + ar) * SD + ao);
    v8s xv = *(const v8s*)(B + (size_t)xk * ldb + tN + xn);
    for (int k0 = 0; k0 < SD; k0 += 32) {
        *(v8s*)(Al + ar * 40 + ao) = av;
#pragma unroll
        for (int c = 0; c < 8; ++c) {
            int n = xn + c, sw = (n >> 3) & 3;
            Xt[n * 40 + (((qb ^ sw) << 3) | (xk & 7))] = xv[c];
        }
        __syncthreads();
        if (k0 + 32 < SD) {
            av = *(const v8s*)(A + (size_t)(tM + ar) * SD + (k0 + 32) + ao);
            xv = *(const v8s*)(B + (size_t)(k0 + 32 + xk) * ldb + tN + xn);
        }
        v8s a = *(const v8s*)(Al + (w * 16 + m16) * 40 + q * 8);
#pragma unroll
        for (int c = 0; c < 4; ++c) {
            int nl = c * 16 + m16, swn = (nl >> 3) & 3;
            v8s b = *(const v8s*)(Xt + nl * 40 + ((q ^ swn) << 3));
            acc[c] = __builtin_amdgcn_mfma_f32_16x16x32_bf16(a, b, acc[c], 0, 0, 0);
        }
        __syncthreads();
    }
#pragma unroll
    for (int c = 0; c < 4; ++c) {
#pragma unroll
        for (int j = 0; j < 4; ++j) {
            int r = tM + w * 16 + q * 4 + j;
            int col = tN + c * 16 + m16;
            float v = acc[c][j];
            if (o32) o32[(size_t)r * ldo + col] = v;
            if (obf) obf[(size_t)r * ldo + col] = f2bf(v);
        }
    }
}

// ---------------- Pall = CEcat(2560x2048) @ pnbf(8192x2048)^T (128^2 core, 5 blk/CU) -----
__global__ __launch_bounds__(256) void k_g128(const unsigned short* __restrict__ Aptr, int lda,
                                              const unsigned short* __restrict__ Bptr, int ldb,
                                              int mtiles,
                                              unsigned short* __restrict__ obf, size_t ldo) {
    __shared__ __align__(16) unsigned short As[128 * 32];
    __shared__ __align__(16) unsigned short Bs[128 * 32];
    int tid = threadIdx.x, lane = tid & 63, w = tid >> 6;
    int bid = blockIdx.x;
    int npx = (int)(gridDim.x >> 3) / mtiles;
    int mT = (bid >> 3) % mtiles;
    int nT = (bid & 7) * npx + (bid >> 3) / mtiles;
    int tM = mT * 128, tN = nT * 128;
    int wr = w >> 1, wc = w & 1;
    int m16 = lane & 15, q = lane >> 4;
    int srow = lane >> 2, sk8 = lane & 3;
    const unsigned short* ga0 = Aptr + (size_t)(tM + w * 16 + srow) * lda + sk8 * 8;
    const unsigned short* ga1 = ga0 + (size_t)64 * lda;
    const unsigned short* gb0 = Bptr + (size_t)(tN + w * 16 + srow) * ldb + sk8 * 8;
    const unsigned short* gb1 = gb0 + (size_t)64 * ldb;
    unsigned short* la0 = As + w * 512;
    unsigned short* la1 = As + 2048 + w * 512;
    unsigned short* lb0 = Bs + w * 512;
    unsigned short* lb1 = Bs + 2048 + w * 512;

    v4f acc[4][4];
#pragma unroll
    for (int mi = 0; mi < 4; ++mi)
#pragma unroll
        for (int ni = 0; ni < 4; ++ni) acc[mi][ni] = (v4f){0, 0, 0, 0};

    GLD16(ga0, la0); GLD16(ga1, la1); GLD16(gb0, lb0); GLD16(gb1, lb1);
    ga0 += 32; ga1 += 32; gb0 += 32; gb1 += 32;
    __syncthreads();

    int arow = (wr * 64 + m16) * 32 + q * 8;
    int brow = (wc * 64 + m16) * 32 + q * 8;
    for (int k0 = 0; k0 < SD; k0 += 32) {
        v8s a[4], b[4];
#pragma unroll
        for (int mi = 0; mi < 4; ++mi) a[mi] = *(const v8s*)(As + arow + mi * 512);
#pragma unroll
        for (int ni = 0; ni < 4; ++ni) b[ni] = *(const v8s*)(Bs + brow + ni * 512);
        __syncthreads();
        if (k0 + 32 < SD) {
            GLD16(ga0, la0); GLD16(ga1, la1); GLD16(gb0, lb0); GLD16(gb1, lb1);
            ga0 += 32; ga1 += 32; gb0 += 32; gb1 += 32;
        }
#pragma unroll
        for (int mi = 0; mi < 4; ++mi)
#pragma unroll
            for (int ni = 0; ni < 4; ++ni)
                acc[mi][ni] = __builtin_amdgcn_mfma_f32_16x16x32_bf16(a[mi], b[ni],
                                                                      acc[mi][ni], 0, 0, 0);
        __syncthreads();
    }

#pragma unroll
    for (int mi = 0; mi < 4; ++mi)
#pragma unroll
        for (int ni = 0; ni < 4; ++ni)
#pragma unroll
            for (int j = 0; j < 4; ++j) {
                int row = tM + wr * 64 + mi * 16 + q * 4 + j;
                int col = tN + wc * 64 + ni * 16 + m16;
                obf[(size_t)row * ldo + col] = f2bf(acc[mi][ni][j]);
            }
}

// ---------------- final: out[64k+i][o] = Pall_p(o,:)@T_p(:,i) + hom + noise --------------
__global__ __launch_bounds__(256) void k_final2(const unsigned short* __restrict__ P,
                                                const unsigned short* __restrict__ Tbf,
                                                const float* __restrict__ H,
                                                const float* __restrict__ cW,
                                                const float* __restrict__ on,
                                                float* __restrict__ out) {
    __shared__ __align__(16) float obsT[64][65];
    unsigned short* Al = (unsigned short*)obsT;
    unsigned short* Xt = Al + 64 * 40;
    int bx = blockIdx.x;                 // 1024 = 128 kb * 8 o-tiles
    int kb = bx >> 3, ob = bx & 7;
    int o0 = ob * 64;
    int tid = threadIdx.x, lane = tid & 63, w = tid >> 6;
    int m16 = lane & 15, q = lane >> 4;
    int ar = tid >> 2, ao = (tid & 3) * 8;
    int xk = tid >> 3, xn = (tid & 7) * 8;
    int qb = xk >> 3;
    v4f acc[4] = {{0,0,0,0},{0,0,0,0},{0,0,0,0},{0,0,0,0}};
    const unsigned short* Abase = P + (size_t)kb * 64;

    v8s av = *(const v8s*)(Abase + (size_t)(o0 + ar) * NT + ao);
    v8s xv = *(const v8s*)(Tbf + xk * 64 + xn);
    for (int kc = 0; kc < 2 * NPN; ++kc) {
        *(v8s*)(Al + ar * 40 + ao) = av;
#pragma unroll
        for (int c = 0; c < 8; ++c) {
            int n = xn + c, sw = (n >> 3) & 3;
            Xt[n * 40 + (((qb ^ sw) << 3) | (xk & 7))] = xv[c];
        }
        __syncthreads();
        if (kc + 1 < 2 * NPN) {
            int p = (kc + 1) >> 1, j0 = ((kc + 1) & 1) * 32;
            av = *(const v8s*)(Abase + (size_t)(p * OD + o0 + ar) * NT + j0 + ao);
            xv = *(const v8s*)(Tbf + p * 4096 + (j0 + xk) * 64 + xn);
        }
        v8s a = *(const v8s*)(Al + (w * 16 + m16) * 40 + q * 8);
#pragma unroll
        for (int c = 0; c < 4; ++c) {
            int nl = c * 16 + m16, swn = (nl >> 3) & 3;
            v8s b = *(const v8s*)(Xt + nl * 40 + ((q ^ swn) << 3));
            acc[c] = __builtin_amdgcn_mfma_f32_16x16x32_bf16(a, b, acc[c], 0, 0, 0);
        }
        __syncthreads();
    }
#pragma unroll
    for (int c = 0; c < 4; ++c)
#pragma unroll
        for (int j = 0; j < 4; ++j)
            obsT[w * 16 + q * 4 + j][c * 16 + m16] = acc[c][j];
    __syncthreads();
    int g = tid >> 6;
    float Hv[NPH];
#pragma unroll
    for (int p = 0; p < NPH; ++p)
        Hv[p] = H[((size_t)p * OD + o0 + lane) * KB + kb];
#pragma unroll
    for (int r = 0; r < 16; ++r) {
        int trow = r * 4 + g;
        float a2 = obsT[lane][trow];
#pragma unroll
        for (int p = 0; p < NPH; ++p) a2 += cW[p * 64 + trow] * Hv[p];
        size_t oidx = (size_t)(kb * 64 + trow) * OD + o0 + lane;
        out[oidx] = a2 + OBS_STD * on[oidx];
    }
}

// ---------------- host ----------------
extern "C" void kernel_launch(void* const* d_in, const int* in_sizes, int n_in,
                              void* d_out, int out_size, void* d_ws, size_t ws_size,
                              hipStream_t stream) {
    const float* s0 = (const float*)d_in[0];
    const float* A  = (const float*)d_in[1];
    const float* C  = (const float*)d_in[2];
    const float* pn = (const float*)d_in[3];
    const float* on = (const float*)d_in[4];
    float* out = (float*)d_out;

    char* p = (char*)d_ws;
    auto take = [&](size_t n) { char* r = p; p += (n + 255) & ~(size_t)255; return r; };
    unsigned short* Ebf = (unsigned short*)take((size_t)SD * SD * 2);   // E -> later Mbf
    unsigned short* CEall = (unsigned short*)take((size_t)NPH * OD * SD * 2);
    // contiguous region M+Xp0+Xp1+Xp2 = 41,943,040 B == Pall (2560*8192*2) exactly
    float* M            = (float*)take((size_t)SD * SD * 4);
    unsigned short* Xp0 = (unsigned short*)take((size_t)SD * SD * 2);   // E2 -> sq ping
    unsigned short* Xp1 = (unsigned short*)take((size_t)SD * SD * 2);   // E3
    unsigned short* Xp2 = (unsigned short*)take((size_t)SD * SD * 2);   // P
    unsigned short* Pall = (unsigned short*)M;                          // after scan
    float* W      = (float*)take((size_t)6 * SD * KB * 4);
    float* V32[2] = {(float*)take((size_t)SD * KB * 4), (float*)take((size_t)SD * KB * 4)};
    unsigned short* Vbf[2] = {(unsigned short*)take((size_t)SD * KB * 2),
                              (unsigned short*)take((size_t)SD * KB * 2)};
    float* SC32[2] = {(float*)take((size_t)SD * KB * 4), (float*)take((size_t)SD * KB * 4)};
    unsigned short* SCbf[2] = {(unsigned short*)take((size_t)SD * KBP * 2),
                               (unsigned short*)take((size_t)SD * KBP * 2)};
    float* wW   = (float*)take((size_t)NP * 64 * 4);
    float* cW   = (float*)take((size_t)NP * 64 * 4);
    unsigned short* Tbf = (unsigned short*)take((size_t)NP * 64 * 64 * 2);
    unsigned short* pnbf = (unsigned short*)take((size_t)SD * NT * 2);
    float* H    = (float*)take((size_t)NPH * OD * KB * 4);

    double pw[65]; pw[0] = 1.0;
    for (int m = 1; m <= 64; ++m) pw[m] = pw[m - 1] * 0.99;
    const double bin[7] = {1, 64, 2016, 41664, 635376, 7624512, 74974368};
    float cf[7];
    for (int m = 1; m <= 6; ++m) cf[m] = (float)(bin[m] * pw[64 - m]);
    float a64 = (float)pw[64];

    k_weights2<<<NP * 64 * 64 / 256, 256, 0, stream>>>(wW, cW, Tbf);
    k_prep_A<<<SD * SD / 256, 256, 0, stream>>>(A, Ebf, M, cf[1]);
    k_prep_C<<<OD * SD / 256, 256, 0, stream>>>(C, CEall);    // CE_0 = bf16(C)

    // E2 first (old 64^2 core), then CE chain in 3 batched rounds:
    //   {CE1=C@E, CE2=C@E2}, {CE3=CE1@E2, CE4=CE2@E2}, CE5=CE3@E2
    k_gemmNN<<<1024, 256, 0, stream>>>(Ebf, Ebf, Xp0);        // E2
    k_gemm2b<<<dim3(256, 2), 256, 0, stream>>>(CEall, 0, Ebf, Xp0, SD,
                                               CEall + (size_t)OD * SD, (float*)nullptr, SD);
    k_gemm2b<<<dim3(256, 2), 256, 0, stream>>>(CEall + (size_t)OD * SD, (size_t)OD * SD,
                                               Xp0, Xp0, SD,
                                               CEall + (size_t)3 * OD * SD, (float*)nullptr, SD);
    k_gemm2b<<<dim3(256, 1), 256, 0, stream>>>(CEall + (size_t)3 * OD * SD, 0, Xp0, Xp0, SD,
                                               CEall + (size_t)5 * OD * SD, (float*)nullptr, SD);

    // E3, P combo
    k_gemmNN<<<1024, 256, 0, stream>>>(Ebf, Xp0, Xp1);        // E3
    k_combP<<<SD * SD / 256, 256, 0, stream>>>(Ebf, Xp0, Xp1, Xp2, cf[4], cf[5], cf[6]);

    // pass 1: u_k via Horner; also emits pnbf[t][d] (float4)
    k_wsum<<<256, 256, 0, stream>>>(pn, wW, W, V32[0], Vbf[0], pnbf);
    int cur = 0;
    for (int pp = 5; pp >= 0; --pp) {
        k_horner<<<256, 256, 0, stream>>>(Ebf, Vbf[cur], W + (size_t)pp * SD * KB,
                                          V32[cur ^ 1], Vbf[cur ^ 1]);
        cur ^= 1;
    }  // cur == 0: V32[0] = u_k in [d][k]

    // M = cf1 E + cf2 E2 + cf3 E3 + E3@P  (fp32 into M, bf16 into Ebf = Mbf)
    k_gemm_M<<<1024, 256, 0, stream>>>(Xp1, Xp2, M, Xp0, Ebf, cf[2], cf[3]);

    // pass 2: 5-round matrix scan (shifts 1,2,4,8,16); squarings via old 64^2 core
    k_scan_init<<<SD * KBP / 256, 256, 0, stream>>>(s0, V32[cur], SC32[0], SCbf[0], SCbf[1]);
    unsigned short* MbfA = Ebf;
    unsigned short* MbfB = Xp0;
    float a = a64;
    int sc = 0;
    for (int r = 0; r < 5; ++r) {
        k_scan<<<256, 256, 0, stream>>>(MbfA, SCbf[sc], SC32[sc],
                                        SC32[sc ^ 1], SCbf[sc ^ 1], a, 1 << r);
        sc ^= 1;
        if (r < 4) {
            k_gemm_sq<<<1024, 256, 0, stream>>>(MbfA, M, MbfB, 2.f * a);
            unsigned short* t = MbfA; MbfA = MbfB; MbfB = t;
            a = a * a;
        }
    }  // SCbf[sc] = padded bf16 boundary states

    // pass 3: H[p] = CE_p @ S_bound (batched over p)
    k_gemm2b<<<dim3(16, NPH), 256, 0, stream>>>(CEall, (size_t)OD * SD,
                                                SCbf[sc] + 16, SCbf[sc] + 16, KBP,
                                                (unsigned short*)nullptr, H, KB);
    // Pall = CEcat @ pnbf^T  (M/Xp region dead -> aliased; XCD-swizzled 128^2 core)
    k_g128<<<1280, 256, 0, stream>>>(CEall, SD, pnbf, SD, 20, Pall, (size_t)NT);
    k_final2<<<1024, 256, 0, stream>>>(Pall, Tbf, H, cW, on, out);
}

// Round 7
// 787.825 us; speedup vs baseline: 6.1956x; 1.2740x over previous
//
#include <hip/hip_runtime.h>

// SimpleStateSpaceModel restructure v8:
//   v7 accounting: ~670us kernel work vs 1003us wall -> ~300us launch/drain gaps (30 dispatches).
//   (1) 17 launches via fusion (branch-on-blockIdx, proven bodies as device fns):
//       [E2+CE1] [E3+CE2] [gemm_M+Y-batch] [CE34+Z2] [CE5+Z1] [sq+scan]x3 [Pall+H] [prepAll]
//   (2) squarings 4->3: M4 (norm ~3e-3) matrix dropped; scan round 4 = scalar elementwise.
//   (3) horner 6->4 rounds: u = Y0 + E2(Y1 + E2(Y2 + E2 W6)), Y_j batched in one launch.
//   k_g128 bank-"conflict" theory REJECTED by arithmetic (reads are bijective; m97 itself
//   counts 1.7e7). Mbf gets a dedicated buffer (removes Ebf alias race with Y's E reads).

#define SD 2048      // state dim
#define OD 512       // obs dim
#define NT 8192      // steps
#define BLK 64       // steps per block
#define KB 128       // number of blocks = NT/BLK
#define KBP (KB+16)  // padded column stride for scan bf16 buffers
#define NP 7         // binomial terms p=0..6
#define NPH 6        // homogeneous obs terms p=0..5
#define NPN 5        // noise obs terms p=0..4
#define PROC_STD 0.31622776601683794f
#define OBS_STD  0.7071067811865476f

typedef __attribute__((ext_vector_type(8))) short v8s;
typedef __attribute__((ext_vector_type(4))) float v4f;

__device__ __forceinline__ unsigned short f2bf(float f) {
    union { float f; unsigned int u; } v; v.f = f;
    unsigned int r = v.u + 0x7fffu + ((v.u >> 16) & 1u);
    return (unsigned short)(r >> 16);
}
__device__ __forceinline__ float bf2f(unsigned short u) {
    union { unsigned int ui; float f; } cv; cv.ui = (unsigned int)u << 16;
    return cv.f;
}

#define GLD16(g, l) __builtin_amdgcn_global_load_lds( \
    (const __attribute__((address_space(1))) unsigned int*)(g), \
    (__attribute__((address_space(3))) unsigned int*)(l), 16, 0, 0)

// ================= device bodies =================

// 64^2-tile GEMM body over K=SD. mode 0: obf=bf16(acc) @ldo; 1: o32=acc @ldo;
// 2: M-combine (o32[iS]+=c1*X1+c2*X2+acc, obf=bf16) @SD; 3: squaring (o32[iS]=c1*o32+acc) @SD.
__device__ __forceinline__ void body_g64(unsigned short* SH,
        const unsigned short* __restrict__ A,
        const unsigned short* __restrict__ B, int ldb,
        int tM, int tN, int mode,
        unsigned short* __restrict__ obf, int ldo,
        float* __restrict__ o32,
        const unsigned short* __restrict__ X1,
        const unsigned short* __restrict__ X2,
        float c1, float c2) {
    unsigned short* Al = SH;
    unsigned short* Xt = SH + 64 * 40;
    int tid = threadIdx.x, lane = tid & 63, w = tid >> 6;
    int m16 = lane & 15, q = lane >> 4;
    int ar = tid >> 2, ao = (tid & 3) * 8;
    int xk = tid >> 3, xn = (tid & 7) * 8;
    int qb = xk >> 3;
    v4f acc[4] = {{0,0,0,0},{0,0,0,0},{0,0,0,0},{0,0,0,0}};

    v8s av = *(const v8s*)(A + (size_t)(tM + ar) * SD + ao);
    v8s xv = *(const v8s*)(B + (size_t)xk * ldb + tN + xn);
    for (int k0 = 0; k0 < SD; k0 += 32) {
        *(v8s*)(Al + ar * 40 + ao) = av;
#pragma unroll
        for (int c = 0; c < 8; ++c) {
            int n = xn + c, sw = (n >> 3) & 3;
            Xt[n * 40 + (((qb ^ sw) << 3) | (xk & 7))] = xv[c];
        }
        __syncthreads();
        if (k0 + 32 < SD) {
            av = *(const v8s*)(A + (size_t)(tM + ar) * SD + (k0 + 32) + ao);
            xv = *(const v8s*)(B + (size_t)(k0 + 32 + xk) * ldb + tN + xn);
        }
        v8s a = *(const v8s*)(Al + (w * 16 + m16) * 40 + q * 8);
#pragma unroll
        for (int c = 0; c < 4; ++c) {
            int nl = c * 16 + m16, swn = (nl >> 3) & 3;
            v8s b = *(const v8s*)(Xt + nl * 40 + ((q ^ swn) << 3));
            acc[c] = __builtin_amdgcn_mfma_f32_16x16x32_bf16(a, b, acc[c], 0, 0, 0);
        }
        __syncthreads();
    }
#pragma unroll
    for (int c = 0; c < 4; ++c)
#pragma unroll
        for (int j = 0; j < 4; ++j) {
            int r = tM + w * 16 + q * 4 + j;
            int col = tN + c * 16 + m16;
            float v = acc[c][j];
            if (mode == 2) {
                size_t iS = (size_t)r * SD + col;
                v += o32[iS] + c1 * bf2f(X1[iS]) + c2 * bf2f(X2[iS]);
                o32[iS] = v;
                obf[iS] = f2bf(v);
            } else if (mode == 3) {
                size_t iS = (size_t)r * SD + col;
                v = c1 * o32[iS] + v;
                o32[iS] = v;
                obf[iS] = f2bf(v);
            } else if (mode == 1) {
                o32[(size_t)r * ldo + col] = v;
            } else {
                obf[(size_t)r * ldo + col] = f2bf(v);
            }
        }
}

// Horner body: out = A(2048x2048 bf16) @ Xbf(2048x128) + Wp ; dual write (bf16 optional)
__device__ __forceinline__ void body_horner(unsigned short* SH, int bx,
        const unsigned short* __restrict__ Abf,
        const unsigned short* __restrict__ Xbf,
        const float* __restrict__ Wp,
        float* __restrict__ X32o,
        unsigned short* __restrict__ Xbfo) {
    unsigned short* Al = SH;
    unsigned short* Xt = SH + 32 * 72;
    int tM = (bx & 63) * 32, tN = (bx >> 6) * 32;
    int tid = threadIdx.x, lane = tid & 63, w = tid >> 6;
    int m16 = lane & 15, q = lane >> 4;
    int ar = tid >> 3, ao = (tid & 7) * 8;
    int xk = tid >> 2, xn = (tid & 3) * 8;
    int qb = xk >> 3;
    v4f acc = {0, 0, 0, 0};
    v8s av = *(const v8s*)(Abf + (size_t)(tM + ar) * SD + ao);
    v8s xv = *(const v8s*)(Xbf + (size_t)xk * KB + tN + xn);
    int nl = (w & 1) * 16 + m16;
    int swn = (nl >> 3) & 3;
    int rl = (w >> 1) * 16 + m16;
    for (int k0 = 0; k0 < SD; k0 += 64) {
        *(v8s*)(Al + ar * 72 + ao) = av;
#pragma unroll
        for (int c = 0; c < 8; ++c) {
            int n = xn + c, sw = (n >> 3) & 3;
            Xt[n * 72 + (((qb ^ sw) << 3) | (xk & 7))] = xv[c];
        }
        __syncthreads();
        if (k0 + 64 < SD) {
            av = *(const v8s*)(Abf + (size_t)(tM + ar) * SD + (k0 + 64) + ao);
            xv = *(const v8s*)(Xbf + (size_t)(k0 + 64 + xk) * KB + tN + xn);
        }
#pragma unroll
        for (int ch = 0; ch < 2; ++ch) {
            v8s a = *(const v8s*)(Al + rl * 72 + ch * 32 + q * 8);
            int q2 = ch * 4 + q;
            v8s b = *(const v8s*)(Xt + nl * 72 + ((q2 ^ swn) << 3));
            acc = __builtin_amdgcn_mfma_f32_16x16x32_bf16(a, b, acc, 0, 0, 0);
        }
        __syncthreads();
    }
#pragma unroll
    for (int j = 0; j < 4; ++j) {
        int r = tM + (w >> 1) * 16 + q * 4 + j;
        int kc = tN + (w & 1) * 16 + m16;
        int idx = r * KB + kc;
        float v = acc[j] + Wp[idx];
        X32o[idx] = v;
        if (Xbfo) Xbfo[idx] = f2bf(v);
    }
}

// Scan body: S'[:,k] = S[:,k] + ar*S[:,k-sh] + Mr@S[:,k-sh]
__device__ __forceinline__ void body_scan(unsigned short* SH, int bx,
        const unsigned short* __restrict__ Mrbf,
        const unsigned short* __restrict__ Sbf_in,
        const float* __restrict__ S32_in,
        float* __restrict__ S32_out,
        unsigned short* __restrict__ Sbf_out,
        float ar, int shift) {
    unsigned short* Al = SH;
    unsigned short* Xt = SH + 32 * 72;
    int tM = (bx & 63) * 32, tN = (bx >> 6) * 32;
    int tid = threadIdx.x, lane = tid & 63, w = tid >> 6;
    int m16 = lane & 15, q = lane >> 4;
    int ar_ = tid >> 3, ao = (tid & 7) * 8;
    int xk = tid >> 2, xn = (tid & 3) * 8;
    int qb = xk >> 3;
    int coff = tN + xn + 16 - shift;
    v4f acc = {0, 0, 0, 0};
    v8s av = *(const v8s*)(Mrbf + (size_t)(tM + ar_) * SD + ao);
    v8s xv = *(const v8s*)(Sbf_in + (size_t)xk * KBP + coff);
    int nl = (w & 1) * 16 + m16;
    int swn = (nl >> 3) & 3;
    int rl = (w >> 1) * 16 + m16;
    for (int k0 = 0; k0 < SD; k0 += 64) {
        *(v8s*)(Al + ar_ * 72 + ao) = av;
#pragma unroll
        for (int c = 0; c < 8; ++c) {
            int n = xn + c, sw = (n >> 3) & 3;
            Xt[n * 72 + (((qb ^ sw) << 3) | (xk & 7))] = xv[c];
        }
        __syncthreads();
        if (k0 + 64 < SD) {
            av = *(const v8s*)(Mrbf + (size_t)(tM + ar_) * SD + (k0 + 64) + ao);
            xv = *(const v8s*)(Sbf_in + (size_t)(k0 + 64 + xk) * KBP + coff);
        }
#pragma unroll
        for (int ch = 0; ch < 2; ++ch) {
            v8s a = *(const v8s*)(Al + rl * 72 + ch * 32 + q * 8);
            int q2 = ch * 4 + q;
            v8s b = *(const v8s*)(Xt + nl * 72 + ((q2 ^ swn) << 3));
            acc = __builtin_amdgcn_mfma_f32_16x16x32_bf16(a, b, acc, 0, 0, 0);
        }
        __syncthreads();
    }
#pragma unroll
    for (int j = 0; j < 4; ++j) {
        int r = tM + (w >> 1) * 16 + q * 4 + j;
        int kc = tN + (w & 1) * 16 + m16;
        int idx = r * KB + kc;
        int ksh = kc - shift;
        float v = S32_in[idx] + acc[j] + (ksh >= 0 ? ar * S32_in[r * KB + ksh] : 0.f);
        S32_out[idx] = v;
        Sbf_out[(size_t)r * KBP + kc + 16] = f2bf(v);
    }
}

// 128^2-tile GEMM (m97 structure), XCD-swizzled; used only for Pall (2560x8192, K=2048)
__device__ __forceinline__ void body_g128(unsigned short* SH, int bid,
        const unsigned short* __restrict__ Aptr, int lda,
        const unsigned short* __restrict__ Bptr, int ldb,
        int mtiles, int npx,
        unsigned short* __restrict__ obf, size_t ldo) {
    unsigned short* As = SH;
    unsigned short* Bs = SH + 4096;
    int tid = threadIdx.x, lane = tid & 63, w = tid >> 6;
    int mT = (bid >> 3) % mtiles;
    int nT = (bid & 7) * npx + (bid >> 3) / mtiles;
    int tM = mT * 128, tN = nT * 128;
    int wr = w >> 1, wc = w & 1;
    int m16 = lane & 15, q = lane >> 4;
    int srow = lane >> 2, sk8 = lane & 3;
    const unsigned short* ga0 = Aptr + (size_t)(tM + w * 16 + srow) * lda + sk8 * 8;
    const unsigned short* ga1 = ga0 + (size_t)64 * lda;
    const unsigned short* gb0 = Bptr + (size_t)(tN + w * 16 + srow) * ldb + sk8 * 8;
    const unsigned short* gb1 = gb0 + (size_t)64 * ldb;
    unsigned short* la0 = As + w * 512;
    unsigned short* la1 = As + 2048 + w * 512;
    unsigned short* lb0 = Bs + w * 512;
    unsigned short* lb1 = Bs + 2048 + w * 512;

    v4f acc[4][4];
#pragma unroll
    for (int mi = 0; mi < 4; ++mi)
#pragma unroll
        for (int ni = 0; ni < 4; ++ni) acc[mi][ni] = (v4f){0, 0, 0, 0};

    GLD16(ga0, la0); GLD16(ga1, la1); GLD16(gb0, lb0); GLD16(gb1, lb1);
    ga0 += 32; ga1 += 32; gb0 += 32; gb1 += 32;
    __syncthreads();

    int arow = (wr * 64 + m16) * 32 + q * 8;
    int brow = (wc * 64 + m16) * 32 + q * 8;
    for (int k0 = 0; k0 < SD; k0 += 32) {
        v8s a[4], b[4];
#pragma unroll
        for (int mi = 0; mi < 4; ++mi) a[mi] = *(const v8s*)(As + arow + mi * 512);
#pragma unroll
        for (int ni = 0; ni < 4; ++ni) b[ni] = *(const v8s*)(Bs + brow + ni * 512);
        __syncthreads();
        if (k0 + 32 < SD) {
            GLD16(ga0, la0); GLD16(ga1, la1); GLD16(gb0, lb0); GLD16(gb1, lb1);
            ga0 += 32; ga1 += 32; gb0 += 32; gb1 += 32;
        }
#pragma unroll
        for (int mi = 0; mi < 4; ++mi)
#pragma unroll
            for (int ni = 0; ni < 4; ++ni)
                acc[mi][ni] = __builtin_amdgcn_mfma_f32_16x16x32_bf16(a[mi], b[ni],
                                                                      acc[mi][ni], 0, 0, 0);
        __syncthreads();
    }
#pragma unroll
    for (int mi = 0; mi < 4; ++mi)
#pragma unroll
        for (int ni = 0; ni < 4; ++ni)
#pragma unroll
            for (int j = 0; j < 4; ++j) {
                int row = tM + wr * 64 + mi * 16 + q * 4 + j;
                int col = tN + wc * 64 + ni * 16 + m16;
                obf[(size_t)row * ldo + col] = f2bf(acc[mi][ni][j]);
            }
}

// ================= kernels =================

__device__ double d_binom(int m, int p) {
    if (p < 0 || p > m) return 0.0;
    double c = 1.0;
    for (int q = 1; q <= p; ++q) c = c * (double)(m - p + q) / (double)q;
    return c;
}
__device__ double d_p99(int n) {
    double r = 1.0;
    for (int q = 0; q < n; ++q) r *= 0.99;
    return r;
}

// fused prep: [0,16384) prep_A ; [16384,20480) prep_C ; [20480,20592) weights
__global__ __launch_bounds__(256) void k_prepAll(const float* __restrict__ A,
                                                 const float* __restrict__ C,
                                                 unsigned short* __restrict__ Ebf,
                                                 float* __restrict__ M, float c1,
                                                 unsigned short* __restrict__ Cbf,
                                                 float* __restrict__ wW,
                                                 float* __restrict__ cW,
                                                 unsigned short* __restrict__ Tbf) {
    int bid = blockIdx.x;
    if (bid < 16384) {
        int idx = bid * 256 + threadIdx.x;
        int r = idx >> 11, c = idx & 2047;
        float e = A[idx] - (r == c ? 0.99f : 0.0f);
        Ebf[idx] = f2bf(e);
        M[idx] = c1 * e;
    } else if (bid < 20480) {
        int idx = (bid - 16384) * 256 + threadIdx.x;
        Cbf[idx] = f2bf(C[idx]);
    } else {
        int idx = (bid - 20480) * 256 + threadIdx.x;
        if (idx < NP * 64) {
            int p = idx >> 6, j = idx & 63;
            int m = 63 - j;
            wW[idx] = (p <= m) ? (float)((double)PROC_STD * d_binom(m, p) * d_p99(m - p)) : 0.f;
            cW[idx] = (p <= j) ? (float)(d_binom(j, p) * d_p99(j - p)) : 0.f;
        }
        if (idx < NP * 64 * 64) {
            int p = idx >> 12, j = (idx >> 6) & 63, i = idx & 63;
            int mm = i - 1 - j;
            float t = (mm >= p) ? (float)((double)PROC_STD * d_binom(mm, p) * d_p99(mm - p)) : 0.f;
            Tbf[idx] = f2bf(t);
        }
    }
}

// pass1 reduction + pnbf: W32[j]=acc[2j] (fp32), Wbf[j]=bf16(acc[2j+1]), Vbf=bf16(acc[6])
__global__ __launch_bounds__(256) void k_wsum(const float* __restrict__ pn,
                                              const float* __restrict__ wW,
                                              float* __restrict__ W32,
                                              unsigned short* __restrict__ Wbf,
                                              unsigned short* __restrict__ Vbf,
                                              unsigned short* __restrict__ pnbf) {
    __shared__ float ws[NP * 64];
    int tid = threadIdx.x;
    for (int t = tid; t < NP * 64; t += 256) ws[t] = wW[t];
    __syncthreads();
    int bx = blockIdx.x;                 // 256 = 128 k * 2 d-chunks
    int k = bx >> 1, dc = bx & 1;
    int d0 = dc * 1024 + tid * 4;
    float acc[NP][4];
#pragma unroll
    for (int p = 0; p < NP; ++p)
#pragma unroll
        for (int u = 0; u < 4; ++u) acc[p][u] = 0.f;
    for (int j = 0; j < 64; ++j) {
        size_t gi = (size_t)(k * BLK + j) * SD + d0;
        float4 v = *(const float4*)(pn + gi);
        ushort4 b4;
        b4.x = f2bf(v.x); b4.y = f2bf(v.y); b4.z = f2bf(v.z); b4.w = f2bf(v.w);
        *(ushort4*)(pnbf + gi) = b4;
#pragma unroll
        for (int p = 0; p < NP; ++p) {
            float wv = ws[p * 64 + j];
            acc[p][0] += wv * v.x; acc[p][1] += wv * v.y;
            acc[p][2] += wv * v.z; acc[p][3] += wv * v.w;
        }
    }
#pragma unroll
    for (int jj = 0; jj < 3; ++jj)
#pragma unroll
        for (int u = 0; u < 4; ++u) {
            W32[((size_t)jj * SD + d0 + u) * KB + k] = acc[2 * jj][u];
            Wbf[((size_t)jj * SD + d0 + u) * KB + k] = f2bf(acc[2 * jj + 1][u]);
        }
#pragma unroll
    for (int u = 0; u < 4; ++u)
        Vbf[(size_t)(d0 + u) * KB + k] = f2bf(acc[6][u]);
}

// P = bf16(cf4*E + cf5*E2 + cf6*E3)
__global__ __launch_bounds__(256) void k_combP(const unsigned short* __restrict__ Ebf,
                                               const unsigned short* __restrict__ E2,
                                               const unsigned short* __restrict__ E3,
                                               unsigned short* __restrict__ P,
                                               float c4, float c5, float c6) {
    int idx = blockIdx.x * 256 + threadIdx.x;
    P[idx] = f2bf(c4 * bf2f(Ebf[idx]) + c5 * bf2f(E2[idx]) + c6 * bf2f(E3[idx]));
}

// fused: [0,1024) NN = L@X (2048^3) ; [1024,1280) CEout = CEa @ CEb (512x2048)
__global__ __launch_bounds__(256) void k_nn_ce(const unsigned short* __restrict__ L,
                                               const unsigned short* __restrict__ X,
                                               unsigned short* __restrict__ NNout,
                                               const unsigned short* __restrict__ CEa,
                                               const unsigned short* __restrict__ CEb,
                                               unsigned short* __restrict__ CEout) {
    __shared__ __align__(16) unsigned short SH[5120];
    int bid = blockIdx.x;
    if (bid < 1024)
        body_g64(SH, L, X, SD, (bid & 31) * 64, (bid >> 5) * 64, 0, NNout, SD,
                 nullptr, nullptr, nullptr, 0.f, 0.f);
    else {
        int bx = bid - 1024;
        body_g64(SH, CEa, CEb, SD, (bx & 7) * 64, (bx >> 3) * 64, 0, CEout, SD,
                 nullptr, nullptr, nullptr, 0.f, 0.f);
    }
}

// fused: [0,1024) gemm_M (M32 += c2*E2+c3*E3+E3@P, Mbf out) ; [1024,1792) Y_j batch
__global__ __launch_bounds__(256) void k_M_Y(const unsigned short* __restrict__ E3,
                                             const unsigned short* __restrict__ P,
                                             float* __restrict__ M32,
                                             const unsigned short* __restrict__ E2,
                                             unsigned short* __restrict__ Mbf,
                                             float c2, float c3,
                                             const unsigned short* __restrict__ Ebf,
                                             const unsigned short* __restrict__ Wbf,
                                             const float* __restrict__ W32,
                                             float* __restrict__ Y32) {
    __shared__ __align__(16) unsigned short SH[5120];
    int bid = blockIdx.x;
    if (bid < 1024)
        body_g64(SH, E3, P, SD, (bid & 31) * 64, (bid >> 5) * 64, 2, Mbf, SD,
                 M32, E2, E3, c2, c3);
    else {
        int l = bid - 1024;
        int j = l >> 8, bx = l & 255;
        body_horner(SH, bx, Ebf, Wbf + (size_t)j * SD * KB, W32 + (size_t)j * SD * KB,
                    Y32 + (size_t)j * SD * KB, nullptr);
    }
}

// fused: [0,512) CE3,CE4 = CE1,CE2 @ E2 ; [512,768) Z2 = E2@Vbf0 + Y2
__global__ __launch_bounds__(256) void k_ce2_z(const unsigned short* __restrict__ CEall,
                                               const unsigned short* __restrict__ E2,
                                               const float* __restrict__ Y32,
                                               const unsigned short* __restrict__ Vbf0,
                                               float* __restrict__ V32o,
                                               unsigned short* __restrict__ Vbfo) {
    __shared__ __align__(16) unsigned short SH[5120];
    int bid = blockIdx.x;
    if (bid < 512) {
        int y = bid >> 8, bx = bid & 255;
        body_g64(SH, CEall + (size_t)(1 + y) * OD * SD, E2, SD,
                 (bx & 7) * 64, (bx >> 3) * 64, 0,
                 (unsigned short*)(CEall + (size_t)(3 + y) * OD * SD), SD,
                 nullptr, nullptr, nullptr, 0.f, 0.f);
    } else
        body_horner(SH, bid - 512, E2, Vbf0, Y32 + (size_t)2 * SD * KB, V32o, Vbfo);
}

// fused: [0,256) CE5 = CE3 @ E2 ; [256,512) Z1 = E2@Vbf1 + Y1
__global__ __launch_bounds__(256) void k_ce1_z(const unsigned short* __restrict__ CEall,
                                               const unsigned short* __restrict__ E2,
                                               const float* __restrict__ Y32,
                                               const unsigned short* __restrict__ Vbf1,
                                               float* __restrict__ V32o,
                                               unsigned short* __restrict__ Vbfo) {
    __shared__ __align__(16) unsigned short SH[5120];
    int bid = blockIdx.x;
    if (bid < 256)
        body_g64(SH, CEall + (size_t)3 * OD * SD, E2, SD,
                 (bid & 7) * 64, (bid >> 3) * 64, 0,
                 (unsigned short*)(CEall + (size_t)5 * OD * SD), SD,
                 nullptr, nullptr, nullptr, 0.f, 0.f);
    else
        body_horner(SH, bid - 256, E2, Vbf1, Y32 + (size_t)SD * KB, V32o, Vbfo);
}

// Z0: u = E2@Vbf0 + Y0
__global__ __launch_bounds__(256) void k_hornerZ(const unsigned short* __restrict__ E2,
                                                 const unsigned short* __restrict__ Vbf0,
                                                 const float* __restrict__ Y32,
                                                 float* __restrict__ V32o) {
    __shared__ __align__(16) unsigned short SH[5120];
    body_horner(SH, blockIdx.x, E2, Vbf0, Y32, V32o, nullptr);
}

// scan init: X[:,0]=s0, X[:,k]=u_{k-1}; zero 16-col pads of both bf bufs
__global__ __launch_bounds__(256) void k_scan_init(const float* __restrict__ s0,
                                                   const float* __restrict__ U,
                                                   float* __restrict__ S32,
                                                   unsigned short* __restrict__ Sbf0,
                                                   unsigned short* __restrict__ Sbf1) {
    int idx = blockIdx.x * 256 + threadIdx.x;
    int d = idx / KBP, c = idx - d * KBP;
    if (c < 16) { Sbf0[idx] = 0; Sbf1[idx] = 0; return; }
    int k = c - 16;
    float v = (k == 0) ? s0[d] : U[(size_t)d * KB + (k - 1)];
    S32[(size_t)d * KB + k] = v;
    Sbf0[idx] = f2bf(v);
}

// fused: [0,1024) squaring M'=2a*M+Mbf@Mbf ; [1024,1280) scan round (same M_r input)
__global__ __launch_bounds__(256) void k_sqscan(const unsigned short* __restrict__ Lbf,
                                                float* __restrict__ M32,
                                                unsigned short* __restrict__ Mbfo,
                                                float twoa,
                                                const unsigned short* __restrict__ Sbf_in,
                                                const float* __restrict__ S32_in,
                                                float* __restrict__ S32_out,
                                                unsigned short* __restrict__ Sbf_out,
                                                float ar, int shift) {
    __shared__ __align__(16) unsigned short SH[5120];
    int bid = blockIdx.x;
    if (bid < 1024)
        body_g64(SH, Lbf, Lbf, SD, (bid & 31) * 64, (bid >> 5) * 64, 3, Mbfo, SD,
                 M32, nullptr, nullptr, twoa, 0.f);
    else
        body_scan(SH, bid - 1024, Lbf, Sbf_in, S32_in, S32_out, Sbf_out, ar, shift);
}

// scan round 3 (GEMM, no paired squaring)
__global__ __launch_bounds__(256) void k_scan3(const unsigned short* __restrict__ Mrbf,
                                               const unsigned short* __restrict__ Sbf_in,
                                               const float* __restrict__ S32_in,
                                               float* __restrict__ S32_out,
                                               unsigned short* __restrict__ Sbf_out,
                                               float ar, int shift) {
    __shared__ __align__(16) unsigned short SH[5120];
    body_scan(SH, blockIdx.x, Mrbf, Sbf_in, S32_in, S32_out, Sbf_out, ar, shift);
}

// scan round 4: scalar only (M4 matrix dropped, ||M4||~3e-3)
__global__ __launch_bounds__(256) void k_scan16(const float* __restrict__ S32_in,
                                                float* __restrict__ S32_out,
                                                unsigned short* __restrict__ Sbf_out,
                                                float a4) {
    int idx = blockIdx.x * 256 + threadIdx.x;   // over SD*KB
    int d = idx >> 7, k = idx & 127;
    float v = S32_in[idx] + (k >= 16 ? a4 * S32_in[idx - 16] : 0.f);
    S32_out[idx] = v;
    Sbf_out[(size_t)d * KBP + k + 16] = f2bf(v);
}

// fused: [0,1280) Pall = CEcat @ pnbf^T (128^2 core) ; [1280,1376) H = CE_p @ S_bound
__global__ __launch_bounds__(256) void k_pall_h(const unsigned short* __restrict__ CEall,
                                                const unsigned short* __restrict__ pnbf,
                                                unsigned short* __restrict__ Pall,
                                                const unsigned short* __restrict__ Sbf16,
                                                float* __restrict__ H) {
    __shared__ __align__(16) unsigned short SH[8192];
    int bid = blockIdx.x;
    if (bid < 1280)
        body_g128(SH, bid, CEall, SD, pnbf, SD, 20, 8, Pall, (size_t)NT);
    else {
        int l = bid - 1280;
        int y = l >> 4, bx = l & 15;
        body_g64(SH, CEall + (size_t)y * OD * SD, Sbf16, KBP,
                 (bx & 7) * 64, (bx >> 3) * 64, 1, nullptr, KB,
                 H + (size_t)y * OD * KB, nullptr, nullptr, 0.f, 0.f);
    }
}

// final: out[64k+i][o] = Pall_p(o,:)@T_p(:,i) + sum_p cW[p][i]*H[p][o][k] + OBS_STD*on
__global__ __launch_bounds__(256) void k_final2(const unsigned short* __restrict__ P,
                                                const unsigned short* __restrict__ Tbf,
                                                const float* __restrict__ H,
                                                const float* __restrict__ cW,
                                                const float* __restrict__ on,
                                                float* __restrict__ out) {
    __shared__ __align__(16) float obsT[64][65];
    unsigned short* Al = (unsigned short*)obsT;
    unsigned short* Xt = Al + 64 * 40;
    int bx = blockIdx.x;
    int kb = bx >> 3, ob = bx & 7;
    int o0 = ob * 64;
    int tid = threadIdx.x, lane = tid & 63, w = tid >> 6;
    int m16 = lane & 15, q = lane >> 4;
    int ar = tid >> 2, ao = (tid & 3) * 8;
    int xk = tid >> 3, xn = (tid & 7) * 8;
    int qb = xk >> 3;
    v4f acc[4] = {{0,0,0,0},{0,0,0,0},{0,0,0,0},{0,0,0,0}};
    const unsigned short* Abase = P + (size_t)kb * 64;

    v8s av = *(const v8s*)(Abase + (size_t)(o0 + ar) * NT + ao);
    v8s xv = *(const v8s*)(Tbf + xk * 64 + xn);
    for (int kc = 0; kc < 2 * NPN; ++kc) {
        *(v8s*)(Al + ar * 40 + ao) = av;
#pragma unroll
        for (int c = 0; c < 8; ++c) {
            int n = xn + c, sw = (n >> 3) & 3;
            Xt[n * 40 + (((qb ^ sw) << 3) | (xk & 7))] = xv[c];
        }
        __syncthreads();
        if (kc + 1 < 2 * NPN) {
            int p = (kc + 1) >> 1, j0 = ((kc + 1) & 1) * 32;
            av = *(const v8s*)(Abase + (size_t)(p * OD + o0 + ar) * NT + j0 + ao);
            xv = *(const v8s*)(Tbf + p * 4096 + (j0 + xk) * 64 + xn);
        }
        v8s a = *(const v8s*)(Al + (w * 16 + m16) * 40 + q * 8);
#pragma unroll
        for (int c = 0; c < 4; ++c) {
            int nl = c * 16 + m16, swn = (nl >> 3) & 3;
            v8s b = *(const v8s*)(Xt + nl * 40 + ((q ^ swn) << 3));
            acc[c] = __builtin_amdgcn_mfma_f32_16x16x32_bf16(a, b, acc[c], 0, 0, 0);
        }
        __syncthreads();
    }
#pragma unroll
    for (int c = 0; c < 4; ++c)
#pragma unroll
        for (int j = 0; j < 4; ++j)
            obsT[w * 16 + q * 4 + j][c * 16 + m16] = acc[c][j];
    __syncthreads();
    int g = tid >> 6;
    float Hv[NPH];
#pragma unroll
    for (int p = 0; p < NPH; ++p)
        Hv[p] = H[((size_t)p * OD + o0 + lane) * KB + kb];
#pragma unroll
    for (int r = 0; r < 16; ++r) {
        int trow = r * 4 + g;
        float a2 = obsT[lane][trow];
#pragma unroll
        for (int p = 0; p < NPH; ++p) a2 += cW[p * 64 + trow] * Hv[p];
        size_t oidx = (size_t)(kb * 64 + trow) * OD + o0 + lane;
        out[oidx] = a2 + OBS_STD * on[oidx];
    }
}

// ================= host =================
extern "C" void kernel_launch(void* const* d_in, const int* in_sizes, int n_in,
                              void* d_out, int out_size, void* d_ws, size_t ws_size,
                              hipStream_t stream) {
    const float* s0 = (const float*)d_in[0];
    const float* A  = (const float*)d_in[1];
    const float* C  = (const float*)d_in[2];
    const float* pn = (const float*)d_in[3];
    const float* on = (const float*)d_in[4];
    float* out = (float*)d_out;

    char* p = (char*)d_ws;
    auto take = [&](size_t n) { char* r = p; p += (n + 255) & ~(size_t)255; return r; };
    unsigned short* Ebf = (unsigned short*)take((size_t)SD * SD * 2);
    unsigned short* CEall = (unsigned short*)take((size_t)NPH * OD * SD * 2);
    // contiguous M+Xp0+Xp1+Xp2 = 41,943,040 B == Pall (2560*8192*2) exactly
    float* M            = (float*)take((size_t)SD * SD * 4);
    unsigned short* Xp0 = (unsigned short*)take((size_t)SD * SD * 2);   // E2 -> M-ping
    unsigned short* Xp1 = (unsigned short*)take((size_t)SD * SD * 2);   // E3
    unsigned short* Xp2 = (unsigned short*)take((size_t)SD * SD * 2);   // P
    unsigned short* Pall = (unsigned short*)M;
    unsigned short* Mbf = (unsigned short*)take((size_t)SD * SD * 2);   // dedicated Mbf
    float* W32          = (float*)take((size_t)3 * SD * KB * 4);
    unsigned short* Wbf = (unsigned short*)take((size_t)3 * SD * KB * 2);
    float* Y32          = (float*)take((size_t)3 * SD * KB * 4);
    float* V32[2] = {(float*)take((size_t)SD * KB * 4), (float*)take((size_t)SD * KB * 4)};
    unsigned short* Vbf[2] = {(unsigned short*)take((size_t)SD * KB * 2),
                              (unsigned short*)take((size_t)SD * KB * 2)};
    float* SC32[2] = {(float*)take((size_t)SD * KB * 4), (float*)take((size_t)SD * KB * 4)};
    unsigned short* SCbf[2] = {(unsigned short*)take((size_t)SD * KBP * 2),
                               (unsigned short*)take((size_t)SD * KBP * 2)};
    float* wW   = (float*)take((size_t)NP * 64 * 4);
    float* cW   = (float*)take((size_t)NP * 64 * 4);
    unsigned short* Tbf = (unsigned short*)take((size_t)NP * 64 * 64 * 2);
    unsigned short* pnbf = (unsigned short*)take((size_t)SD * NT * 2);
    float* H    = (float*)take((size_t)NPH * OD * KB * 4);

    double pw[65]; pw[0] = 1.0;
    for (int m = 1; m <= 64; ++m) pw[m] = pw[m - 1] * 0.99;
    const double bin[7] = {1, 64, 2016, 41664, 635376, 7624512, 74974368};
    float cf[7];
    for (int m = 1; m <= 6; ++m) cf[m] = (float)(bin[m] * pw[64 - m]);
    float a64 = (float)pw[64];

    // 1. fused prep (E/M, CE0, weights)
    k_prepAll<<<20592, 256, 0, stream>>>(A, C, Ebf, M, cf[1], CEall, wW, cW, Tbf);
    // 2. pass1 reduction + pnbf
    k_wsum<<<256, 256, 0, stream>>>(pn, wW, W32, Wbf, Vbf[0], pnbf);
    // 3. E2 + CE1
    k_nn_ce<<<1280, 256, 0, stream>>>(Ebf, Ebf, Xp0, CEall, Ebf, CEall + (size_t)OD * SD);
    // 4. E3 + CE2
    k_nn_ce<<<1280, 256, 0, stream>>>(Ebf, Xp0, Xp1, CEall, Xp0, CEall + (size_t)2 * OD * SD);
    // 5. P combo
    k_combP<<<SD * SD / 256, 256, 0, stream>>>(Ebf, Xp0, Xp1, Xp2, cf[4], cf[5], cf[6]);
    // 6. gemm_M + Y batch
    k_M_Y<<<1792, 256, 0, stream>>>(Xp1, Xp2, M, Xp0, Mbf, cf[2], cf[3], Ebf, Wbf, W32, Y32);
    // 7. CE3,CE4 + Z2
    k_ce2_z<<<768, 256, 0, stream>>>(CEall, Xp0, Y32, Vbf[0], V32[1], Vbf[1]);
    // 8. CE5 + Z1
    k_ce1_z<<<512, 256, 0, stream>>>(CEall, Xp0, Y32, Vbf[1], V32[0], Vbf[0]);
    // 9. u
    k_hornerZ<<<256, 256, 0, stream>>>(Xp0, Vbf[0], Y32, V32[1]);
    // 10. scan init
    k_scan_init<<<SD * KBP / 256, 256, 0, stream>>>(s0, V32[1], SC32[0], SCbf[0], SCbf[1]);
    // 11-13. fused squaring+scan rounds 0..2
    float a = a64;
    k_sqscan<<<1280, 256, 0, stream>>>(Mbf, M, Xp0, 2.f * a,
                                       SCbf[0], SC32[0], SC32[1], SCbf[1], a, 1);
    a *= a;
    k_sqscan<<<1280, 256, 0, stream>>>(Xp0, M, Mbf, 2.f * a,
                                       SCbf[1], SC32[1], SC32[0], SCbf[0], a, 2);
    a *= a;
    k_sqscan<<<1280, 256, 0, stream>>>(Mbf, M, Xp0, 2.f * a,
                                       SCbf[0], SC32[0], SC32[1], SCbf[1], a, 4);
    a *= a;
    // 14. scan round 3 (M3)
    k_scan3<<<256, 256, 0, stream>>>(Xp0, SCbf[1], SC32[1], SC32[0], SCbf[0], a, 8);
    a *= a;
    // 15. scan round 4 (scalar)
    k_scan16<<<SD * KB / 256, 256, 0, stream>>>(SC32[0], SC32[1], SCbf[1], a);
    // 16. Pall + H
    k_pall_h<<<1376, 256, 0, stream>>>(CEall, pnbf, Pall, SCbf[1] + 16, H);
    // 17. final
    k_final2<<<1024, 256, 0, stream>>>(Pall, Tbf, H, cW, on, out);
}

// Round 8
// 760.127 us; speedup vs baseline: 6.4213x; 1.0364x over previous
//
#include <hip/hip_runtime.h>

// SimpleStateSpaceModel restructure v9:
//   v8 accounting: pall 151us (structure-bound 569 TF), sqscan x3 ~195us (67MB fp32 M RMW
//   each), nn_ce x2 ~115us, ~120us gaps over 17 launches.
//   (1) pure-bf16 M chain: fp32 M deleted (scan consumes bf16 M_r anyway) -> -45us traffic
//   (2) P fused into E3 epilogue (mode 4); combP deleted
//   (3) scan16 deleted: H = G + a16*shift16(G), G = CE@scan3out, combined in final2
//   (4) scan_init fused into hornerZ epilogue; scan-shift8 fused into Pall launch
//   14 launches. Pall gets its own region (no Xp0 alias -> safe to fuse scan3 with it).

#define SD 2048      // state dim
#define OD 512       // obs dim
#define NT 8192      // steps
#define BLK 64       // steps per block
#define KB 128       // number of blocks = NT/BLK
#define KBP (KB+16)  // padded column stride for scan bf16 buffers
#define NP 7         // binomial terms p=0..6
#define NPH 6        // homogeneous obs terms p=0..5
#define NPN 5        // noise obs terms p=0..4
#define PROC_STD 0.31622776601683794f
#define OBS_STD  0.7071067811865476f

typedef __attribute__((ext_vector_type(8))) short v8s;
typedef __attribute__((ext_vector_type(4))) float v4f;

__device__ __forceinline__ unsigned short f2bf(float f) {
    union { float f; unsigned int u; } v; v.f = f;
    unsigned int r = v.u + 0x7fffu + ((v.u >> 16) & 1u);
    return (unsigned short)(r >> 16);
}
__device__ __forceinline__ float bf2f(unsigned short u) {
    union { unsigned int ui; float f; } cv; cv.ui = (unsigned int)u << 16;
    return cv.f;
}

#define GLD16(g, l) __builtin_amdgcn_global_load_lds( \
    (const __attribute__((address_space(1))) unsigned int*)(g), \
    (__attribute__((address_space(3))) unsigned int*)(l), 16, 0, 0)

// ================= device bodies =================

// 64^2-tile GEMM body over K=SD.
// mode 0: obf[r*ldo+col]=bf16(acc)
// mode 1: o32[r*ldo+col]=acc
// mode 2 (gemm_M): v=c1*X1+c2*X2+c3*X3+acc (X* bf16 @SD); obf=bf16(v) @SD
// mode 3 (squaring): v=c1*bf2f(X1[iS])+acc; obf=bf16(v) @SD
// mode 4 (E3+P): obf[iS]=bf16(acc); Pout[iS]=bf16(c1*X1+c2*X2+c3*acc)
__device__ __forceinline__ void body_g64(unsigned short* SH,
        const unsigned short* __restrict__ A,
        const unsigned short* __restrict__ B, int ldb,
        int tM, int tN, int mode,
        unsigned short* __restrict__ obf, int ldo,
        float* __restrict__ o32,
        const unsigned short* __restrict__ X1,
        const unsigned short* __restrict__ X2,
        const unsigned short* __restrict__ X3,
        unsigned short* __restrict__ Pout,
        float c1, float c2, float c3) {
    unsigned short* Al = SH;
    unsigned short* Xt = SH + 64 * 40;
    int tid = threadIdx.x, lane = tid & 63, w = tid >> 6;
    int m16 = lane & 15, q = lane >> 4;
    int ar = tid >> 2, ao = (tid & 3) * 8;
    int xk = tid >> 3, xn = (tid & 7) * 8;
    int qb = xk >> 3;
    v4f acc[4] = {{0,0,0,0},{0,0,0,0},{0,0,0,0},{0,0,0,0}};

    v8s av = *(const v8s*)(A + (size_t)(tM + ar) * SD + ao);
    v8s xv = *(const v8s*)(B + (size_t)xk * ldb + tN + xn);
    for (int k0 = 0; k0 < SD; k0 += 32) {
        *(v8s*)(Al + ar * 40 + ao) = av;
#pragma unroll
        for (int c = 0; c < 8; ++c) {
            int n = xn + c, sw = (n >> 3) & 3;
            Xt[n * 40 + (((qb ^ sw) << 3) | (xk & 7))] = xv[c];
        }
        __syncthreads();
        if (k0 + 32 < SD) {
            av = *(const v8s*)(A + (size_t)(tM + ar) * SD + (k0 + 32) + ao);
            xv = *(const v8s*)(B + (size_t)(k0 + 32 + xk) * ldb + tN + xn);
        }
        v8s a = *(const v8s*)(Al + (w * 16 + m16) * 40 + q * 8);
#pragma unroll
        for (int c = 0; c < 4; ++c) {
            int nl = c * 16 + m16, swn = (nl >> 3) & 3;
            v8s b = *(const v8s*)(Xt + nl * 40 + ((q ^ swn) << 3));
            acc[c] = __builtin_amdgcn_mfma_f32_16x16x32_bf16(a, b, acc[c], 0, 0, 0);
        }
        __syncthreads();
    }
#pragma unroll
    for (int c = 0; c < 4; ++c)
#pragma unroll
        for (int j = 0; j < 4; ++j) {
            int r = tM + w * 16 + q * 4 + j;
            int col = tN + c * 16 + m16;
            float v = acc[c][j];
            size_t iS = (size_t)r * SD + col;
            if (mode == 2) {
                v += c1 * bf2f(X1[iS]) + c2 * bf2f(X2[iS]) + c3 * bf2f(X3[iS]);
                obf[iS] = f2bf(v);
            } else if (mode == 3) {
                v = c1 * bf2f(X1[iS]) + v;
                obf[iS] = f2bf(v);
            } else if (mode == 4) {
                obf[iS] = f2bf(v);
                Pout[iS] = f2bf(c1 * bf2f(X1[iS]) + c2 * bf2f(X2[iS]) + c3 * v);
            } else if (mode == 1) {
                o32[(size_t)r * ldo + col] = v;
            } else {
                obf[(size_t)r * ldo + col] = f2bf(v);
            }
        }
}

// Horner body: out = Abf(2048x2048) @ Xbf(2048x128) + Wp
// initShift=0: X32o[idx]=v, Xbfo[idx]=bf16 (Xbfo may be null)
// initShift=1: scan-init store: col kc -> k=kc+1 (kc==127 dropped), padded bf16
__device__ __forceinline__ void body_horner(unsigned short* SH, int bx,
        const unsigned short* __restrict__ Abf,
        const unsigned short* __restrict__ Xbf,
        const float* __restrict__ Wp,
        float* __restrict__ X32o,
        unsigned short* __restrict__ Xbfo,
        int initShift) {
    unsigned short* Al = SH;
    unsigned short* Xt = SH + 32 * 72;
    int tM = (bx & 63) * 32, tN = (bx >> 6) * 32;
    int tid = threadIdx.x, lane = tid & 63, w = tid >> 6;
    int m16 = lane & 15, q = lane >> 4;
    int ar = tid >> 3, ao = (tid & 7) * 8;
    int xk = tid >> 2, xn = (tid & 3) * 8;
    int qb = xk >> 3;
    v4f acc = {0, 0, 0, 0};
    v8s av = *(const v8s*)(Abf + (size_t)(tM + ar) * SD + ao);
    v8s xv = *(const v8s*)(Xbf + (size_t)xk * KB + tN + xn);
    int nl = (w & 1) * 16 + m16;
    int swn = (nl >> 3) & 3;
    int rl = (w >> 1) * 16 + m16;
    for (int k0 = 0; k0 < SD; k0 += 64) {
        *(v8s*)(Al + ar * 72 + ao) = av;
#pragma unroll
        for (int c = 0; c < 8; ++c) {
            int n = xn + c, sw = (n >> 3) & 3;
            Xt[n * 72 + (((qb ^ sw) << 3) | (xk & 7))] = xv[c];
        }
        __syncthreads();
        if (k0 + 64 < SD) {
            av = *(const v8s*)(Abf + (size_t)(tM + ar) * SD + (k0 + 64) + ao);
            xv = *(const v8s*)(Xbf + (size_t)(k0 + 64 + xk) * KB + tN + xn);
        }
#pragma unroll
        for (int ch = 0; ch < 2; ++ch) {
            v8s a = *(const v8s*)(Al + rl * 72 + ch * 32 + q * 8);
            int q2 = ch * 4 + q;
            v8s b = *(const v8s*)(Xt + nl * 72 + ((q2 ^ swn) << 3));
            acc = __builtin_amdgcn_mfma_f32_16x16x32_bf16(a, b, acc, 0, 0, 0);
        }
        __syncthreads();
    }
#pragma unroll
    for (int j = 0; j < 4; ++j) {
        int r = tM + (w >> 1) * 16 + q * 4 + j;
        int kc = tN + (w & 1) * 16 + m16;
        float v = acc[j] + Wp[r * KB + kc];
        if (initShift) {
            if (kc < 127) {
                X32o[r * KB + kc + 1] = v;
                Xbfo[(size_t)r * KBP + kc + 17] = f2bf(v);
            }
        } else {
            X32o[r * KB + kc] = v;
            if (Xbfo) Xbfo[r * KB + kc] = f2bf(v);
        }
    }
}

// Scan body: S'[:,k] = S[:,k] + ar*S[:,k-sh] + Mr@S[:,k-sh]
__device__ __forceinline__ void body_scan(unsigned short* SH, int bx,
        const unsigned short* __restrict__ Mrbf,
        const unsigned short* __restrict__ Sbf_in,
        const float* __restrict__ S32_in,
        float* __restrict__ S32_out,
        unsigned short* __restrict__ Sbf_out,
        float ar, int shift) {
    unsigned short* Al = SH;
    unsigned short* Xt = SH + 32 * 72;
    int tM = (bx & 63) * 32, tN = (bx >> 6) * 32;
    int tid = threadIdx.x, lane = tid & 63, w = tid >> 6;
    int m16 = lane & 15, q = lane >> 4;
    int ar_ = tid >> 3, ao = (tid & 7) * 8;
    int xk = tid >> 2, xn = (tid & 3) * 8;
    int qb = xk >> 3;
    int coff = tN + xn + 16 - shift;
    v4f acc = {0, 0, 0, 0};
    v8s av = *(const v8s*)(Mrbf + (size_t)(tM + ar_) * SD + ao);
    v8s xv = *(const v8s*)(Sbf_in + (size_t)xk * KBP + coff);
    int nl = (w & 1) * 16 + m16;
    int swn = (nl >> 3) & 3;
    int rl = (w >> 1) * 16 + m16;
    for (int k0 = 0; k0 < SD; k0 += 64) {
        *(v8s*)(Al + ar_ * 72 + ao) = av;
#pragma unroll
        for (int c = 0; c < 8; ++c) {
            int n = xn + c, sw = (n >> 3) & 3;
            Xt[n * 72 + (((qb ^ sw) << 3) | (xk & 7))] = xv[c];
        }
        __syncthreads();
        if (k0 + 64 < SD) {
            av = *(const v8s*)(Mrbf + (size_t)(tM + ar_) * SD + (k0 + 64) + ao);
            xv = *(const v8s*)(Sbf_in + (size_t)(k0 + 64 + xk) * KBP + coff);
        }
#pragma unroll
        for (int ch = 0; ch < 2; ++ch) {
            v8s a = *(const v8s*)(Al + rl * 72 + ch * 32 + q * 8);
            int q2 = ch * 4 + q;
            v8s b = *(const v8s*)(Xt + nl * 72 + ((q2 ^ swn) << 3));
            acc = __builtin_amdgcn_mfma_f32_16x16x32_bf16(a, b, acc, 0, 0, 0);
        }
        __syncthreads();
    }
#pragma unroll
    for (int j = 0; j < 4; ++j) {
        int r = tM + (w >> 1) * 16 + q * 4 + j;
        int kc = tN + (w & 1) * 16 + m16;
        int idx = r * KB + kc;
        int ksh = kc - shift;
        float v = S32_in[idx] + acc[j] + (ksh >= 0 ? ar * S32_in[r * KB + ksh] : 0.f);
        S32_out[idx] = v;
        Sbf_out[(size_t)r * KBP + kc + 16] = f2bf(v);
    }
}

// 128^2-tile GEMM (m97 structure), XCD-swizzled; used only for Pall
__device__ __forceinline__ void body_g128(unsigned short* SH, int bid,
        const unsigned short* __restrict__ Aptr, int lda,
        const unsigned short* __restrict__ Bptr, int ldb,
        int mtiles, int npx,
        unsigned short* __restrict__ obf, size_t ldo) {
    unsigned short* As = SH;
    unsigned short* Bs = SH + 4096;
    int tid = threadIdx.x, lane = tid & 63, w = tid >> 6;
    int mT = (bid >> 3) % mtiles;
    int nT = (bid & 7) * npx + (bid >> 3) / mtiles;
    int tM = mT * 128, tN = nT * 128;
    int wr = w >> 1, wc = w & 1;
    int m16 = lane & 15, q = lane >> 4;
    int srow = lane >> 2, sk8 = lane & 3;
    const unsigned short* ga0 = Aptr + (size_t)(tM + w * 16 + srow) * lda + sk8 * 8;
    const unsigned short* ga1 = ga0 + (size_t)64 * lda;
    const unsigned short* gb0 = Bptr + (size_t)(tN + w * 16 + srow) * ldb + sk8 * 8;
    const unsigned short* gb1 = gb0 + (size_t)64 * ldb;
    unsigned short* la0 = As + w * 512;
    unsigned short* la1 = As + 2048 + w * 512;
    unsigned short* lb0 = Bs + w * 512;
    unsigned short* lb1 = Bs + 2048 + w * 512;

    v4f acc[4][4];
#pragma unroll
    for (int mi = 0; mi < 4; ++mi)
#pragma unroll
        for (int ni = 0; ni < 4; ++ni) acc[mi][ni] = (v4f){0, 0, 0, 0};

    GLD16(ga0, la0); GLD16(ga1, la1); GLD16(gb0, lb0); GLD16(gb1, lb1);
    ga0 += 32; ga1 += 32; gb0 += 32; gb1 += 32;
    __syncthreads();

    int arow = (wr * 64 + m16) * 32 + q * 8;
    int brow = (wc * 64 + m16) * 32 + q * 8;
    for (int k0 = 0; k0 < SD; k0 += 32) {
        v8s a[4], b[4];
#pragma unroll
        for (int mi = 0; mi < 4; ++mi) a[mi] = *(const v8s*)(As + arow + mi * 512);
#pragma unroll
        for (int ni = 0; ni < 4; ++ni) b[ni] = *(const v8s*)(Bs + brow + ni * 512);
        __syncthreads();
        if (k0 + 32 < SD) {
            GLD16(ga0, la0); GLD16(ga1, la1); GLD16(gb0, lb0); GLD16(gb1, lb1);
            ga0 += 32; ga1 += 32; gb0 += 32; gb1 += 32;
        }
#pragma unroll
        for (int mi = 0; mi < 4; ++mi)
#pragma unroll
            for (int ni = 0; ni < 4; ++ni)
                acc[mi][ni] = __builtin_amdgcn_mfma_f32_16x16x32_bf16(a[mi], b[ni],
                                                                      acc[mi][ni], 0, 0, 0);
        __syncthreads();
    }
#pragma unroll
    for (int mi = 0; mi < 4; ++mi)
#pragma unroll
        for (int ni = 0; ni < 4; ++ni)
#pragma unroll
            for (int j = 0; j < 4; ++j) {
                int row = tM + wr * 64 + mi * 16 + q * 4 + j;
                int col = tN + wc * 64 + ni * 16 + m16;
                obf[(size_t)row * ldo + col] = f2bf(acc[mi][ni][j]);
            }
}

// ================= kernels =================

__device__ double d_binom(int m, int p) {
    if (p < 0 || p > m) return 0.0;
    double c = 1.0;
    for (int q = 1; q <= p; ++q) c = c * (double)(m - p + q) / (double)q;
    return c;
}
__device__ double d_p99(int n) {
    double r = 1.0;
    for (int q = 0; q < n; ++q) r *= 0.99;
    return r;
}

// fused prep: [0,16384) Ebf ; [16384,20480) prep_C ; [20480,20592) weights
__global__ __launch_bounds__(256) void k_prepAll(const float* __restrict__ A,
                                                 const float* __restrict__ C,
                                                 unsigned short* __restrict__ Ebf,
                                                 unsigned short* __restrict__ Cbf,
                                                 float* __restrict__ wW,
                                                 float* __restrict__ cW,
                                                 unsigned short* __restrict__ Tbf) {
    int bid = blockIdx.x;
    if (bid < 16384) {
        int idx = bid * 256 + threadIdx.x;
        int r = idx >> 11, c = idx & 2047;
        float e = A[idx] - (r == c ? 0.99f : 0.0f);
        Ebf[idx] = f2bf(e);
    } else if (bid < 20480) {
        int idx = (bid - 16384) * 256 + threadIdx.x;
        Cbf[idx] = f2bf(C[idx]);
    } else {
        int idx = (bid - 20480) * 256 + threadIdx.x;
        if (idx < NP * 64) {
            int p = idx >> 6, j = idx & 63;
            int m = 63 - j;
            wW[idx] = (p <= m) ? (float)((double)PROC_STD * d_binom(m, p) * d_p99(m - p)) : 0.f;
            cW[idx] = (p <= j) ? (float)(d_binom(j, p) * d_p99(j - p)) : 0.f;
        }
        if (idx < NP * 64 * 64) {
            int p = idx >> 12, j = (idx >> 6) & 63, i = idx & 63;
            int mm = i - 1 - j;
            float t = (mm >= p) ? (float)((double)PROC_STD * d_binom(mm, p) * d_p99(mm - p)) : 0.f;
            Tbf[idx] = f2bf(t);
        }
    }
}

// pass1 reduction + pnbf
__global__ __launch_bounds__(256) void k_wsum(const float* __restrict__ pn,
                                              const float* __restrict__ wW,
                                              float* __restrict__ W32,
                                              unsigned short* __restrict__ Wbf,
                                              unsigned short* __restrict__ Vbf,
                                              unsigned short* __restrict__ pnbf) {
    __shared__ float ws[NP * 64];
    int tid = threadIdx.x;
    for (int t = tid; t < NP * 64; t += 256) ws[t] = wW[t];
    __syncthreads();
    int bx = blockIdx.x;
    int k = bx >> 1, dc = bx & 1;
    int d0 = dc * 1024 + tid * 4;
    float acc[NP][4];
#pragma unroll
    for (int p = 0; p < NP; ++p)
#pragma unroll
        for (int u = 0; u < 4; ++u) acc[p][u] = 0.f;
    for (int j = 0; j < 64; ++j) {
        size_t gi = (size_t)(k * BLK + j) * SD + d0;
        float4 v = *(const float4*)(pn + gi);
        ushort4 b4;
        b4.x = f2bf(v.x); b4.y = f2bf(v.y); b4.z = f2bf(v.z); b4.w = f2bf(v.w);
        *(ushort4*)(pnbf + gi) = b4;
#pragma unroll
        for (int p = 0; p < NP; ++p) {
            float wv = ws[p * 64 + j];
            acc[p][0] += wv * v.x; acc[p][1] += wv * v.y;
            acc[p][2] += wv * v.z; acc[p][3] += wv * v.w;
        }
    }
#pragma unroll
    for (int jj = 0; jj < 3; ++jj)
#pragma unroll
        for (int u = 0; u < 4; ++u) {
            W32[((size_t)jj * SD + d0 + u) * KB + k] = acc[2 * jj][u];
            Wbf[((size_t)jj * SD + d0 + u) * KB + k] = f2bf(acc[2 * jj + 1][u]);
        }
#pragma unroll
    for (int u = 0; u < 4; ++u)
        Vbf[(size_t)(d0 + u) * KB + k] = f2bf(acc[6][u]);
}

// fused: [0,1024) NN = L@X ; [1024,1280) CEout = CEa @ CEb
__global__ __launch_bounds__(256) void k_nn_ce(const unsigned short* __restrict__ L,
                                               const unsigned short* __restrict__ X,
                                               unsigned short* __restrict__ NNout,
                                               const unsigned short* __restrict__ CEa,
                                               const unsigned short* __restrict__ CEb,
                                               unsigned short* __restrict__ CEout,
                                               int mode,
                                               unsigned short* __restrict__ Pout,
                                               const unsigned short* __restrict__ X1,
                                               const unsigned short* __restrict__ X2,
                                               float c1, float c2, float c3) {
    __shared__ __align__(16) unsigned short SH[5120];
    int bid = blockIdx.x;
    if (bid < 1024)
        body_g64(SH, L, X, SD, (bid & 31) * 64, (bid >> 5) * 64, mode, NNout, SD,
                 nullptr, X1, X2, nullptr, Pout, c1, c2, c3);
    else {
        int bx = bid - 1024;
        body_g64(SH, CEa, CEb, SD, (bx & 7) * 64, (bx >> 3) * 64, 0, CEout, SD,
                 nullptr, nullptr, nullptr, nullptr, nullptr, 0.f, 0.f, 0.f);
    }
}

// fused: [0,1024) gemm_M (Mbf = bf16(c1 E + c2 E2 + c3 E3 + E3@P)) ; [1024,1792) Y batch
__global__ __launch_bounds__(256) void k_M_Y(const unsigned short* __restrict__ E3,
                                             const unsigned short* __restrict__ P,
                                             const unsigned short* __restrict__ Ebf,
                                             const unsigned short* __restrict__ E2,
                                             unsigned short* __restrict__ Mbf,
                                             float c1, float c2, float c3,
                                             const unsigned short* __restrict__ Wbf,
                                             const float* __restrict__ W32,
                                             float* __restrict__ Y32) {
    __shared__ __align__(16) unsigned short SH[5120];
    int bid = blockIdx.x;
    if (bid < 1024)
        body_g64(SH, E3, P, SD, (bid & 31) * 64, (bid >> 5) * 64, 2, Mbf, SD,
                 nullptr, Ebf, E2, E3, nullptr, c1, c2, c3);
    else {
        int l = bid - 1024;
        int j = l >> 8, bx = l & 255;
        body_horner(SH, bx, Ebf, Wbf + (size_t)j * SD * KB, W32 + (size_t)j * SD * KB,
                    Y32 + (size_t)j * SD * KB, nullptr, 0);
    }
}

// fused: [0,512) CE3,CE4 = CE1,CE2 @ E2 ; [512,768) Z2 = E2@Vbf0 + Y2
__global__ __launch_bounds__(256) void k_ce2_z(const unsigned short* __restrict__ CEall,
                                               const unsigned short* __restrict__ E2,
                                               const float* __restrict__ Y32,
                                               const unsigned short* __restrict__ Vbf0,
                                               float* __restrict__ V32o,
                                               unsigned short* __restrict__ Vbfo) {
    __shared__ __align__(16) unsigned short SH[5120];
    int bid = blockIdx.x;
    if (bid < 512) {
        int y = bid >> 8, bx = bid & 255;
        body_g64(SH, CEall + (size_t)(1 + y) * OD * SD, E2, SD,
                 (bx & 7) * 64, (bx >> 3) * 64, 0,
                 (unsigned short*)(CEall + (size_t)(3 + y) * OD * SD), SD,
                 nullptr, nullptr, nullptr, nullptr, nullptr, 0.f, 0.f, 0.f);
    } else
        body_horner(SH, bid - 512, E2, Vbf0, Y32 + (size_t)2 * SD * KB, V32o, Vbfo, 0);
}

// fused: [0,256) CE5 = CE3 @ E2 ; [256,512) Z1 = E2@Vbf1 + Y1
__global__ __launch_bounds__(256) void k_ce1_z(const unsigned short* __restrict__ CEall,
                                               const unsigned short* __restrict__ E2,
                                               const float* __restrict__ Y32,
                                               const unsigned short* __restrict__ Vbf1,
                                               float* __restrict__ V32o,
                                               unsigned short* __restrict__ Vbfo) {
    __shared__ __align__(16) unsigned short SH[5120];
    int bid = blockIdx.x;
    if (bid < 256)
        body_g64(SH, CEall + (size_t)3 * OD * SD, E2, SD,
                 (bid & 7) * 64, (bid >> 3) * 64, 0,
                 (unsigned short*)(CEall + (size_t)5 * OD * SD), SD,
                 nullptr, nullptr, nullptr, nullptr, nullptr, 0.f, 0.f, 0.f);
    else
        body_horner(SH, bid - 256, E2, Vbf1, Y32 + (size_t)SD * KB, V32o, Vbfo, 0);
}

// fused: [0,256) u = E2@Vbf0 + Y0 with scan-init shifted store ; [256,384) pads + s0 col
__global__ __launch_bounds__(256) void k_hornerZI(const unsigned short* __restrict__ E2,
                                                  const unsigned short* __restrict__ Vbf0,
                                                  const float* __restrict__ Y32,
                                                  const float* __restrict__ s0,
                                                  float* __restrict__ S32,
                                                  unsigned short* __restrict__ Sbf0,
                                                  unsigned short* __restrict__ Sbf1) {
    __shared__ __align__(16) unsigned short SH[5120];
    int bid = blockIdx.x;
    if (bid < 256)
        body_horner(SH, bid, E2, Vbf0, Y32, S32, Sbf0, 1);
    else {
        int idx = (bid - 256) * 256 + threadIdx.x;   // SD*16 = 32768
        int d = idx >> 4, c = idx & 15;
        Sbf0[(size_t)d * KBP + c] = 0;
        Sbf1[(size_t)d * KBP + c] = 0;
        if (c == 0) {
            float v = s0[d];
            S32[d * KB] = v;
            Sbf0[(size_t)d * KBP + 16] = f2bf(v);
        }
    }
}

// fused: [0,1024) squaring Mbf' = bf16(2a*Mbf + Mbf@Mbf) ; [1024,1280) scan round
__global__ __launch_bounds__(256) void k_sqscan(const unsigned short* __restrict__ Lbf,
                                                unsigned short* __restrict__ Mbfo,
                                                float twoa,
                                                const unsigned short* __restrict__ Sbf_in,
                                                const float* __restrict__ S32_in,
                                                float* __restrict__ S32_out,
                                                unsigned short* __restrict__ Sbf_out,
                                                float ar, int shift) {
    __shared__ __align__(16) unsigned short SH[5120];
    int bid = blockIdx.x;
    if (bid < 1024)
        body_g64(SH, Lbf, Lbf, SD, (bid & 31) * 64, (bid >> 5) * 64, 3, Mbfo, SD,
                 nullptr, Lbf, nullptr, nullptr, nullptr, twoa, 0.f, 0.f);
    else
        body_scan(SH, bid - 1024, Lbf, Sbf_in, S32_in, S32_out, Sbf_out, ar, shift);
}

// fused: [0,1280) Pall = CEcat @ pnbf^T ; [1280,1536) scan shift-8 (independent inputs)
__global__ __launch_bounds__(256) void k_pall_s(const unsigned short* __restrict__ CEall,
                                                const unsigned short* __restrict__ pnbf,
                                                unsigned short* __restrict__ Pall,
                                                const unsigned short* __restrict__ M4,
                                                const unsigned short* __restrict__ Sbf_in,
                                                const float* __restrict__ S32_in,
                                                float* __restrict__ S32_out,
                                                unsigned short* __restrict__ Sbf_out,
                                                float ar) {
    __shared__ __align__(16) unsigned short SH[8192];
    int bid = blockIdx.x;
    if (bid < 1280)
        body_g128(SH, bid, CEall, SD, pnbf, SD, 20, 8, Pall, (size_t)NT);
    else
        body_scan(SH, bid - 1280, M4, Sbf_in, S32_in, S32_out, Sbf_out, ar, 8);
}

// G = CE_p @ S3  (96 blocks)
__global__ __launch_bounds__(256) void k_G(const unsigned short* __restrict__ CEall,
                                           const unsigned short* __restrict__ Sbf16,
                                           float* __restrict__ G) {
    __shared__ __align__(16) unsigned short SH[5120];
    int l = blockIdx.x;
    int y = l >> 4, bx = l & 15;
    body_g64(SH, CEall + (size_t)y * OD * SD, Sbf16, KBP,
             (bx & 7) * 64, (bx >> 3) * 64, 1, nullptr, KB,
             G + (size_t)y * OD * KB, nullptr, nullptr, nullptr, nullptr, 0.f, 0.f, 0.f);
}

// final: out = Pall_p(o,:)@T_p(:,i) + sum_p cW[p][i]*(G[p][o][k]+af*G[p][o][k-16]) + noise
__global__ __launch_bounds__(256) void k_final2(const unsigned short* __restrict__ P,
                                                const unsigned short* __restrict__ Tbf,
                                                const float* __restrict__ G,
                                                const float* __restrict__ cW,
                                                const float* __restrict__ on,
                                                float* __restrict__ out, float af) {
    __shared__ __align__(16) float obsT[64][65];
    unsigned short* Al = (unsigned short*)obsT;
    unsigned short* Xt = Al + 64 * 40;
    int bx = blockIdx.x;
    int kb = bx >> 3, ob = bx & 7;
    int o0 = ob * 64;
    int tid = threadIdx.x, lane = tid & 63, w = tid >> 6;
    int m16 = lane & 15, q = lane >> 4;
    int ar = tid >> 2, ao = (tid & 3) * 8;
    int xk = tid >> 3, xn = (tid & 7) * 8;
    int qb = xk >> 3;
    v4f acc[4] = {{0,0,0,0},{0,0,0,0},{0,0,0,0},{0,0,0,0}};
    const unsigned short* Abase = P + (size_t)kb * 64;

    v8s av = *(const v8s*)(Abase + (size_t)(o0 + ar) * NT + ao);
    v8s xv = *(const v8s*)(Tbf + xk * 64 + xn);
    for (int kc = 0; kc < 2 * NPN; ++kc) {
        *(v8s*)(Al + ar * 40 + ao) = av;
#pragma unroll
        for (int c = 0; c < 8; ++c) {
            int n = xn + c, sw = (n >> 3) & 3;
            Xt[n * 40 + (((qb ^ sw) << 3) | (xk & 7))] = xv[c];
        }
        __syncthreads();
        if (kc + 1 < 2 * NPN) {
            int p = (kc + 1) >> 1, j0 = ((kc + 1) & 1) * 32;
            av = *(const v8s*)(Abase + (size_t)(p * OD + o0 + ar) * NT + j0 + ao);
            xv = *(const v8s*)(Tbf + p * 4096 + (j0 + xk) * 64 + xn);
        }
        v8s a = *(const v8s*)(Al + (w * 16 + m16) * 40 + q * 8);
#pragma unroll
        for (int c = 0; c < 4; ++c) {
            int nl = c * 16 + m16, swn = (nl >> 3) & 3;
            v8s b = *(const v8s*)(Xt + nl * 40 + ((q ^ swn) << 3));
            acc[c] = __builtin_amdgcn_mfma_f32_16x16x32_bf16(a, b, acc[c], 0, 0, 0);
        }
        __syncthreads();
    }
#pragma unroll
    for (int c = 0; c < 4; ++c)
#pragma unroll
        for (int j = 0; j < 4; ++j)
            obsT[w * 16 + q * 4 + j][c * 16 + m16] = acc[c][j];
    __syncthreads();
    int g = tid >> 6;
    float Hv[NPH];
#pragma unroll
    for (int p = 0; p < NPH; ++p) {
        size_t base = ((size_t)p * OD + o0 + lane) * KB + kb;
        Hv[p] = G[base] + (kb >= 16 ? af * G[base - 16] : 0.f);
    }
#pragma unroll
    for (int r = 0; r < 16; ++r) {
        int trow = r * 4 + g;
        float a2 = obsT[lane][trow];
#pragma unroll
        for (int p = 0; p < NPH; ++p) a2 += cW[p * 64 + trow] * Hv[p];
        size_t oidx = (size_t)(kb * 64 + trow) * OD + o0 + lane;
        out[oidx] = a2 + OBS_STD * on[oidx];
    }
}

// ================= host =================
extern "C" void kernel_launch(void* const* d_in, const int* in_sizes, int n_in,
                              void* d_out, int out_size, void* d_ws, size_t ws_size,
                              hipStream_t stream) {
    const float* s0 = (const float*)d_in[0];
    const float* A  = (const float*)d_in[1];
    const float* C  = (const float*)d_in[2];
    const float* pn = (const float*)d_in[3];
    const float* on = (const float*)d_in[4];
    float* out = (float*)d_out;

    char* p = (char*)d_ws;
    auto take = [&](size_t n) { char* r = p; p += (n + 255) & ~(size_t)255; return r; };
    unsigned short* Ebf = (unsigned short*)take((size_t)SD * SD * 2);
    unsigned short* CEall = (unsigned short*)take((size_t)NPH * OD * SD * 2);
    unsigned short* Pall = (unsigned short*)take((size_t)(NPN * OD) * NT * 2);  // 41.94 MB
    unsigned short* Xp0 = (unsigned short*)take((size_t)SD * SD * 2);   // E2 -> M ping
    unsigned short* Xp1 = (unsigned short*)take((size_t)SD * SD * 2);   // E3 -> M ping
    unsigned short* Xp2 = (unsigned short*)take((size_t)SD * SD * 2);   // P
    unsigned short* Mbf = (unsigned short*)take((size_t)SD * SD * 2);
    float* W32          = (float*)take((size_t)3 * SD * KB * 4);
    unsigned short* Wbf = (unsigned short*)take((size_t)3 * SD * KB * 2);
    float* Y32          = (float*)take((size_t)3 * SD * KB * 4);
    float* V32[2] = {(float*)take((size_t)SD * KB * 4), (float*)take((size_t)SD * KB * 4)};
    unsigned short* Vbf[2] = {(unsigned short*)take((size_t)SD * KB * 2),
                              (unsigned short*)take((size_t)SD * KB * 2)};
    float* SC32[2] = {(float*)take((size_t)SD * KB * 4), (float*)take((size_t)SD * KB * 4)};
    unsigned short* SCbf[2] = {(unsigned short*)take((size_t)SD * KBP * 2),
                               (unsigned short*)take((size_t)SD * KBP * 2)};
    float* wW   = (float*)take((size_t)NP * 64 * 4);
    float* cW   = (float*)take((size_t)NP * 64 * 4);
    unsigned short* Tbf = (unsigned short*)take((size_t)NP * 64 * 64 * 2);
    unsigned short* pnbf = (unsigned short*)take((size_t)SD * NT * 2);
    float* G    = (float*)take((size_t)NPH * OD * KB * 4);

    double pw[65]; pw[0] = 1.0;
    for (int m = 1; m <= 64; ++m) pw[m] = pw[m - 1] * 0.99;
    const double bin[7] = {1, 64, 2016, 41664, 635376, 7624512, 74974368};
    float cf[7];
    for (int m = 1; m <= 6; ++m) cf[m] = (float)(bin[m] * pw[64 - m]);
    float a64 = (float)pw[64];

    // 1. fused prep
    k_prepAll<<<20592, 256, 0, stream>>>(A, C, Ebf, CEall, wW, cW, Tbf);
    // 2. pass1 reduction + pnbf
    k_wsum<<<256, 256, 0, stream>>>(pn, wW, W32, Wbf, Vbf[0], pnbf);
    // 3. E2 + CE1
    k_nn_ce<<<1280, 256, 0, stream>>>(Ebf, Ebf, Xp0, CEall, Ebf, CEall + (size_t)OD * SD,
                                      0, nullptr, nullptr, nullptr, 0.f, 0.f, 0.f);
    // 4. E3 (+P epilogue) + CE2
    k_nn_ce<<<1280, 256, 0, stream>>>(Ebf, Xp0, Xp1, CEall, Xp0,
                                      CEall + (size_t)2 * OD * SD,
                                      4, Xp2, Ebf, Xp0, cf[4], cf[5], cf[6]);
    // 5. gemm_M + Y batch
    k_M_Y<<<1792, 256, 0, stream>>>(Xp1, Xp2, Ebf, Xp0, Mbf, cf[1], cf[2], cf[3],
                                    Wbf, W32, Y32);
    // 6. CE3,CE4 + Z2
    k_ce2_z<<<768, 256, 0, stream>>>(CEall, Xp0, Y32, Vbf[0], V32[1], Vbf[1]);
    // 7. CE5 + Z1
    k_ce1_z<<<512, 256, 0, stream>>>(CEall, Xp0, Y32, Vbf[1], V32[0], Vbf[0]);
    // 8. u + scan init (shifted store; pads + s0 col)
    k_hornerZI<<<384, 256, 0, stream>>>(Xp0, Vbf[0], Y32, s0, SC32[0], SCbf[0], SCbf[1]);
    // 9-11. fused squaring+scan rounds (bf16-only M chain; Xp0/Xp1 dead -> ping-pong)
    float a = a64;
    k_sqscan<<<1280, 256, 0, stream>>>(Mbf, Xp0, 2.f * a,
                                       SCbf[0], SC32[0], SC32[1], SCbf[1], a, 1);
    a *= a;
    k_sqscan<<<1280, 256, 0, stream>>>(Xp0, Xp1, 2.f * a,
                                       SCbf[1], SC32[1], SC32[0], SCbf[0], a, 2);
    a *= a;
    k_sqscan<<<1280, 256, 0, stream>>>(Xp1, Xp0, 2.f * a,
                                       SCbf[0], SC32[0], SC32[1], SCbf[1], a, 4);
    a *= a;
    // 12. Pall + scan shift-8 (M4 = Xp0; Pall region disjoint from Xp0/Xp1)
    k_pall_s<<<1536, 256, 0, stream>>>(CEall, pnbf, Pall, Xp0,
                                       SCbf[1], SC32[1], SC32[0], SCbf[0], a);
    a *= a;   // a = a64^16 for the final G combine
    // 13. G = CE_p @ S3
    k_G<<<96, 256, 0, stream>>>(CEall, SCbf[0] + 16, G);
    // 14. final
    k_final2<<<1024, 256, 0, stream>>>(Pall, Tbf, G, cW, on, out, a);
}